// Round 1
// baseline (522.588 us; speedup 1.0000x reference)
//
#include <hip/hip_runtime.h>
#include <hip/hip_bf16.h>

typedef unsigned short u16;
typedef unsigned int u32;
typedef __attribute__((ext_vector_type(4))) float f32x4;
typedef __attribute__((ext_vector_type(8))) short bf16x8;

#define TOKENS 4096
#define DMODEL 1024
#define NEXP 32
#define ESIZE 512

// round-to-nearest-even f32 -> bf16 bits
__device__ __forceinline__ u16 f2b(float f) {
  union { float f; u32 u; } v; v.f = f;
  u32 u = v.u;
  return (u16)((u + 0x7fffu + ((u >> 16) & 1u)) >> 16);
}

// swizzled LDS address (in shorts) for a [rows][64] bf16 tile, row stride 72 shorts (144B).
// XOR the 16B-granule index with (row>>2) to spread banks for both transpose-writes and frag-reads.
__device__ __forceinline__ int swz(int row, int kk) {
  return row * 72 + ((((kk >> 3) ^ (row >> 2)) & 7) << 3) + (kk & 7);
}

// ---------------- routing: sel_raw, softmax probs, top-4, buckets ----------------
__global__ __launch_bounds__(64) void k_route(
    const float* __restrict__ x, const float* __restrict__ es,
    float* __restrict__ probs, float* __restrict__ selval,
    int* __restrict__ cnt, int* __restrict__ bucket)
{
  int t = blockIdx.x;
  int lane = threadIdx.x;
  int e = lane & 31, half = lane >> 5;
  const float4* xr = (const float4*)(x + (size_t)t * DMODEL + half * 512);
  const float4* er = (const float4*)(es + (size_t)e * DMODEL + half * 512);
  float acc = 0.f;
#pragma unroll 8
  for (int i = 0; i < 128; ++i) {
    float4 a = xr[i]; float4 b = er[i];
    acc += a.x * b.x + a.y * b.y + a.z * b.z + a.w * b.w;
  }
  float r = acc + __shfl_xor(acc, 32);  // full dot; duplicated across halves

  // softmax over the 32 experts (lanes 0-31 and 32-63 hold identical copies)
  float m = r;
#pragma unroll
  for (int mk = 16; mk; mk >>= 1) m = fmaxf(m, __shfl_xor(m, mk));
  float sx = __expf(r - m);
#pragma unroll
  for (int mk = 16; mk; mk >>= 1) sx += __shfl_xor(sx, mk);
  float lse = m + __logf(sx);
  float p = __expf(r - lse);
  if (!half) probs[(size_t)e * TOKENS + t] = p;

  // top-4 by raw logit (sigmoid is monotone); ties -> lower index (matches top_k)
  float v = r;
#pragma unroll
  for (int it = 0; it < 4; ++it) {
    float bv = v; int bi = e;
#pragma unroll
    for (int mk = 16; mk; mk >>= 1) {
      float ov = __shfl_xor(bv, mk); int oi = __shfl_xor(bi, mk);
      if (ov > bv || (ov == bv && oi < bi)) { bv = ov; bi = oi; }
    }
    if (lane == it) {
      float g = 1.f / (1.f + __expf(-bv));
      selval[t * 4 + it] = g;
      int pos = atomicAdd(&cnt[bi], 1);
      bucket[bi * TOKENS + pos] = t * 4 + it;  // encode (token, head-slot)
    }
    if (e == bi) v = -3.0e38f;
  }
}

// ---------------- entropy regularizer ----------------
__global__ __launch_bounds__(1024) void k_reg(const float* __restrict__ probs,
                                              float* __restrict__ out_reg)
{
  __shared__ float part[NEXP][33];
  int tid = threadIdx.x;
  int e = tid >> 5, c = tid & 31;
  const float* col = probs + (size_t)e * TOKENS + c * 128;
  float s = 0.f;
#pragma unroll 8
  for (int i = 0; i < 128; ++i) s += col[i];
  part[e][c] = s;
  __syncthreads();
  if (tid < NEXP) {
    float S = 0.f;
#pragma unroll
    for (int i = 0; i < 32; ++i) S += part[tid][i];
    float Pm = S * (1.0f / TOKENS);   // exp(lm)
    float lm = __logf(Pm);
    float rp = lm * Pm;
#pragma unroll
    for (int mk = 16; mk; mk >>= 1) rp += __shfl_xor(rp, mk);
    if (tid == 0) *out_reg = rp;
  }
}

// ---------------- up-projection: scores[slot][h] = relu(x[t] @ keys[e]) * gate ----------------
__global__ __launch_bounds__(256) void k_up(
    const float* __restrict__ x, const float* __restrict__ keys,
    const float* __restrict__ selval, const int* __restrict__ cnt,
    const int* __restrict__ bucket, u16* __restrict__ scores)
{
  int e = blockIdx.x >> 6, mt = blockIdx.x & 63;
  int ne = cnt[e];
  int row0 = mt << 6;
  if (row0 >= ne) return;
  int rem = ne - row0; if (rem > 64) rem = 64;
  int nb0 = blockIdx.y << 7;  // 128-wide slice of ESIZE
  int tid = threadIdx.x;

  __shared__ __align__(16) u16 Al[64 * 72];
  __shared__ __align__(16) u16 Bl[128 * 72];
  __shared__ int slot_l[64];
  __shared__ float gate_l[64];

  if (tid < 64) {
    int slot = -1; float g = 0.f;
    if (tid < rem) { slot = bucket[e * TOKENS + row0 + tid]; g = selval[slot]; }
    slot_l[tid] = slot; gate_l[tid] = g;
  }
  __syncthreads();

  int arow = tid >> 2;
  int ac0 = (tid & 3) << 4;
  int aslot = slot_l[arow];
  const float* xrow = (aslot >= 0) ? (x + (size_t)(aslot >> 2) * DMODEL) : nullptr;

  int bn4 = tid & 31;           // n block of 4
  int bkb = (tid >> 5) << 3;    // k base (8 rows)
  const float* kb = keys + (size_t)e * DMODEL * ESIZE + nb0 + (bn4 << 2);

  int lane = tid & 63, w = tid >> 6;
  int wm = (w >> 1) << 5, wn = (w & 1) << 6;
  f32x4 zero = {0.f, 0.f, 0.f, 0.f};
  f32x4 acc[2][4];
#pragma unroll
  for (int i = 0; i < 2; ++i)
#pragma unroll
    for (int j = 0; j < 4; ++j) acc[i][j] = zero;

  for (int k0 = 0; k0 < DMODEL; k0 += 64) {
    // A: gathered x rows, f32 -> bf16
    u32 apk[8];
    if (xrow) {
      const float4* p = (const float4*)(xrow + k0 + ac0);
#pragma unroll
      for (int rr = 0; rr < 4; ++rr) {
        float4 vv = p[rr];
        apk[rr * 2 + 0] = (u32)f2b(vv.x) | ((u32)f2b(vv.y) << 16);
        apk[rr * 2 + 1] = (u32)f2b(vv.z) | ((u32)f2b(vv.w) << 16);
      }
    } else {
#pragma unroll
      for (int rr = 0; rr < 8; ++rr) apk[rr] = 0;
    }
    // B: keys slice, read coalesced along n, repack in-thread to k-contiguous
    float bcol[4][8];
#pragma unroll
    for (int rr = 0; rr < 8; ++rr) {
      float4 vv = *(const float4*)(kb + (size_t)(k0 + bkb + rr) * ESIZE);
      bcol[0][rr] = vv.x; bcol[1][rr] = vv.y; bcol[2][rr] = vv.z; bcol[3][rr] = vv.w;
    }
    __syncthreads();  // previous iteration's reads done
    *(uint4*)&Al[swz(arow, ac0)]     = make_uint4(apk[0], apk[1], apk[2], apk[3]);
    *(uint4*)&Al[swz(arow, ac0 + 8)] = make_uint4(apk[4], apk[5], apk[6], apk[7]);
#pragma unroll
    for (int j = 0; j < 4; ++j) {
      u32 q0 = (u32)f2b(bcol[j][0]) | ((u32)f2b(bcol[j][1]) << 16);
      u32 q1 = (u32)f2b(bcol[j][2]) | ((u32)f2b(bcol[j][3]) << 16);
      u32 q2 = (u32)f2b(bcol[j][4]) | ((u32)f2b(bcol[j][5]) << 16);
      u32 q3 = (u32)f2b(bcol[j][6]) | ((u32)f2b(bcol[j][7]) << 16);
      *(uint4*)&Bl[swz((bn4 << 2) + j, bkb)] = make_uint4(q0, q1, q2, q3);
    }
    __syncthreads();
#pragma unroll
    for (int kh = 0; kh < 2; ++kh) {
      int kk = (kh << 5) + ((lane >> 4) << 3);
      bf16x8 af[2], bf[4];
#pragma unroll
      for (int mi = 0; mi < 2; ++mi)
        af[mi] = *(const bf16x8*)&Al[swz(wm + (mi << 4) + (lane & 15), kk)];
#pragma unroll
      for (int ni = 0; ni < 4; ++ni)
        bf[ni] = *(const bf16x8*)&Bl[swz(wn + (ni << 4) + (lane & 15), kk)];
#pragma unroll
      for (int mi = 0; mi < 2; ++mi)
#pragma unroll
        for (int ni = 0; ni < 4; ++ni)
          acc[mi][ni] = __builtin_amdgcn_mfma_f32_16x16x32_bf16(af[mi], bf[ni], acc[mi][ni], 0, 0, 0);
    }
  }

#pragma unroll
  for (int mi = 0; mi < 2; ++mi)
#pragma unroll
    for (int ni = 0; ni < 4; ++ni)
#pragma unroll
      for (int rr = 0; rr < 4; ++rr) {
        int row = wm + (mi << 4) + ((lane >> 4) << 2) + rr;
        int col = wn + (ni << 4) + (lane & 15);
        if (row < rem) {
          float vv = fmaxf(acc[mi][ni][rr], 0.f) * gate_l[row];
          scores[(size_t)slot_l[row] * ESIZE + nb0 + col] = f2b(vv);
        }
      }
}

// ---------------- down-projection: out[t] += scores[slot] @ values[e] ----------------
__global__ __launch_bounds__(256) void k_down(
    const u16* __restrict__ scores, const float* __restrict__ values,
    const int* __restrict__ cnt, const int* __restrict__ bucket,
    float* __restrict__ out)
{
  int e = blockIdx.x >> 6, mt = blockIdx.x & 63;
  int ne = cnt[e];
  int row0 = mt << 6;
  if (row0 >= ne) return;
  int rem = ne - row0; if (rem > 64) rem = 64;
  int nb0 = blockIdx.y << 7;  // 128-wide slice of DMODEL
  int tid = threadIdx.x;

  __shared__ __align__(16) u16 Al[64 * 72];
  __shared__ __align__(16) u16 Bl[128 * 72];
  __shared__ int slot_l[64];

  if (tid < 64) {
    int slot = -1;
    if (tid < rem) slot = bucket[e * TOKENS + row0 + tid];
    slot_l[tid] = slot;
  }
  __syncthreads();

  int arow = tid >> 2;
  int ac0 = (tid & 3) << 4;
  int aslot = slot_l[arow];
  const u16* srow = (aslot >= 0) ? (scores + (size_t)aslot * ESIZE) : nullptr;

  int bn4 = tid & 31;
  int bkb = (tid >> 5) << 3;
  const float* vb = values + (size_t)e * ESIZE * DMODEL + nb0 + (bn4 << 2);

  int lane = tid & 63, w = tid >> 6;
  int wm = (w >> 1) << 5, wn = (w & 1) << 6;
  f32x4 zero = {0.f, 0.f, 0.f, 0.f};
  f32x4 acc[2][4];
#pragma unroll
  for (int i = 0; i < 2; ++i)
#pragma unroll
    for (int j = 0; j < 4; ++j) acc[i][j] = zero;

  for (int k0 = 0; k0 < ESIZE; k0 += 64) {
    uint4 a0 = make_uint4(0, 0, 0, 0), a1 = make_uint4(0, 0, 0, 0);
    if (srow) {
      a0 = *(const uint4*)(srow + k0 + ac0);
      a1 = *(const uint4*)(srow + k0 + ac0 + 8);
    }
    float bcol[4][8];
#pragma unroll
    for (int rr = 0; rr < 8; ++rr) {
      float4 vv = *(const float4*)(vb + (size_t)(k0 + bkb + rr) * DMODEL);
      bcol[0][rr] = vv.x; bcol[1][rr] = vv.y; bcol[2][rr] = vv.z; bcol[3][rr] = vv.w;
    }
    __syncthreads();
    *(uint4*)&Al[swz(arow, ac0)]     = a0;
    *(uint4*)&Al[swz(arow, ac0 + 8)] = a1;
#pragma unroll
    for (int j = 0; j < 4; ++j) {
      u32 q0 = (u32)f2b(bcol[j][0]) | ((u32)f2b(bcol[j][1]) << 16);
      u32 q1 = (u32)f2b(bcol[j][2]) | ((u32)f2b(bcol[j][3]) << 16);
      u32 q2 = (u32)f2b(bcol[j][4]) | ((u32)f2b(bcol[j][5]) << 16);
      u32 q3 = (u32)f2b(bcol[j][6]) | ((u32)f2b(bcol[j][7]) << 16);
      *(uint4*)&Bl[swz((bn4 << 2) + j, bkb)] = make_uint4(q0, q1, q2, q3);
    }
    __syncthreads();
#pragma unroll
    for (int kh = 0; kh < 2; ++kh) {
      int kk = (kh << 5) + ((lane >> 4) << 3);
      bf16x8 af[2], bf[4];
#pragma unroll
      for (int mi = 0; mi < 2; ++mi)
        af[mi] = *(const bf16x8*)&Al[swz(wm + (mi << 4) + (lane & 15), kk)];
#pragma unroll
      for (int ni = 0; ni < 4; ++ni)
        bf[ni] = *(const bf16x8*)&Bl[swz(wn + (ni << 4) + (lane & 15), kk)];
#pragma unroll
      for (int mi = 0; mi < 2; ++mi)
#pragma unroll
        for (int ni = 0; ni < 4; ++ni)
          acc[mi][ni] = __builtin_amdgcn_mfma_f32_16x16x32_bf16(af[mi], bf[ni], acc[mi][ni], 0, 0, 0);
    }
  }

#pragma unroll
  for (int mi = 0; mi < 2; ++mi)
#pragma unroll
    for (int ni = 0; ni < 4; ++ni)
#pragma unroll
      for (int rr = 0; rr < 4; ++rr) {
        int row = wm + (mi << 4) + ((lane >> 4) << 2) + rr;
        int col = wn + (ni << 4) + (lane & 15);
        if (row < rem) {
          int t = slot_l[row] >> 2;
          atomicAdd(&out[(size_t)t * DMODEL + nb0 + col], acc[mi][ni][rr]);
        }
      }
}

extern "C" void kernel_launch(void* const* d_in, const int* in_sizes, int n_in,
                              void* d_out, int out_size, void* d_ws, size_t ws_size,
                              hipStream_t stream) {
  (void)in_sizes; (void)n_in; (void)ws_size;
  const float* x      = (const float*)d_in[0];
  const float* keys   = (const float*)d_in[1];
  const float* values = (const float*)d_in[2];
  const float* es     = (const float*)d_in[3];
  float* out = (float*)d_out;

  char* W = (char*)d_ws;
  int*   cnt    = (int*)W;                         // 128 B
  float* selval = (float*)(W + 1024);              // 64 KB
  int*   bucket = (int*)(W + 128 * 1024);          // 512 KB
  float* probs  = (float*)(W + 704 * 1024);        // 512 KB
  u16*   scores = (u16*)(W + 2u * 1024 * 1024);    // 16 MB (bf16 [16384][512])

  hipMemsetAsync(cnt, 0, 128, stream);
  hipMemsetAsync(d_out, 0, (size_t)out_size * sizeof(float), stream);
  k_route<<<TOKENS, 64, 0, stream>>>(x, es, probs, selval, cnt, bucket);
  k_reg<<<1, 1024, 0, stream>>>(probs, out + (size_t)out_size - 1);
  k_up<<<dim3(NEXP * 64, 4), 256, 0, stream>>>(x, keys, selval, cnt, bucket, scores);
  k_down<<<dim3(NEXP * 64, 8), 256, 0, stream>>>(scores, values, cnt, bucket, out);
}

// Round 2
// 359.224 us; speedup vs baseline: 1.4548x; 1.4548x over previous
//
#include <hip/hip_runtime.h>
#include <hip/hip_bf16.h>

typedef unsigned short u16;
typedef unsigned int u32;
typedef __attribute__((ext_vector_type(4))) float f32x4;
typedef __attribute__((ext_vector_type(8))) short bf16x8;

#define TOKENS 4096
#define DMODEL 1024
#define NEXP 32
#define ESIZE 512

// round-to-nearest-even f32 -> bf16 bits (epilogue scalar use)
__device__ __forceinline__ u16 f2b(float f) {
  union { float f; u32 u; } v; v.f = f;
  u32 u = v.u;
  return (u16)((u + 0x7fffu + ((u >> 16) & 1u)) >> 16);
}

// packed f32x2 -> bf16x2 (v_cvt_pk_bf16_f32 via compiler)
__device__ __forceinline__ u32 pk2(float a, float b) {
  union { __hip_bfloat162 h; u32 u; } v;
  v.h = __float22bfloat162_rn(make_float2(a, b));
  return v.u;
}

// swizzled LDS address (in shorts) for a [rows][64] bf16 tile, row stride 72 shorts.
// XOR 16B-granule index with (row>>2) to spread banks for transpose-writes and frag-reads.
__device__ __forceinline__ int swz(int row, int kk) {
  return row * 72 + ((((kk >> 3) ^ (row >> 2)) & 7) << 3) + (kk & 7);
}

// ---------------- routing: logits, softmax colsum, top-4, buckets ----------------
__global__ __launch_bounds__(256) void k_route(
    const float* __restrict__ x, const float* __restrict__ es,
    float* __restrict__ selval, int* __restrict__ cnt, int* __restrict__ bucket,
    float* __restrict__ colsum)
{
  __shared__ float ps[4][32];
  int tid = threadIdx.x;
  int w = tid >> 6, lane = tid & 63;
  int t = (blockIdx.x << 2) + w;
  int e = lane & 31, half = lane >> 5;
  const float4* xr = (const float4*)(x + (size_t)t * DMODEL + half * 512);
  const float4* er = (const float4*)(es + (size_t)e * DMODEL + half * 512);
  float acc = 0.f;
#pragma unroll 8
  for (int i = 0; i < 128; ++i) {
    float4 a = xr[i]; float4 b = er[i];
    acc += a.x * b.x + a.y * b.y + a.z * b.z + a.w * b.w;
  }
  float r = acc + __shfl_xor(acc, 32);  // full dot; duplicated across halves

  // softmax over 32 experts (both 32-lane halves hold identical copies)
  float m = r;
#pragma unroll
  for (int mk = 16; mk; mk >>= 1) m = fmaxf(m, __shfl_xor(m, mk));
  float sx = __expf(r - m);
#pragma unroll
  for (int mk = 16; mk; mk >>= 1) sx += __shfl_xor(sx, mk);
  float p = __expf(r - (m + __logf(sx)));
  if (!half) ps[w][e] = p;

  // top-4 by raw logit (sigmoid monotone); ties -> lower index
  float v = r;
#pragma unroll
  for (int it = 0; it < 4; ++it) {
    float bv = v; int bi = e;
#pragma unroll
    for (int mk = 16; mk; mk >>= 1) {
      float ov = __shfl_xor(bv, mk); int oi = __shfl_xor(bi, mk);
      if (ov > bv || (ov == bv && oi < bi)) { bv = ov; bi = oi; }
    }
    if (lane == it) {
      float g = 1.f / (1.f + __expf(-bv));
      selval[t * 4 + it] = g;
      int pos = atomicAdd(&cnt[bi], 1);
      bucket[bi * TOKENS + pos] = t * 4 + it;  // (token<<2)|head
    }
    if (e == bi) v = -3.0e38f;
  }
  __syncthreads();
  if (tid < 32)
    atomicAdd(&colsum[tid], ps[0][tid] + ps[1][tid] + ps[2][tid] + ps[3][tid]);
}

// ---------------- entropy regularizer from column sums ----------------
__global__ __launch_bounds__(64) void k_fin(const float* __restrict__ colsum,
                                            float* __restrict__ out_reg)
{
  int l = threadIdx.x;
  float rp = 0.f;
  if (l < 32) {
    float Pm = colsum[l] * (1.0f / TOKENS);
    rp = __logf(Pm) * Pm;
  }
#pragma unroll
  for (int mk = 16; mk; mk >>= 1) rp += __shfl_xor(rp, mk);
  if (l == 0) *out_reg = rp;
}

// ---------------- up-projection: scores[slot][h] = relu(x[t] @ keys[e]) * gate --------
// grid 512: pair = bid&127 -> (e = pair>>2, ns = pair&3), mz = bid>>7 (4-way m-split).
// Partners differ by 128 (== 0 mod 8) -> same XCD -> share B panel via L2.
__global__ __launch_bounds__(256, 2) void k_up(
    const float* __restrict__ x, const float* __restrict__ keys,
    const float* __restrict__ selval, const int* __restrict__ cnt,
    const int* __restrict__ bucket, u16* __restrict__ scores)
{
  int bid = blockIdx.x;
  int pair = bid & 127, mz = bid >> 7;
  int e = pair >> 2, ns = pair & 3;
  int ne = cnt[e];
  if ((mz << 7) >= ne) return;
  int nb0 = ns << 7;
  int tid = threadIdx.x;

  __shared__ __align__(16) u16 Abuf[2][128 * 72];
  __shared__ __align__(16) u16 Bbuf[2][128 * 72];
  __shared__ int slot_l[128];
  __shared__ float gate_l[128];

  const float* Kb = keys + (size_t)e * (DMODEL * ESIZE) + nb0;

  int arow = tid >> 1, ac0 = (tid & 1) << 5;   // 32 floats of one gathered row
  int bn = tid & 31, bk0 = (tid >> 5) << 3;    // 4 n-cols x 8 k-rows of B
  int lane = tid & 63, w = tid >> 6;
  int wm = (w >> 1) << 6, wn = (w & 1) << 6;   // wave tile 64x64

  for (int mt = mz; (mt << 7) < ne; mt += 4) {
    int row0 = mt << 7;
    int rem = ne - row0; if (rem > 128) rem = 128;
    __syncthreads();
    if (tid < 128) {
      int slot = -1; float g = 0.f;
      if (tid < rem) { slot = bucket[e * TOKENS + row0 + tid]; g = selval[slot]; }
      slot_l[tid] = slot; gate_l[tid] = g;
    }
    __syncthreads();

    int aslot = slot_l[arow];
    const float* xr = (aslot >= 0) ? (x + (size_t)(aslot >> 2) * DMODEL + ac0) : nullptr;
    const float* bp = Kb + (size_t)bk0 * ESIZE + (bn << 2);

    f32x4 acc[4][4];
#pragma unroll
    for (int i = 0; i < 4; ++i)
#pragma unroll
      for (int j = 0; j < 4; ++j) acc[i][j] = (f32x4){0.f, 0.f, 0.f, 0.f};

    float4 ar[8], br[8];
#define LOADA_UP(K) do { if (xr) { const float4* p_ = (const float4*)(xr + (K)); \
    _Pragma("unroll") for (int i_ = 0; i_ < 8; ++i_) ar[i_] = p_[i_]; } \
    else { _Pragma("unroll") for (int i_ = 0; i_ < 8; ++i_) ar[i_] = make_float4(0.f,0.f,0.f,0.f); } } while (0)
#define LOADB(K, LDB) do { const float* q_ = bp + (size_t)(K) * (LDB); \
    _Pragma("unroll") for (int r_ = 0; r_ < 8; ++r_) br[r_] = *(const float4*)(q_ + (size_t)r_ * (LDB)); } while (0)
#define CVTWR_A(NB) do { _Pragma("unroll") for (int g_ = 0; g_ < 4; ++g_) { \
    u32 q0_ = pk2(ar[2*g_].x, ar[2*g_].y),   q1_ = pk2(ar[2*g_].z, ar[2*g_].w); \
    u32 q2_ = pk2(ar[2*g_+1].x, ar[2*g_+1].y), q3_ = pk2(ar[2*g_+1].z, ar[2*g_+1].w); \
    *(uint4*)&Abuf[NB][swz(arow, ac0 + 8*g_)] = make_uint4(q0_,q1_,q2_,q3_); } } while (0)
#define CVTWR_B(NB) do { \
    { u32 q0_=pk2(br[0].x,br[1].x),q1_=pk2(br[2].x,br[3].x),q2_=pk2(br[4].x,br[5].x),q3_=pk2(br[6].x,br[7].x); \
      *(uint4*)&Bbuf[NB][swz((bn<<2)+0, bk0)] = make_uint4(q0_,q1_,q2_,q3_); } \
    { u32 q0_=pk2(br[0].y,br[1].y),q1_=pk2(br[2].y,br[3].y),q2_=pk2(br[4].y,br[5].y),q3_=pk2(br[6].y,br[7].y); \
      *(uint4*)&Bbuf[NB][swz((bn<<2)+1, bk0)] = make_uint4(q0_,q1_,q2_,q3_); } \
    { u32 q0_=pk2(br[0].z,br[1].z),q1_=pk2(br[2].z,br[3].z),q2_=pk2(br[4].z,br[5].z),q3_=pk2(br[6].z,br[7].z); \
      *(uint4*)&Bbuf[NB][swz((bn<<2)+2, bk0)] = make_uint4(q0_,q1_,q2_,q3_); } \
    { u32 q0_=pk2(br[0].w,br[1].w),q1_=pk2(br[2].w,br[3].w),q2_=pk2(br[4].w,br[5].w),q3_=pk2(br[6].w,br[7].w); \
      *(uint4*)&Bbuf[NB][swz((bn<<2)+3, bk0)] = make_uint4(q0_,q1_,q2_,q3_); } } while (0)
#define MFMA_PHASE(CUR) do { _Pragma("unroll") for (int kh_ = 0; kh_ < 2; ++kh_) { \
    int kk_ = (kh_ << 5) | ((lane >> 4) << 3); \
    bf16x8 af_[4], bf_[4]; \
    _Pragma("unroll") for (int mi_ = 0; mi_ < 4; ++mi_) \
      af_[mi_] = *(const bf16x8*)&Abuf[CUR][swz(wm + (mi_ << 4) + (lane & 15), kk_)]; \
    _Pragma("unroll") for (int ni_ = 0; ni_ < 4; ++ni_) \
      bf_[ni_] = *(const bf16x8*)&Bbuf[CUR][swz(wn + (ni_ << 4) + (lane & 15), kk_)]; \
    _Pragma("unroll") for (int mi_ = 0; mi_ < 4; ++mi_) \
      _Pragma("unroll") for (int ni_ = 0; ni_ < 4; ++ni_) \
        acc[mi_][ni_] = __builtin_amdgcn_mfma_f32_16x16x32_bf16(af_[mi_], bf_[ni_], acc[mi_][ni_], 0, 0, 0); \
  } } while (0)

    LOADA_UP(0); LOADB(0, ESIZE);
    CVTWR_A(0); CVTWR_B(0);
    __syncthreads();
    int cur = 0;
    for (int k0 = 0; k0 < DMODEL; k0 += 64) {
      bool late = (k0 + 64 >= DMODEL);
      if (!late) { LOADA_UP(k0 + 64); LOADB(k0 + 64, ESIZE); }
      MFMA_PHASE(cur);
      if (!late) { CVTWR_A(cur ^ 1); CVTWR_B(cur ^ 1); }
      __syncthreads();
      cur ^= 1;
    }

#pragma unroll
    for (int mi = 0; mi < 4; ++mi) {
      int rbase = wm + (mi << 4) + ((lane >> 4) << 2);
#pragma unroll
      for (int rr = 0; rr < 4; ++rr) {
        int r = rbase + rr;
        if (r < rem) {
          float g = gate_l[r];
          u16* so = scores + (size_t)slot_l[r] * ESIZE + nb0 + wn + (lane & 15);
#pragma unroll
          for (int ni = 0; ni < 4; ++ni)
            so[ni << 4] = f2b(fmaxf(acc[mi][ni][rr], 0.f) * g);
        }
      }
    }
#undef LOADA_UP
#undef LOADB
#undef CVTWR_A
#undef CVTWR_B
#undef MFMA_PHASE
  }
}

// ---------------- down-projection: out[t] += scores[slot] @ values[e] ----------------
// grid 512: pair = bid&255 -> (e = pair>>3, ns = pair&7), mz = bid>>8 (2-way m-split).
__global__ __launch_bounds__(256, 2) void k_down(
    const u16* __restrict__ scores, const float* __restrict__ values,
    const int* __restrict__ cnt, const int* __restrict__ bucket,
    float* __restrict__ out)
{
  int bid = blockIdx.x;
  int pair = bid & 255, mz = bid >> 8;
  int e = pair >> 3, ns = pair & 7;
  int ne = cnt[e];
  if ((mz << 7) >= ne) return;
  int nb0 = ns << 7;
  int tid = threadIdx.x;

  __shared__ __align__(16) u16 Abuf[2][128 * 72];
  __shared__ __align__(16) u16 Bbuf[2][128 * 72];
  __shared__ int slot_l[128];

  const float* Vb = values + (size_t)e * (ESIZE * DMODEL) + nb0;

  int arow = tid >> 1, ac0 = (tid & 1) << 5;   // 32 shorts of one scores row
  int bn = tid & 31, bk0 = (tid >> 5) << 3;
  int lane = tid & 63, w = tid >> 6;
  int wm = (w >> 1) << 6, wn = (w & 1) << 6;

  for (int mt = mz; (mt << 7) < ne; mt += 2) {
    int row0 = mt << 7;
    int rem = ne - row0; if (rem > 128) rem = 128;
    __syncthreads();
    if (tid < 128) {
      int slot = -1;
      if (tid < rem) slot = bucket[e * TOKENS + row0 + tid];
      slot_l[tid] = slot;
    }
    __syncthreads();

    int aslot = slot_l[arow];
    const u16* sr = (aslot >= 0) ? (scores + (size_t)aslot * ESIZE + ac0) : nullptr;
    const float* bp = Vb + (size_t)bk0 * DMODEL + (bn << 2);

    f32x4 acc[4][4];
#pragma unroll
    for (int i = 0; i < 4; ++i)
#pragma unroll
      for (int j = 0; j < 4; ++j) acc[i][j] = (f32x4){0.f, 0.f, 0.f, 0.f};

    uint4 a4[4]; float4 br[8];
#define LOADA_DN(K) do { if (sr) { const uint4* p_ = (const uint4*)(sr + (K)); \
    _Pragma("unroll") for (int i_ = 0; i_ < 4; ++i_) a4[i_] = p_[i_]; } \
    else { _Pragma("unroll") for (int i_ = 0; i_ < 4; ++i_) a4[i_] = make_uint4(0,0,0,0); } } while (0)
#define LOADB(K, LDB) do { const float* q_ = bp + (size_t)(K) * (LDB); \
    _Pragma("unroll") for (int r_ = 0; r_ < 8; ++r_) br[r_] = *(const float4*)(q_ + (size_t)r_ * (LDB)); } while (0)
#define WR_A(NB) do { _Pragma("unroll") for (int g_ = 0; g_ < 4; ++g_) \
    *(uint4*)&Abuf[NB][swz(arow, ac0 + 8*g_)] = a4[g_]; } while (0)
#define CVTWR_B(NB) do { \
    { u32 q0_=pk2(br[0].x,br[1].x),q1_=pk2(br[2].x,br[3].x),q2_=pk2(br[4].x,br[5].x),q3_=pk2(br[6].x,br[7].x); \
      *(uint4*)&Bbuf[NB][swz((bn<<2)+0, bk0)] = make_uint4(q0_,q1_,q2_,q3_); } \
    { u32 q0_=pk2(br[0].y,br[1].y),q1_=pk2(br[2].y,br[3].y),q2_=pk2(br[4].y,br[5].y),q3_=pk2(br[6].y,br[7].y); \
      *(uint4*)&Bbuf[NB][swz((bn<<2)+1, bk0)] = make_uint4(q0_,q1_,q2_,q3_); } \
    { u32 q0_=pk2(br[0].z,br[1].z),q1_=pk2(br[2].z,br[3].z),q2_=pk2(br[4].z,br[5].z),q3_=pk2(br[6].z,br[7].z); \
      *(uint4*)&Bbuf[NB][swz((bn<<2)+2, bk0)] = make_uint4(q0_,q1_,q2_,q3_); } \
    { u32 q0_=pk2(br[0].w,br[1].w),q1_=pk2(br[2].w,br[3].w),q2_=pk2(br[4].w,br[5].w),q3_=pk2(br[6].w,br[7].w); \
      *(uint4*)&Bbuf[NB][swz((bn<<2)+3, bk0)] = make_uint4(q0_,q1_,q2_,q3_); } } while (0)
#define MFMA_PHASE(CUR) do { _Pragma("unroll") for (int kh_ = 0; kh_ < 2; ++kh_) { \
    int kk_ = (kh_ << 5) | ((lane >> 4) << 3); \
    bf16x8 af_[4], bf_[4]; \
    _Pragma("unroll") for (int mi_ = 0; mi_ < 4; ++mi_) \
      af_[mi_] = *(const bf16x8*)&Abuf[CUR][swz(wm + (mi_ << 4) + (lane & 15), kk_)]; \
    _Pragma("unroll") for (int ni_ = 0; ni_ < 4; ++ni_) \
      bf_[ni_] = *(const bf16x8*)&Bbuf[CUR][swz(wn + (ni_ << 4) + (lane & 15), kk_)]; \
    _Pragma("unroll") for (int mi_ = 0; mi_ < 4; ++mi_) \
      _Pragma("unroll") for (int ni_ = 0; ni_ < 4; ++ni_) \
        acc[mi_][ni_] = __builtin_amdgcn_mfma_f32_16x16x32_bf16(af_[mi_], bf_[ni_], acc[mi_][ni_], 0, 0, 0); \
  } } while (0)

    LOADA_DN(0); LOADB(0, DMODEL);
    WR_A(0); CVTWR_B(0);
    __syncthreads();
    int cur = 0;
    for (int k0 = 0; k0 < ESIZE; k0 += 64) {
      bool late = (k0 + 64 >= ESIZE);
      if (!late) { LOADA_DN(k0 + 64); LOADB(k0 + 64, DMODEL); }
      MFMA_PHASE(cur);
      if (!late) { WR_A(cur ^ 1); CVTWR_B(cur ^ 1); }
      __syncthreads();
      cur ^= 1;
    }

#pragma unroll
    for (int mi = 0; mi < 4; ++mi) {
      int rbase = wm + (mi << 4) + ((lane >> 4) << 2);
#pragma unroll
      for (int rr = 0; rr < 4; ++rr) {
        int r = rbase + rr;
        if (r < rem) {
          int t = slot_l[r] >> 2;
          float* oo = out + (size_t)t * DMODEL + nb0 + wn + (lane & 15);
#pragma unroll
          for (int ni = 0; ni < 4; ++ni)
            atomicAdd(&oo[ni << 4], acc[mi][ni][rr]);
        }
      }
    }
#undef LOADA_DN
#undef LOADB
#undef WR_A
#undef CVTWR_B
#undef MFMA_PHASE
  }
}

extern "C" void kernel_launch(void* const* d_in, const int* in_sizes, int n_in,
                              void* d_out, int out_size, void* d_ws, size_t ws_size,
                              hipStream_t stream) {
  (void)in_sizes; (void)n_in; (void)ws_size;
  const float* x      = (const float*)d_in[0];
  const float* keys   = (const float*)d_in[1];
  const float* values = (const float*)d_in[2];
  const float* es     = (const float*)d_in[3];
  float* out = (float*)d_out;

  char* W = (char*)d_ws;
  int*   cnt    = (int*)W;                         // 128 B
  float* colsum = (float*)(W + 128);               // 128 B
  float* selval = (float*)(W + 1024);              // 64 KB
  int*   bucket = (int*)(W + 128 * 1024);          // 512 KB
  u16*   scores = (u16*)(W + 2u * 1024 * 1024);    // 16 MB bf16 [16384][512]

  hipMemsetAsync(W, 0, 512, stream);
  hipMemsetAsync(d_out, 0, (size_t)out_size * sizeof(float), stream);
  k_route<<<TOKENS / 4, 256, 0, stream>>>(x, es, selval, cnt, bucket, colsum);
  k_fin<<<1, 64, 0, stream>>>(colsum, out + (size_t)out_size - 1);
  k_up<<<512, 256, 0, stream>>>(x, keys, selval, cnt, bucket, scores);
  k_down<<<512, 256, 0, stream>>>(scores, values, cnt, bucket, out);
}

// Round 3
// 299.227 us; speedup vs baseline: 1.7465x; 1.2005x over previous
//
#include <hip/hip_runtime.h>
#include <hip/hip_bf16.h>

typedef unsigned short u16;
typedef unsigned int u32;
typedef __attribute__((ext_vector_type(4))) float f32x4;
typedef __attribute__((ext_vector_type(8))) short bf16x8;

#define TOKENS 4096
#define DMODEL 1024
#define NEXP 32
#define ESIZE 512

// round-to-nearest-even f32 -> bf16 bits (epilogue scalar use)
__device__ __forceinline__ u16 f2b(float f) {
  union { float f; u32 u; } v; v.f = f;
  u32 u = v.u;
  return (u16)((u + 0x7fffu + ((u >> 16) & 1u)) >> 16);
}

// packed f32x2 -> bf16x2 (v_cvt_pk_bf16_f32 via compiler)
__device__ __forceinline__ u32 pk2(float a, float b) {
  union { __hip_bfloat162 h; u32 u; } v;
  v.h = __float22bfloat162_rn(make_float2(a, b));
  return v.u;
}

__device__ __forceinline__ float blo(u32 w) { union { u32 u; float f; } v; v.u = w << 16; return v.f; }
__device__ __forceinline__ float bhi(u32 w) { union { u32 u; float f; } v; v.u = w & 0xffff0000u; return v.f; }

// swizzled LDS address (in shorts) for a [rows][64] bf16 tile, row stride 72 shorts.
__device__ __forceinline__ int swz(int row, int kk) {
  return row * 72 + ((((kk >> 3) ^ (row >> 2)) & 7) << 3) + (kk & 7);
}

// ---------------- routing: logits, top-4, gates, softmax block-partials (NO atomics) ----
__global__ __launch_bounds__(256) void k_route(
    const float* __restrict__ x, const float* __restrict__ es,
    float* __restrict__ selval, u32* __restrict__ selpk,
    float* __restrict__ blockpart)
{
  __shared__ float ps[4][32];
  int tid = threadIdx.x;
  int w = tid >> 6, lane = tid & 63;
  int t = (blockIdx.x << 2) + w;
  int e = lane & 31, half = lane >> 5;
  const float4* xr = (const float4*)(x + (size_t)t * DMODEL + half * 512);
  const float4* er = (const float4*)(es + (size_t)e * DMODEL + half * 512);
  float acc = 0.f;
#pragma unroll 8
  for (int i = 0; i < 128; ++i) {
    float4 a = xr[i]; float4 b = er[i];
    acc += a.x * b.x + a.y * b.y + a.z * b.z + a.w * b.w;
  }
  float r = acc + __shfl_xor(acc, 32);  // full dot; duplicated across halves

  // softmax over 32 experts (both halves identical)
  float m = r;
#pragma unroll
  for (int mk = 16; mk; mk >>= 1) m = fmaxf(m, __shfl_xor(m, mk));
  float sx = __expf(r - m);
#pragma unroll
  for (int mk = 16; mk; mk >>= 1) sx += __shfl_xor(sx, mk);
  float p = __expf(r - (m + __logf(sx)));
  if (!half) ps[w][e] = p;

  // top-4 by raw logit (sigmoid monotone); ties -> lower index
  u32 packed = 0;
  float v = r;
#pragma unroll
  for (int it = 0; it < 4; ++it) {
    float bv = v; int bi = e;
#pragma unroll
    for (int mk = 16; mk; mk >>= 1) {
      float ov = __shfl_xor(bv, mk); int oi = __shfl_xor(bi, mk);
      if (ov > bv || (ov == bv && oi < bi)) { bv = ov; bi = oi; }
    }
    packed |= (u32)bi << (8 * it);
    if (lane == it) selval[t * 4 + it] = 1.f / (1.f + __expf(-bv));
    if (e == bi) v = -3.0e38f;
  }
  if (lane == 0) selpk[t] = packed;
  __syncthreads();
  if (tid < 32)
    blockpart[blockIdx.x * 32 + tid] = ps[0][tid] + ps[1][tid] + ps[2][tid] + ps[3][tid];
}

// ---------------- bucket build: single block, LDS histogram ----------------
__global__ __launch_bounds__(1024) void k_count(
    const u32* __restrict__ selpk, int* __restrict__ cnt, int* __restrict__ bucket)
{
  __shared__ int cl[32];
  int tid = threadIdx.x;
  if (tid < 32) cl[tid] = 0;
  __syncthreads();
  int ex[16], pos[16];
#pragma unroll
  for (int j = 0; j < 4; ++j) {
    int t = tid + (j << 10);
    u32 pk = selpk[t];
#pragma unroll
    for (int h = 0; h < 4; ++h) {
      int e = (pk >> (8 * h)) & 0xff;
      ex[j * 4 + h] = e;
      pos[j * 4 + h] = atomicAdd(&cl[e], 1);
    }
  }
#pragma unroll
  for (int j = 0; j < 4; ++j) {
    int t = tid + (j << 10);
#pragma unroll
    for (int h = 0; h < 4; ++h)
      bucket[ex[j * 4 + h] * TOKENS + pos[j * 4 + h]] = (t << 2) | h;
  }
  __syncthreads();
  if (tid < 32) cnt[tid] = cl[tid];
}

// ---------------- entropy regularizer from block partials ----------------
__global__ __launch_bounds__(256) void k_fin(const float* __restrict__ blockpart,
                                             float* __restrict__ out_reg)
{
  __shared__ float part[8][32];
  int tid = threadIdx.x;
  int e = tid & 31, c = tid >> 5;
  float s = 0.f;
  for (int b = c; b < 1024; b += 8) s += blockpart[b * 32 + e];
  part[c][e] = s;
  __syncthreads();
  if (tid < 32) {
    float S = 0.f;
#pragma unroll
    for (int i = 0; i < 8; ++i) S += part[i][tid];
    float Pm = S * (1.0f / TOKENS);
    float rp = __logf(Pm) * Pm;
#pragma unroll
    for (int mk = 16; mk; mk >>= 1) rp += __shfl_xor(rp, mk);
    if (tid == 0) *out_reg = rp;
  }
}

// ---------------- up-projection: scores[slot][h] = relu(x[t] @ keys[e]) * gate --------
__global__ __launch_bounds__(256, 2) void k_up(
    const float* __restrict__ x, const float* __restrict__ keys,
    const float* __restrict__ selval, const int* __restrict__ cnt,
    const int* __restrict__ bucket, u16* __restrict__ scores)
{
  int bid = blockIdx.x;
  int pair = bid & 127, mz = bid >> 7;
  int e = pair >> 2, ns = pair & 3;
  int ne = cnt[e];
  if ((mz << 7) >= ne) return;
  int nb0 = ns << 7;
  int tid = threadIdx.x;

  __shared__ __align__(16) u16 Abuf[2][128 * 72];
  __shared__ __align__(16) u16 Bbuf[2][128 * 72];
  __shared__ int slot_l[128];
  __shared__ float gate_l[128];

  const float* Kb = keys + (size_t)e * (DMODEL * ESIZE) + nb0;

  int arow = tid >> 1, ac0 = (tid & 1) << 5;
  int bn = tid & 31, bk0 = (tid >> 5) << 3;
  int lane = tid & 63, w = tid >> 6;
  int wm = (w >> 1) << 6, wn = (w & 1) << 6;

  for (int mt = mz; (mt << 7) < ne; mt += 4) {
    int row0 = mt << 7;
    int rem = ne - row0; if (rem > 128) rem = 128;
    __syncthreads();
    if (tid < 128) {
      int slot = -1; float g = 0.f;
      if (tid < rem) { slot = bucket[e * TOKENS + row0 + tid]; g = selval[slot]; }
      slot_l[tid] = slot; gate_l[tid] = g;
    }
    __syncthreads();

    int aslot = slot_l[arow];
    const float* xr = (aslot >= 0) ? (x + (size_t)(aslot >> 2) * DMODEL + ac0) : nullptr;
    const float* bp = Kb + (size_t)bk0 * ESIZE + (bn << 2);

    f32x4 acc[4][4];
#pragma unroll
    for (int i = 0; i < 4; ++i)
#pragma unroll
      for (int j = 0; j < 4; ++j) acc[i][j] = (f32x4){0.f, 0.f, 0.f, 0.f};

    float4 ar[8], br[8];
#define LOADA_UP(K) do { if (xr) { const float4* p_ = (const float4*)(xr + (K)); \
    _Pragma("unroll") for (int i_ = 0; i_ < 8; ++i_) ar[i_] = p_[i_]; } \
    else { _Pragma("unroll") for (int i_ = 0; i_ < 8; ++i_) ar[i_] = make_float4(0.f,0.f,0.f,0.f); } } while (0)
#define LOADB(K, LDB) do { const float* q_ = bp + (size_t)(K) * (LDB); \
    _Pragma("unroll") for (int r_ = 0; r_ < 8; ++r_) br[r_] = *(const float4*)(q_ + (size_t)r_ * (LDB)); } while (0)
#define CVTWR_A(NB) do { _Pragma("unroll") for (int g_ = 0; g_ < 4; ++g_) { \
    u32 q0_ = pk2(ar[2*g_].x, ar[2*g_].y),   q1_ = pk2(ar[2*g_].z, ar[2*g_].w); \
    u32 q2_ = pk2(ar[2*g_+1].x, ar[2*g_+1].y), q3_ = pk2(ar[2*g_+1].z, ar[2*g_+1].w); \
    *(uint4*)&Abuf[NB][swz(arow, ac0 + 8*g_)] = make_uint4(q0_,q1_,q2_,q3_); } } while (0)
#define CVTWR_B(NB) do { \
    { u32 q0_=pk2(br[0].x,br[1].x),q1_=pk2(br[2].x,br[3].x),q2_=pk2(br[4].x,br[5].x),q3_=pk2(br[6].x,br[7].x); \
      *(uint4*)&Bbuf[NB][swz((bn<<2)+0, bk0)] = make_uint4(q0_,q1_,q2_,q3_); } \
    { u32 q0_=pk2(br[0].y,br[1].y),q1_=pk2(br[2].y,br[3].y),q2_=pk2(br[4].y,br[5].y),q3_=pk2(br[6].y,br[7].y); \
      *(uint4*)&Bbuf[NB][swz((bn<<2)+1, bk0)] = make_uint4(q0_,q1_,q2_,q3_); } \
    { u32 q0_=pk2(br[0].z,br[1].z),q1_=pk2(br[2].z,br[3].z),q2_=pk2(br[4].z,br[5].z),q3_=pk2(br[6].z,br[7].z); \
      *(uint4*)&Bbuf[NB][swz((bn<<2)+2, bk0)] = make_uint4(q0_,q1_,q2_,q3_); } \
    { u32 q0_=pk2(br[0].w,br[1].w),q1_=pk2(br[2].w,br[3].w),q2_=pk2(br[4].w,br[5].w),q3_=pk2(br[6].w,br[7].w); \
      *(uint4*)&Bbuf[NB][swz((bn<<2)+3, bk0)] = make_uint4(q0_,q1_,q2_,q3_); } } while (0)
#define MFMA_PHASE(CUR) do { _Pragma("unroll") for (int kh_ = 0; kh_ < 2; ++kh_) { \
    int kk_ = (kh_ << 5) | ((lane >> 4) << 3); \
    bf16x8 af_[4], bf_[4]; \
    _Pragma("unroll") for (int mi_ = 0; mi_ < 4; ++mi_) \
      af_[mi_] = *(const bf16x8*)&Abuf[CUR][swz(wm + (mi_ << 4) + (lane & 15), kk_)]; \
    _Pragma("unroll") for (int ni_ = 0; ni_ < 4; ++ni_) \
      bf_[ni_] = *(const bf16x8*)&Bbuf[CUR][swz(wn + (ni_ << 4) + (lane & 15), kk_)]; \
    _Pragma("unroll") for (int mi_ = 0; mi_ < 4; ++mi_) \
      _Pragma("unroll") for (int ni_ = 0; ni_ < 4; ++ni_) \
        acc[mi_][ni_] = __builtin_amdgcn_mfma_f32_16x16x32_bf16(af_[mi_], bf_[ni_], acc[mi_][ni_], 0, 0, 0); \
  } } while (0)

    LOADA_UP(0); LOADB(0, ESIZE);
    CVTWR_A(0); CVTWR_B(0);
    __syncthreads();
    int cur = 0;
    for (int k0 = 0; k0 < DMODEL; k0 += 64) {
      bool late = (k0 + 64 >= DMODEL);
      if (!late) { LOADA_UP(k0 + 64); LOADB(k0 + 64, ESIZE); }
      MFMA_PHASE(cur);
      if (!late) { CVTWR_A(cur ^ 1); CVTWR_B(cur ^ 1); }
      __syncthreads();
      cur ^= 1;
    }

#pragma unroll
    for (int mi = 0; mi < 4; ++mi) {
      int rbase = wm + (mi << 4) + ((lane >> 4) << 2);
#pragma unroll
      for (int rr = 0; rr < 4; ++rr) {
        int r = rbase + rr;
        if (r < rem) {
          float g = gate_l[r];
          u16* so = scores + (size_t)slot_l[r] * ESIZE + nb0 + wn + (lane & 15);
#pragma unroll
          for (int ni = 0; ni < 4; ++ni)
            so[ni << 4] = f2b(fmaxf(acc[mi][ni][rr], 0.f) * g);
        }
      }
    }
#undef LOADA_UP
#undef LOADB
#undef CVTWR_A
#undef CVTWR_B
#undef MFMA_PHASE
  }
}

// ---------------- down-projection: stage[slot] = scores[slot] @ values[e] ----------------
__global__ __launch_bounds__(256, 2) void k_down(
    const u16* __restrict__ scores, const float* __restrict__ values,
    const int* __restrict__ cnt, const int* __restrict__ bucket,
    u16* __restrict__ stage, float* __restrict__ out)
{
  int bid = blockIdx.x;
  int pair = bid & 255, mz = bid >> 8;
  int e = pair >> 3, ns = pair & 7;
  int ne = cnt[e];
  if ((mz << 7) >= ne) return;
  int nb0 = ns << 7;
  int tid = threadIdx.x;

  __shared__ __align__(16) u16 Abuf[2][128 * 72];
  __shared__ __align__(16) u16 Bbuf[2][128 * 72];
  __shared__ int slot_l[128];

  const float* Vb = values + (size_t)e * (ESIZE * DMODEL) + nb0;

  int arow = tid >> 1, ac0 = (tid & 1) << 5;
  int bn = tid & 31, bk0 = (tid >> 5) << 3;
  int lane = tid & 63, w = tid >> 6;
  int wm = (w >> 1) << 6, wn = (w & 1) << 6;

  for (int mt = mz; (mt << 7) < ne; mt += 2) {
    int row0 = mt << 7;
    int rem = ne - row0; if (rem > 128) rem = 128;
    __syncthreads();
    if (tid < 128) {
      int slot = -1;
      if (tid < rem) slot = bucket[e * TOKENS + row0 + tid];
      slot_l[tid] = slot;
    }
    __syncthreads();

    int aslot = slot_l[arow];
    const u16* sr = (aslot >= 0) ? (scores + (size_t)aslot * ESIZE + ac0) : nullptr;
    const float* bp = Vb + (size_t)bk0 * DMODEL + (bn << 2);

    f32x4 acc[4][4];
#pragma unroll
    for (int i = 0; i < 4; ++i)
#pragma unroll
      for (int j = 0; j < 4; ++j) acc[i][j] = (f32x4){0.f, 0.f, 0.f, 0.f};

    uint4 a4[4]; float4 br[8];
#define LOADA_DN(K) do { if (sr) { const uint4* p_ = (const uint4*)(sr + (K)); \
    _Pragma("unroll") for (int i_ = 0; i_ < 4; ++i_) a4[i_] = p_[i_]; } \
    else { _Pragma("unroll") for (int i_ = 0; i_ < 4; ++i_) a4[i_] = make_uint4(0,0,0,0); } } while (0)
#define LOADB(K, LDB) do { const float* q_ = bp + (size_t)(K) * (LDB); \
    _Pragma("unroll") for (int r_ = 0; r_ < 8; ++r_) br[r_] = *(const float4*)(q_ + (size_t)r_ * (LDB)); } while (0)
#define WR_A(NB) do { _Pragma("unroll") for (int g_ = 0; g_ < 4; ++g_) \
    *(uint4*)&Abuf[NB][swz(arow, ac0 + 8*g_)] = a4[g_]; } while (0)
#define CVTWR_B(NB) do { \
    { u32 q0_=pk2(br[0].x,br[1].x),q1_=pk2(br[2].x,br[3].x),q2_=pk2(br[4].x,br[5].x),q3_=pk2(br[6].x,br[7].x); \
      *(uint4*)&Bbuf[NB][swz((bn<<2)+0, bk0)] = make_uint4(q0_,q1_,q2_,q3_); } \
    { u32 q0_=pk2(br[0].y,br[1].y),q1_=pk2(br[2].y,br[3].y),q2_=pk2(br[4].y,br[5].y),q3_=pk2(br[6].y,br[7].y); \
      *(uint4*)&Bbuf[NB][swz((bn<<2)+1, bk0)] = make_uint4(q0_,q1_,q2_,q3_); } \
    { u32 q0_=pk2(br[0].z,br[1].z),q1_=pk2(br[2].z,br[3].z),q2_=pk2(br[4].z,br[5].z),q3_=pk2(br[6].z,br[7].z); \
      *(uint4*)&Bbuf[NB][swz((bn<<2)+2, bk0)] = make_uint4(q0_,q1_,q2_,q3_); } \
    { u32 q0_=pk2(br[0].w,br[1].w),q1_=pk2(br[2].w,br[3].w),q2_=pk2(br[4].w,br[5].w),q3_=pk2(br[6].w,br[7].w); \
      *(uint4*)&Bbuf[NB][swz((bn<<2)+3, bk0)] = make_uint4(q0_,q1_,q2_,q3_); } } while (0)
#define MFMA_PHASE(CUR) do { _Pragma("unroll") for (int kh_ = 0; kh_ < 2; ++kh_) { \
    int kk_ = (kh_ << 5) | ((lane >> 4) << 3); \
    bf16x8 af_[4], bf_[4]; \
    _Pragma("unroll") for (int mi_ = 0; mi_ < 4; ++mi_) \
      af_[mi_] = *(const bf16x8*)&Abuf[CUR][swz(wm + (mi_ << 4) + (lane & 15), kk_)]; \
    _Pragma("unroll") for (int ni_ = 0; ni_ < 4; ++ni_) \
      bf_[ni_] = *(const bf16x8*)&Bbuf[CUR][swz(wn + (ni_ << 4) + (lane & 15), kk_)]; \
    _Pragma("unroll") for (int mi_ = 0; mi_ < 4; ++mi_) \
      _Pragma("unroll") for (int ni_ = 0; ni_ < 4; ++ni_) \
        acc[mi_][ni_] = __builtin_amdgcn_mfma_f32_16x16x32_bf16(af_[mi_], bf_[ni_], acc[mi_][ni_], 0, 0, 0); \
  } } while (0)

    LOADA_DN(0); LOADB(0, DMODEL);
    WR_A(0); CVTWR_B(0);
    __syncthreads();
    int cur = 0;
    for (int k0 = 0; k0 < ESIZE; k0 += 64) {
      bool late = (k0 + 64 >= ESIZE);
      if (!late) { LOADA_DN(k0 + 64); LOADB(k0 + 64, DMODEL); }
      MFMA_PHASE(cur);
      if (!late) { WR_A(cur ^ 1); CVTWR_B(cur ^ 1); }
      __syncthreads();
      cur ^= 1;
    }

#pragma unroll
    for (int mi = 0; mi < 4; ++mi) {
      int rbase = wm + (mi << 4) + ((lane >> 4) << 2);
#pragma unroll
      for (int rr = 0; rr < 4; ++rr) {
        int r = rbase + rr;
        if (r < rem) {
          if (stage) {
            u16* so = stage + (size_t)slot_l[r] * DMODEL + nb0 + wn + (lane & 15);
#pragma unroll
            for (int ni = 0; ni < 4; ++ni)
              so[ni << 4] = f2b(acc[mi][ni][rr]);
          } else {
            int t = slot_l[r] >> 2;
            float* oo = out + (size_t)t * DMODEL + nb0 + wn + (lane & 15);
#pragma unroll
            for (int ni = 0; ni < 4; ++ni)
              atomicAdd(&oo[ni << 4], acc[mi][ni][rr]);
          }
        }
      }
    }
#undef LOADA_DN
#undef LOADB
#undef WR_A
#undef CVTWR_B
#undef MFMA_PHASE
  }
}

// ---------------- final: out[t] = sum_h stage[t*4+h] ----------------
__global__ __launch_bounds__(256) void k_final(const u16* __restrict__ stage,
                                               float* __restrict__ out)
{
  int tid = threadIdx.x;
  int t = (blockIdx.x << 1) + (tid >> 7);
  int d0 = (tid & 127) << 3;
  const u16* r0 = stage + ((size_t)t << 12) + d0;  // t*4 rows of 1024 shorts
  uint4 a0 = *(const uint4*)(r0);
  uint4 a1 = *(const uint4*)(r0 + 1024);
  uint4 a2 = *(const uint4*)(r0 + 2048);
  uint4 a3 = *(const uint4*)(r0 + 3072);
  float4 lo4, hi4;
  lo4.x = blo(a0.x) + blo(a1.x) + blo(a2.x) + blo(a3.x);
  lo4.y = bhi(a0.x) + bhi(a1.x) + bhi(a2.x) + bhi(a3.x);
  lo4.z = blo(a0.y) + blo(a1.y) + blo(a2.y) + blo(a3.y);
  lo4.w = bhi(a0.y) + bhi(a1.y) + bhi(a2.y) + bhi(a3.y);
  hi4.x = blo(a0.z) + blo(a1.z) + blo(a2.z) + blo(a3.z);
  hi4.y = bhi(a0.z) + bhi(a1.z) + bhi(a2.z) + bhi(a3.z);
  hi4.z = blo(a0.w) + blo(a1.w) + blo(a2.w) + blo(a3.w);
  hi4.w = bhi(a0.w) + bhi(a1.w) + bhi(a2.w) + bhi(a3.w);
  float* o = out + (size_t)t * DMODEL + d0;
  *(float4*)o = lo4;
  *(float4*)(o + 4) = hi4;
}

extern "C" void kernel_launch(void* const* d_in, const int* in_sizes, int n_in,
                              void* d_out, int out_size, void* d_ws, size_t ws_size,
                              hipStream_t stream) {
  (void)in_sizes; (void)n_in;
  const float* x      = (const float*)d_in[0];
  const float* keys   = (const float*)d_in[1];
  const float* values = (const float*)d_in[2];
  const float* es     = (const float*)d_in[3];
  float* out = (float*)d_out;

  char* W = (char*)d_ws;
  int*   cnt       = (int*)W;                        // 128 B
  u32*   selpk     = (u32*)(W + 1024);               // 16 KB
  float* selval    = (float*)(W + 64 * 1024);        // 64 KB
  float* blockpart = (float*)(W + 192 * 1024);       // 128 KB
  int*   bucket    = (int*)(W + 512 * 1024);         // 512 KB
  u16*   scores    = (u16*)(W + 2ull * 1024 * 1024); // 16 MB bf16 [16384][512]
  bool   big = ws_size >= (50ull << 20);
  u16*   stage = big ? (u16*)(W + 18ull * 1024 * 1024) : nullptr;  // 32 MB bf16 [16384][1024]

  if (!big)
    hipMemsetAsync(d_out, 0, (size_t)out_size * sizeof(float), stream);
  k_route<<<TOKENS / 4, 256, 0, stream>>>(x, es, selval, selpk, blockpart);
  k_count<<<1, 1024, 0, stream>>>(selpk, cnt, bucket);
  k_fin<<<1, 256, 0, stream>>>(blockpart, out + (size_t)out_size - 1);
  k_up<<<512, 256, 0, stream>>>(x, keys, selval, cnt, bucket, scores);
  k_down<<<512, 256, 0, stream>>>(scores, values, cnt, bucket, stage, out);
  if (big)
    k_final<<<TOKENS / 2, 256, 0, stream>>>(stage, out);
}

// Round 4
// 252.634 us; speedup vs baseline: 2.0686x; 1.1844x over previous
//
#include <hip/hip_runtime.h>
#include <hip/hip_bf16.h>

typedef unsigned short u16;
typedef unsigned int u32;
typedef __attribute__((ext_vector_type(4))) float f32x4;
typedef __attribute__((ext_vector_type(8))) short bf16x8;

#define TOKENS 4096
#define DMODEL 1024
#define NEXP 32
#define ESIZE 512

// round-to-nearest-even f32 -> bf16 bits
__device__ __forceinline__ u16 f2b(float f) {
  union { float f; u32 u; } v; v.f = f;
  u32 u = v.u;
  return (u16)((u + 0x7fffu + ((u >> 16) & 1u)) >> 16);
}

// packed f32x2 -> bf16x2
__device__ __forceinline__ u32 pk2(float a, float b) {
  union { __hip_bfloat162 h; u32 u; } v;
  v.h = __float22bfloat162_rn(make_float2(a, b));
  return v.u;
}

__device__ __forceinline__ float blo(u32 w) { union { u32 u; float f; } v; v.u = w << 16; return v.f; }
__device__ __forceinline__ float bhi(u32 w) { union { u32 u; float f; } v; v.u = w & 0xffff0000u; return v.f; }

// async global->LDS, 16B per lane; LDS dest = wave-uniform base + lane*16
typedef __attribute__((address_space(1))) const void as1_void;
typedef __attribute__((address_space(3))) void as3_void;
__device__ __forceinline__ void gl16(const void* g, void* l) {
  __builtin_amdgcn_global_load_lds((as1_void*)g, (as3_void*)l, 16, 0, 0);
}

// legacy swizzle for fallback kernels
__device__ __forceinline__ int swz(int row, int kk) {
  return row * 72 + ((((kk >> 3) ^ (row >> 2)) & 7) << 3) + (kk & 7);
}

// ---------------- routing: logits, top-4, gates, softmax block-partials ----------------
__global__ __launch_bounds__(256) void k_route(
    const float* __restrict__ x, const float* __restrict__ es,
    float* __restrict__ selval, u32* __restrict__ selpk,
    float* __restrict__ blockpart)
{
  __shared__ float ps[4][32];
  int tid = threadIdx.x;
  int w = tid >> 6, lane = tid & 63;
  int t = (blockIdx.x << 2) + w;
  int e = lane & 31, half = lane >> 5;
  const float4* xr = (const float4*)(x + (size_t)t * DMODEL + half * 512);
  const float4* er = (const float4*)(es + (size_t)e * DMODEL + half * 512);
  float acc = 0.f;
#pragma unroll 8
  for (int i = 0; i < 128; ++i) {
    float4 a = xr[i]; float4 b = er[i];
    acc += a.x * b.x + a.y * b.y + a.z * b.z + a.w * b.w;
  }
  float r = acc + __shfl_xor(acc, 32);

  float m = r;
#pragma unroll
  for (int mk = 16; mk; mk >>= 1) m = fmaxf(m, __shfl_xor(m, mk));
  float sx = __expf(r - m);
#pragma unroll
  for (int mk = 16; mk; mk >>= 1) sx += __shfl_xor(sx, mk);
  float p = __expf(r - (m + __logf(sx)));
  if (!half) ps[w][e] = p;

  u32 packed = 0;
  float v = r;
#pragma unroll
  for (int it = 0; it < 4; ++it) {
    float bv = v; int bi = e;
#pragma unroll
    for (int mk = 16; mk; mk >>= 1) {
      float ov = __shfl_xor(bv, mk); int oi = __shfl_xor(bi, mk);
      if (ov > bv || (ov == bv && oi < bi)) { bv = ov; bi = oi; }
    }
    packed |= (u32)bi << (8 * it);
    if (lane == it) selval[t * 4 + it] = 1.f / (1.f + __expf(-bv));
    if (e == bi) v = -3.0e38f;
  }
  if (lane == 0) selpk[t] = packed;
  __syncthreads();
  if (tid < 32)
    blockpart[blockIdx.x * 32 + tid] = ps[0][tid] + ps[1][tid] + ps[2][tid] + ps[3][tid];
}

// ---------------- bucket build ----------------
__global__ __launch_bounds__(1024) void k_count(
    const u32* __restrict__ selpk, int* __restrict__ cnt, int* __restrict__ bucket)
{
  __shared__ int cl[32];
  int tid = threadIdx.x;
  if (tid < 32) cl[tid] = 0;
  __syncthreads();
  int ex[16], pos[16];
#pragma unroll
  for (int j = 0; j < 4; ++j) {
    int t = tid + (j << 10);
    u32 pk = selpk[t];
#pragma unroll
    for (int h = 0; h < 4; ++h) {
      int e = (pk >> (8 * h)) & 0xff;
      ex[j * 4 + h] = e;
      pos[j * 4 + h] = atomicAdd(&cl[e], 1);
    }
  }
#pragma unroll
  for (int j = 0; j < 4; ++j) {
    int t = tid + (j << 10);
#pragma unroll
    for (int h = 0; h < 4; ++h)
      bucket[ex[j * 4 + h] * TOKENS + pos[j * 4 + h]] = (t << 2) | h;
  }
  __syncthreads();
  if (tid < 32) cnt[tid] = cl[tid];
}

// ---------------- entropy regularizer ----------------
__global__ __launch_bounds__(256) void k_fin(const float* __restrict__ blockpart,
                                             float* __restrict__ out_reg)
{
  __shared__ float part[8][32];
  int tid = threadIdx.x;
  int e = tid & 31, c = tid >> 5;
  float s = 0.f;
  for (int b = c; b < 1024; b += 8) s += blockpart[b * 32 + e];
  part[c][e] = s;
  __syncthreads();
  if (tid < 32) {
    float S = 0.f;
#pragma unroll
    for (int i = 0; i < 8; ++i) S += part[i][tid];
    float Pm = S * (1.0f / TOKENS);
    float rp = __logf(Pm) * Pm;
#pragma unroll
    for (int mk = 16; mk; mk >>= 1) rp += __shfl_xor(rp, mk);
    if (tid == 0) *out_reg = rp;
  }
}

// ---------------- x f32 -> bf16 ----------------
__global__ __launch_bounds__(256) void k_cvt(const float* __restrict__ src,
                                             u16* __restrict__ dst)
{
  int i = (int)((blockIdx.x * 256 + threadIdx.x) << 3);
  float4 a = *(const float4*)(src + i), b = *(const float4*)(src + i + 4);
  *(uint4*)(dst + i) = make_uint4(pk2(a.x, a.y), pk2(a.z, a.w), pk2(b.x, b.y), pk2(b.z, b.w));
}

// ---------------- transpose-convert: src f32 [E][R][C] -> dst bf16 [E][C][R] ----------------
__global__ __launch_bounds__(256) void k_tr(const float* __restrict__ src,
                                            u16* __restrict__ dst, int R, int C)
{
  __shared__ float tile[64][68];
  int e = blockIdx.z;
  int r0 = blockIdx.y << 6, c0 = blockIdx.x << 6;
  int t = threadIdx.x;
  int rr = t >> 2, cb = (t & 3) << 4;
  const float* sp = src + ((size_t)e * R + r0 + rr) * C + c0 + cb;
#pragma unroll
  for (int j = 0; j < 4; ++j)
    *(float4*)&tile[rr][cb + (j << 2)] = *(const float4*)(sp + (j << 2));
  __syncthreads();
  int wr = t >> 2, wb = (t & 3) << 4;
  u32 q[8];
#pragma unroll
  for (int j = 0; j < 8; ++j)
    q[j] = pk2(tile[wb + (j << 1)][wr], tile[wb + (j << 1) + 1][wr]);
  u16* dp = dst + ((size_t)e * C + c0 + wr) * R + r0 + wb;
  *(uint4*)dp = make_uint4(q[0], q[1], q[2], q[3]);
  *(uint4*)(dp + 8) = make_uint4(q[4], q[5], q[6], q[7]);
}

// ======== fast GEMMs: global_load_lds staging, XOR-granule swizzle, 2-phase dbuf ========
// LDS tile [128 rows][64 k] bf16, row = 128B = 8 granules of 16B.
// Stage: lane l covers row (l>>3), granule (l&7) linearly; global source granule = (l&7)^(l>>3).
// Read: for k-granule gg of row r, read LDS granule gg^(r&7)  (involution, rule 21).

#define GEMM_MACROS                                                                          \
  int wm = (w >> 1) << 6, wn = (w & 1) << 6;                                                 \
  int w32 = w << 5;                                                                          \
  int lg16 = (((l & 7) ^ (l >> 3)) << 4);

#define STAGE(BUF, K0) do {                                                                  \
  _Pragma("unroll") for (int i_ = 0; i_ < 4; ++i_)                                           \
    gl16(gA[i_] + ((K0) << 1), (void*)&Ab[BUF][(((w << 2) + i_) << 9)]);                     \
  _Pragma("unroll") for (int i_ = 0; i_ < 4; ++i_)                                           \
    gl16(gB[i_] + ((K0) << 1), (void*)&Bb[BUF][(((w << 2) + i_) << 9)]);                     \
} while (0)

#define COMPUTE(CUR) do {                                                                    \
  _Pragma("unroll") for (int kh_ = 0; kh_ < 2; ++kh_) {                                      \
    bf16x8 af_[4], bf_[4];                                                                   \
    int gg_ = (kh_ << 2) + (l >> 4);                                                         \
    _Pragma("unroll") for (int mi_ = 0; mi_ < 4; ++mi_) {                                    \
      int row_ = wm + (mi_ << 4) + (l & 15);                                                 \
      af_[mi_] = *(const bf16x8*)&Ab[CUR][(row_ << 6) + ((gg_ ^ (row_ & 7)) << 3)];          \
    }                                                                                        \
    _Pragma("unroll") for (int ni_ = 0; ni_ < 4; ++ni_) {                                    \
      int row_ = wn + (ni_ << 4) + (l & 15);                                                 \
      bf_[ni_] = *(const bf16x8*)&Bb[CUR][(row_ << 6) + ((gg_ ^ (row_ & 7)) << 3)];          \
    }                                                                                        \
    _Pragma("unroll") for (int mi_ = 0; mi_ < 4; ++mi_)                                      \
      _Pragma("unroll") for (int ni_ = 0; ni_ < 4; ++ni_)                                    \
        acc[mi_][ni_] = __builtin_amdgcn_mfma_f32_16x16x32_bf16(af_[mi_], bf_[ni_],          \
                                                                acc[mi_][ni_], 0, 0, 0);     \
  }                                                                                          \
} while (0)

#define VM0_BAR() do {                                                                       \
  asm volatile("s_waitcnt vmcnt(0)" ::: "memory");                                           \
  asm volatile("s_barrier" ::: "memory");                                                    \
} while (0)

// ---------------- up-projection: scores[slot] = relu(xb[t] @ kb[e]^T) * gate ----------------
__global__ __launch_bounds__(256, 2) void k_up(
    const u16* __restrict__ xb, const u16* __restrict__ kb,
    const float* __restrict__ selval, const int* __restrict__ cnt,
    const int* __restrict__ bucket, const u16* __restrict__ zeros,
    u16* __restrict__ scores)
{
  int bid = blockIdx.x;
  int pair = bid & 127, mz = bid >> 7;
  int e = pair >> 2, ns = pair & 3;
  int ne = cnt[e];
  if ((mz << 7) >= ne) return;
  int nb0 = ns << 7;
  int tid = threadIdx.x, l = tid & 63, w = tid >> 6;

  __shared__ __align__(16) u16 Ab[2][8192];
  __shared__ __align__(16) u16 Bb[2][8192];
  __shared__ int slot_l[128];
  __shared__ float gate_l[128];

  GEMM_MACROS;

  const char* gB[4];
#pragma unroll
  for (int i = 0; i < 4; ++i) {
    int n = nb0 + w32 + (i << 3) + (l >> 3);
    gB[i] = (const char*)(kb + ((size_t)e * ESIZE + n) * DMODEL) + lg16;
  }

  for (int mt = mz; (mt << 7) < ne; mt += 4) {
    int row0 = mt << 7;
    int rem = ne - row0; if (rem > 128) rem = 128;
    __syncthreads();
    if (tid < 128) {
      int slot = -1; float g = 0.f;
      if (tid < rem) { slot = bucket[e * TOKENS + row0 + tid]; g = selval[slot]; }
      slot_l[tid] = slot; gate_l[tid] = g;
    }
    __syncthreads();

    const char* gA[4];
#pragma unroll
    for (int i = 0; i < 4; ++i) {
      int s = slot_l[w32 + (i << 3) + (l >> 3)];
      gA[i] = ((s >= 0) ? (const char*)(xb + (size_t)(s >> 2) * DMODEL)
                        : (const char*)zeros) + lg16;
    }

    f32x4 acc[4][4];
#pragma unroll
    for (int i = 0; i < 4; ++i)
#pragma unroll
      for (int j = 0; j < 4; ++j) acc[i][j] = (f32x4){0.f, 0.f, 0.f, 0.f};

    STAGE(0, 0);
    VM0_BAR();
#pragma unroll 1
    for (int t = 0; t < 16; ++t) {
      int cur = t & 1;
      if (t < 15) STAGE(cur ^ 1, (t + 1) << 6);
      COMPUTE(cur);
      VM0_BAR();
    }

#pragma unroll
    for (int mi = 0; mi < 4; ++mi) {
      int rbase = wm + (mi << 4) + ((l >> 4) << 2);
#pragma unroll
      for (int rr = 0; rr < 4; ++rr) {
        int r = rbase + rr;
        if (r < rem) {
          float g = gate_l[r];
          u16* so = scores + (size_t)slot_l[r] * ESIZE + nb0 + wn + (l & 15);
#pragma unroll
          for (int ni = 0; ni < 4; ++ni)
            so[ni << 4] = f2b(fmaxf(acc[mi][ni][rr], 0.f) * g);
        }
      }
    }
  }
}

// ---------------- down-projection: stage[slot] = scores[slot] @ vb[e]^T ----------------
__global__ __launch_bounds__(256, 2) void k_down(
    const u16* __restrict__ scores, const u16* __restrict__ vb,
    const int* __restrict__ cnt, const int* __restrict__ bucket,
    const u16* __restrict__ zeros, u16* __restrict__ stage)
{
  int bid = blockIdx.x;
  int pair = bid & 255, mz = bid >> 8;
  int e = pair >> 3, ns = pair & 7;
  int ne = cnt[e];
  if ((mz << 7) >= ne) return;
  int nb0 = ns << 7;
  int tid = threadIdx.x, l = tid & 63, w = tid >> 6;

  __shared__ __align__(16) u16 Ab[2][8192];
  __shared__ __align__(16) u16 Bb[2][8192];
  __shared__ int slot_l[128];

  GEMM_MACROS;

  const char* gB[4];
#pragma unroll
  for (int i = 0; i < 4; ++i) {
    int n = nb0 + w32 + (i << 3) + (l >> 3);
    gB[i] = (const char*)(vb + ((size_t)e * DMODEL + n) * ESIZE) + lg16;
  }

  for (int mt = mz; (mt << 7) < ne; mt += 2) {
    int row0 = mt << 7;
    int rem = ne - row0; if (rem > 128) rem = 128;
    __syncthreads();
    if (tid < 128) {
      int slot = -1;
      if (tid < rem) slot = bucket[e * TOKENS + row0 + tid];
      slot_l[tid] = slot;
    }
    __syncthreads();

    const char* gA[4];
#pragma unroll
    for (int i = 0; i < 4; ++i) {
      int s = slot_l[w32 + (i << 3) + (l >> 3)];
      gA[i] = ((s >= 0) ? (const char*)(scores + (size_t)s * ESIZE)
                        : (const char*)zeros) + lg16;
    }

    f32x4 acc[4][4];
#pragma unroll
    for (int i = 0; i < 4; ++i)
#pragma unroll
      for (int j = 0; j < 4; ++j) acc[i][j] = (f32x4){0.f, 0.f, 0.f, 0.f};

    STAGE(0, 0);
    VM0_BAR();
#pragma unroll 1
    for (int t = 0; t < 8; ++t) {
      int cur = t & 1;
      if (t < 7) STAGE(cur ^ 1, (t + 1) << 6);
      COMPUTE(cur);
      VM0_BAR();
    }

#pragma unroll
    for (int mi = 0; mi < 4; ++mi) {
      int rbase = wm + (mi << 4) + ((l >> 4) << 2);
#pragma unroll
      for (int rr = 0; rr < 4; ++rr) {
        int r = rbase + rr;
        if (r < rem) {
          u16* so = stage + (size_t)slot_l[r] * DMODEL + nb0 + wn + (l & 15);
#pragma unroll
          for (int ni = 0; ni < 4; ++ni)
            so[ni << 4] = f2b(acc[mi][ni][rr]);
        }
      }
    }
  }
}

// ---------------- final: out[t] = sum_h stage[t*4+h] ----------------
__global__ __launch_bounds__(256) void k_final(const u16* __restrict__ stage,
                                               float* __restrict__ out)
{
  int tid = threadIdx.x;
  int t = (blockIdx.x << 1) + (tid >> 7);
  int d0 = (tid & 127) << 3;
  const u16* r0 = stage + ((size_t)t << 12) + d0;
  uint4 a0 = *(const uint4*)(r0);
  uint4 a1 = *(const uint4*)(r0 + 1024);
  uint4 a2 = *(const uint4*)(r0 + 2048);
  uint4 a3 = *(const uint4*)(r0 + 3072);
  float4 lo4, hi4;
  lo4.x = blo(a0.x) + blo(a1.x) + blo(a2.x) + blo(a3.x);
  lo4.y = bhi(a0.x) + bhi(a1.x) + bhi(a2.x) + bhi(a3.x);
  lo4.z = blo(a0.y) + blo(a1.y) + blo(a2.y) + blo(a3.y);
  lo4.w = bhi(a0.y) + bhi(a1.y) + bhi(a2.y) + bhi(a3.y);
  hi4.x = blo(a0.z) + blo(a1.z) + blo(a2.z) + blo(a3.z);
  hi4.y = bhi(a0.z) + bhi(a1.z) + bhi(a2.z) + bhi(a3.z);
  hi4.z = blo(a0.w) + blo(a1.w) + blo(a2.w) + blo(a3.w);
  hi4.w = bhi(a0.w) + bhi(a1.w) + bhi(a2.w) + bhi(a3.w);
  float* o = out + (size_t)t * DMODEL + d0;
  *(float4*)o = lo4;
  *(float4*)(o + 4) = hi4;
}

// ================= fallback (round-3 proven) kernels, used if ws too small =================
__global__ __launch_bounds__(256, 2) void k_up_rs(
    const float* __restrict__ x, const float* __restrict__ keys,
    const float* __restrict__ selval, const int* __restrict__ cnt,
    const int* __restrict__ bucket, u16* __restrict__ scores)
{
  int bid = blockIdx.x;
  int pair = bid & 127, mz = bid >> 7;
  int e = pair >> 2, ns = pair & 3;
  int ne = cnt[e];
  if ((mz << 7) >= ne) return;
  int nb0 = ns << 7;
  int tid = threadIdx.x;

  __shared__ __align__(16) u16 Abuf[2][128 * 72];
  __shared__ __align__(16) u16 Bbuf[2][128 * 72];
  __shared__ int slot_l[128];
  __shared__ float gate_l[128];

  const float* Kb = keys + (size_t)e * (DMODEL * ESIZE) + nb0;
  int arow = tid >> 1, ac0 = (tid & 1) << 5;
  int bn = tid & 31, bk0 = (tid >> 5) << 3;
  int lane = tid & 63, w = tid >> 6;
  int wm = (w >> 1) << 6, wn = (w & 1) << 6;

  for (int mt = mz; (mt << 7) < ne; mt += 4) {
    int row0 = mt << 7;
    int rem = ne - row0; if (rem > 128) rem = 128;
    __syncthreads();
    if (tid < 128) {
      int slot = -1; float g = 0.f;
      if (tid < rem) { slot = bucket[e * TOKENS + row0 + tid]; g = selval[slot]; }
      slot_l[tid] = slot; gate_l[tid] = g;
    }
    __syncthreads();

    int aslot = slot_l[arow];
    const float* xr = (aslot >= 0) ? (x + (size_t)(aslot >> 2) * DMODEL + ac0) : nullptr;
    const float* bp = Kb + (size_t)bk0 * ESIZE + (bn << 2);

    f32x4 acc[4][4];
#pragma unroll
    for (int i = 0; i < 4; ++i)
#pragma unroll
      for (int j = 0; j < 4; ++j) acc[i][j] = (f32x4){0.f, 0.f, 0.f, 0.f};

    float4 ar[8], br[8];
#define LOADA_UP(K) do { if (xr) { const float4* p_ = (const float4*)(xr + (K)); \
    _Pragma("unroll") for (int i_ = 0; i_ < 8; ++i_) ar[i_] = p_[i_]; } \
    else { _Pragma("unroll") for (int i_ = 0; i_ < 8; ++i_) ar[i_] = make_float4(0.f,0.f,0.f,0.f); } } while (0)
#define LOADB_RS(K, LDB) do { const float* q_ = bp + (size_t)(K) * (LDB); \
    _Pragma("unroll") for (int r_ = 0; r_ < 8; ++r_) br[r_] = *(const float4*)(q_ + (size_t)r_ * (LDB)); } while (0)
#define CVTWR_A(NB) do { _Pragma("unroll") for (int g_ = 0; g_ < 4; ++g_) { \
    u32 q0_ = pk2(ar[2*g_].x, ar[2*g_].y),   q1_ = pk2(ar[2*g_].z, ar[2*g_].w); \
    u32 q2_ = pk2(ar[2*g_+1].x, ar[2*g_+1].y), q3_ = pk2(ar[2*g_+1].z, ar[2*g_+1].w); \
    *(uint4*)&Abuf[NB][swz(arow, ac0 + 8*g_)] = make_uint4(q0_,q1_,q2_,q3_); } } while (0)
#define CVTWR_B(NB) do { \
    { u32 q0_=pk2(br[0].x,br[1].x),q1_=pk2(br[2].x,br[3].x),q2_=pk2(br[4].x,br[5].x),q3_=pk2(br[6].x,br[7].x); \
      *(uint4*)&Bbuf[NB][swz((bn<<2)+0, bk0)] = make_uint4(q0_,q1_,q2_,q3_); } \
    { u32 q0_=pk2(br[0].y,br[1].y),q1_=pk2(br[2].y,br[3].y),q2_=pk2(br[4].y,br[5].y),q3_=pk2(br[6].y,br[7].y); \
      *(uint4*)&Bbuf[NB][swz((bn<<2)+1, bk0)] = make_uint4(q0_,q1_,q2_,q3_); } \
    { u32 q0_=pk2(br[0].z,br[1].z),q1_=pk2(br[2].z,br[3].z),q2_=pk2(br[4].z,br[5].z),q3_=pk2(br[6].z,br[7].z); \
      *(uint4*)&Bbuf[NB][swz((bn<<2)+2, bk0)] = make_uint4(q0_,q1_,q2_,q3_); } \
    { u32 q0_=pk2(br[0].w,br[1].w),q1_=pk2(br[2].w,br[3].w),q2_=pk2(br[4].w,br[5].w),q3_=pk2(br[6].w,br[7].w); \
      *(uint4*)&Bbuf[NB][swz((bn<<2)+3, bk0)] = make_uint4(q0_,q1_,q2_,q3_); } } while (0)
#define MFMA_RS(CUR) do { _Pragma("unroll") for (int kh_ = 0; kh_ < 2; ++kh_) { \
    int kk_ = (kh_ << 5) | ((lane >> 4) << 3); \
    bf16x8 af_[4], bf_[4]; \
    _Pragma("unroll") for (int mi_ = 0; mi_ < 4; ++mi_) \
      af_[mi_] = *(const bf16x8*)&Abuf[CUR][swz(wm + (mi_ << 4) + (lane & 15), kk_)]; \
    _Pragma("unroll") for (int ni_ = 0; ni_ < 4; ++ni_) \
      bf_[ni_] = *(const bf16x8*)&Bbuf[CUR][swz(wn + (ni_ << 4) + (lane & 15), kk_)]; \
    _Pragma("unroll") for (int mi_ = 0; mi_ < 4; ++mi_) \
      _Pragma("unroll") for (int ni_ = 0; ni_ < 4; ++ni_) \
        acc[mi_][ni_] = __builtin_amdgcn_mfma_f32_16x16x32_bf16(af_[mi_], bf_[ni_], acc[mi_][ni_], 0, 0, 0); \
  } } while (0)

    LOADA_UP(0); LOADB_RS(0, ESIZE);
    CVTWR_A(0); CVTWR_B(0);
    __syncthreads();
    int cur = 0;
    for (int k0 = 0; k0 < DMODEL; k0 += 64) {
      bool late = (k0 + 64 >= DMODEL);
      if (!late) { LOADA_UP(k0 + 64); LOADB_RS(k0 + 64, ESIZE); }
      MFMA_RS(cur);
      if (!late) { CVTWR_A(cur ^ 1); CVTWR_B(cur ^ 1); }
      __syncthreads();
      cur ^= 1;
    }

#pragma unroll
    for (int mi = 0; mi < 4; ++mi) {
      int rbase = wm + (mi << 4) + ((lane >> 4) << 2);
#pragma unroll
      for (int rr = 0; rr < 4; ++rr) {
        int r = rbase + rr;
        if (r < rem) {
          float g = gate_l[r];
          u16* so = scores + (size_t)slot_l[r] * ESIZE + nb0 + wn + (lane & 15);
#pragma unroll
          for (int ni = 0; ni < 4; ++ni)
            so[ni << 4] = f2b(fmaxf(acc[mi][ni][rr], 0.f) * g);
        }
      }
    }
#undef LOADA_UP
#undef LOADB_RS
#undef CVTWR_A
#undef CVTWR_B
#undef MFMA_RS
  }
}

__global__ __launch_bounds__(256, 2) void k_down_rs(
    const u16* __restrict__ scores, const float* __restrict__ values,
    const int* __restrict__ cnt, const int* __restrict__ bucket,
    u16* __restrict__ stage, float* __restrict__ out)
{
  int bid = blockIdx.x;
  int pair = bid & 255, mz = bid >> 8;
  int e = pair >> 3, ns = pair & 7;
  int ne = cnt[e];
  if ((mz << 7) >= ne) return;
  int nb0 = ns << 7;
  int tid = threadIdx.x;

  __shared__ __align__(16) u16 Abuf[2][128 * 72];
  __shared__ __align__(16) u16 Bbuf[2][128 * 72];
  __shared__ int slot_l[128];

  const float* Vb = values + (size_t)e * (ESIZE * DMODEL) + nb0;
  int arow = tid >> 1, ac0 = (tid & 1) << 5;
  int bn = tid & 31, bk0 = (tid >> 5) << 3;
  int lane = tid & 63, w = tid >> 6;
  int wm = (w >> 1) << 6, wn = (w & 1) << 6;

  for (int mt = mz; (mt << 7) < ne; mt += 2) {
    int row0 = mt << 7;
    int rem = ne - row0; if (rem > 128) rem = 128;
    __syncthreads();
    if (tid < 128) {
      int slot = -1;
      if (tid < rem) slot = bucket[e * TOKENS + row0 + tid];
      slot_l[tid] = slot;
    }
    __syncthreads();

    int aslot = slot_l[arow];
    const u16* sr = (aslot >= 0) ? (scores + (size_t)aslot * ESIZE + ac0) : nullptr;
    const float* bp = Vb + (size_t)bk0 * DMODEL + (bn << 2);

    f32x4 acc[4][4];
#pragma unroll
    for (int i = 0; i < 4; ++i)
#pragma unroll
      for (int j = 0; j < 4; ++j) acc[i][j] = (f32x4){0.f, 0.f, 0.f, 0.f};

    uint4 a4[4]; float4 br[8];
#define LOADA_DN(K) do { if (sr) { const uint4* p_ = (const uint4*)(sr + (K)); \
    _Pragma("unroll") for (int i_ = 0; i_ < 4; ++i_) a4[i_] = p_[i_]; } \
    else { _Pragma("unroll") for (int i_ = 0; i_ < 4; ++i_) a4[i_] = make_uint4(0,0,0,0); } } while (0)
#define LOADB_RS(K, LDB) do { const float* q_ = bp + (size_t)(K) * (LDB); \
    _Pragma("unroll") for (int r_ = 0; r_ < 8; ++r_) br[r_] = *(const float4*)(q_ + (size_t)r_ * (LDB)); } while (0)
#define WR_A(NB) do { _Pragma("unroll") for (int g_ = 0; g_ < 4; ++g_) \
    *(uint4*)&Abuf[NB][swz(arow, ac0 + 8*g_)] = a4[g_]; } while (0)
#define CVTWR_B(NB) do { \
    { u32 q0_=pk2(br[0].x,br[1].x),q1_=pk2(br[2].x,br[3].x),q2_=pk2(br[4].x,br[5].x),q3_=pk2(br[6].x,br[7].x); \
      *(uint4*)&Bbuf[NB][swz((bn<<2)+0, bk0)] = make_uint4(q0_,q1_,q2_,q3_); } \
    { u32 q0_=pk2(br[0].y,br[1].y),q1_=pk2(br[2].y,br[3].y),q2_=pk2(br[4].y,br[5].y),q3_=pk2(br[6].y,br[7].y); \
      *(uint4*)&Bbuf[NB][swz((bn<<2)+1, bk0)] = make_uint4(q0_,q1_,q2_,q3_); } \
    { u32 q0_=pk2(br[0].z,br[1].z),q1_=pk2(br[2].z,br[3].z),q2_=pk2(br[4].z,br[5].z),q3_=pk2(br[6].z,br[7].z); \
      *(uint4*)&Bbuf[NB][swz((bn<<2)+2, bk0)] = make_uint4(q0_,q1_,q2_,q3_); } \
    { u32 q0_=pk2(br[0].w,br[1].w),q1_=pk2(br[2].w,br[3].w),q2_=pk2(br[4].w,br[5].w),q3_=pk2(br[6].w,br[7].w); \
      *(uint4*)&Bbuf[NB][swz((bn<<2)+3, bk0)] = make_uint4(q0_,q1_,q2_,q3_); } } while (0)
#define MFMA_RS(CUR) do { _Pragma("unroll") for (int kh_ = 0; kh_ < 2; ++kh_) { \
    int kk_ = (kh_ << 5) | ((lane >> 4) << 3); \
    bf16x8 af_[4], bf_[4]; \
    _Pragma("unroll") for (int mi_ = 0; mi_ < 4; ++mi_) \
      af_[mi_] = *(const bf16x8*)&Abuf[CUR][swz(wm + (mi_ << 4) + (lane & 15), kk_)]; \
    _Pragma("unroll") for (int ni_ = 0; ni_ < 4; ++ni_) \
      bf_[ni_] = *(const bf16x8*)&Bbuf[CUR][swz(wn + (ni_ << 4) + (lane & 15), kk_)]; \
    _Pragma("unroll") for (int mi_ = 0; mi_ < 4; ++mi_) \
      _Pragma("unroll") for (int ni_ = 0; ni_ < 4; ++ni_) \
        acc[mi_][ni_] = __builtin_amdgcn_mfma_f32_16x16x32_bf16(af_[mi_], bf_[ni_], acc[mi_][ni_], 0, 0, 0); \
  } } while (0)

    LOADA_DN(0); LOADB_RS(0, DMODEL);
    WR_A(0); CVTWR_B(0);
    __syncthreads();
    int cur = 0;
    for (int k0 = 0; k0 < ESIZE; k0 += 64) {
      bool late = (k0 + 64 >= ESIZE);
      if (!late) { LOADA_DN(k0 + 64); LOADB_RS(k0 + 64, DMODEL); }
      MFMA_RS(cur);
      if (!late) { WR_A(cur ^ 1); CVTWR_B(cur ^ 1); }
      __syncthreads();
      cur ^= 1;
    }

#pragma unroll
    for (int mi = 0; mi < 4; ++mi) {
      int rbase = wm + (mi << 4) + ((lane >> 4) << 2);
#pragma unroll
      for (int rr = 0; rr < 4; ++rr) {
        int r = rbase + rr;
        if (r < rem) {
          if (stage) {
            u16* so = stage + (size_t)slot_l[r] * DMODEL + nb0 + wn + (lane & 15);
#pragma unroll
            for (int ni = 0; ni < 4; ++ni)
              so[ni << 4] = f2b(acc[mi][ni][rr]);
          } else {
            int t = slot_l[r] >> 2;
            float* oo = out + (size_t)t * DMODEL + nb0 + wn + (lane & 15);
#pragma unroll
            for (int ni = 0; ni < 4; ++ni)
              atomicAdd(&oo[ni << 4], acc[mi][ni][rr]);
          }
        }
      }
    }
#undef LOADA_DN
#undef LOADB_RS
#undef WR_A
#undef CVTWR_B
#undef MFMA_RS
  }
}

extern "C" void kernel_launch(void* const* d_in, const int* in_sizes, int n_in,
                              void* d_out, int out_size, void* d_ws, size_t ws_size,
                              hipStream_t stream) {
  (void)in_sizes; (void)n_in;
  const float* x      = (const float*)d_in[0];
  const float* keys   = (const float*)d_in[1];
  const float* values = (const float*)d_in[2];
  const float* es     = (const float*)d_in[3];
  float* out = (float*)d_out;

  char* W = (char*)d_ws;
  int*   cnt       = (int*)W;                        // 128 B
  u16*   zeros     = (u16*)(W + 4 * 1024);           // 4 KB
  u32*   selpk     = (u32*)(W + 16 * 1024);          // 16 KB
  float* selval    = (float*)(W + 64 * 1024);        // 64 KB
  float* blockpart = (float*)(W + 128 * 1024);       // 128 KB
  int*   bucket    = (int*)(W + 512 * 1024);         // 512 KB

  k_route<<<TOKENS / 4, 256, 0, stream>>>(x, es, selval, selpk, blockpart);
  k_count<<<1, 1024, 0, stream>>>(selpk, cnt, bucket);
  k_fin<<<1, 256, 0, stream>>>(blockpart, out + (size_t)out_size - 1);

  if (ws_size >= (90ull << 20)) {
    u16* xb     = (u16*)(W + 2ull * 1024 * 1024);    // 8 MB  bf16 [4096][1024]
    u16* scores = (u16*)(W + 10ull * 1024 * 1024);   // 16 MB bf16 [16384][512]
    u16* kb     = (u16*)(W + 26ull * 1024 * 1024);   // 32 MB bf16 [32][512][1024]
    u16* vb     = (u16*)(W + 58ull * 1024 * 1024);   // 32 MB bf16 [32][1024][512]
    u16* stage  = kb;  // aliases kb: kb dead after k_up, stage written by k_down
    hipMemsetAsync(zeros, 0, 4096, stream);
    k_cvt<<<2048, 256, 0, stream>>>(x, xb);
    k_tr<<<dim3(ESIZE / 64, DMODEL / 64, NEXP), 256, 0, stream>>>(keys, kb, DMODEL, ESIZE);
    k_tr<<<dim3(DMODEL / 64, ESIZE / 64, NEXP), 256, 0, stream>>>(values, vb, ESIZE, DMODEL);
    k_up<<<512, 256, 0, stream>>>(xb, kb, selval, cnt, bucket, zeros, scores);
    k_down<<<512, 256, 0, stream>>>(scores, vb, cnt, bucket, zeros, stage);
    k_final<<<TOKENS / 2, 256, 0, stream>>>(stage, out);
  } else {
    u16* scores = (u16*)(W + 2ull * 1024 * 1024);
    bool big50 = ws_size >= (50ull << 20);
    u16* stage = big50 ? (u16*)(W + 18ull * 1024 * 1024) : nullptr;
    if (!big50)
      hipMemsetAsync(d_out, 0, (size_t)out_size * sizeof(float), stream);
    k_up_rs<<<512, 256, 0, stream>>>(x, keys, selval, cnt, bucket, scores);
    k_down_rs<<<512, 256, 0, stream>>>(scores, values, cnt, bucket, stage, out);
    if (big50)
      k_final<<<TOKENS / 2, 256, 0, stream>>>(stage, out);
  }
}

// Round 5
// 216.424 us; speedup vs baseline: 2.4147x; 1.1673x over previous
//
#include <hip/hip_runtime.h>
#include <hip/hip_bf16.h>

typedef unsigned short u16;
typedef unsigned int u32;
typedef __attribute__((ext_vector_type(4))) float f32x4;
typedef __attribute__((ext_vector_type(8))) short bf16x8;

#define TOKENS 4096
#define DMODEL 1024
#define NEXP 32
#define ESIZE 512

// round-to-nearest-even f32 -> bf16 bits
__device__ __forceinline__ u16 f2b(float f) {
  union { float f; u32 u; } v; v.f = f;
  u32 u = v.u;
  return (u16)((u + 0x7fffu + ((u >> 16) & 1u)) >> 16);
}

// packed f32x2 -> bf16x2
__device__ __forceinline__ u32 pk2(float a, float b) {
  union { __hip_bfloat162 h; u32 u; } v;
  v.h = __float22bfloat162_rn(make_float2(a, b));
  return v.u;
}

__device__ __forceinline__ float blo(u32 w) { union { u32 u; float f; } v; v.u = w << 16; return v.f; }
__device__ __forceinline__ float bhi(u32 w) { union { u32 u; float f; } v; v.u = w & 0xffff0000u; return v.f; }

// async global->LDS, 16B per lane; LDS dest = wave-uniform base + lane*16
typedef __attribute__((address_space(1))) const void as1_void;
typedef __attribute__((address_space(3))) void as3_void;
__device__ __forceinline__ void gl16(const void* g, void* l) {
  __builtin_amdgcn_global_load_lds((as1_void*)g, (as3_void*)l, 16, 0, 0);
}

// legacy swizzle for fallback kernels
__device__ __forceinline__ int swz(int row, int kk) {
  return row * 72 + ((((kk >> 3) ^ (row >> 2)) & 7) << 3) + (kk & 7);
}

// ---------------- es transpose: esT4[dblk][e][j] = es[e][4*dblk+j] ----------------
__global__ __launch_bounds__(256) void k_esT(const float* __restrict__ es,
                                             float* __restrict__ esT4)
{
  int tid = threadIdx.x;
  int dblk = (blockIdx.x << 3) + (tid >> 5);
  int e = tid & 31;
  float4 v = *(const float4*)(es + (size_t)e * DMODEL + (dblk << 2));
  *((float4*)esT4 + (size_t)dblk * 32 + e) = v;
}

// ---------------- routing: logits, top-4, gates, softmax block-partials ----------------
// esT4 layout: float4[256][32] -> lane e reads coalesced 512B per iteration.
__global__ __launch_bounds__(256) void k_route(
    const float* __restrict__ x, const float* __restrict__ esT4,
    float* __restrict__ selval, u32* __restrict__ selpk,
    float* __restrict__ blockpart)
{
  __shared__ float ps[4][32];
  int tid = threadIdx.x;
  int w = tid >> 6, lane = tid & 63;
  int t = (blockIdx.x << 2) + w;
  int e = lane & 31, half = lane >> 5;
  const float4* xr = (const float4*)(x + (size_t)t * DMODEL) + half * 128;
  const float4* er = (const float4*)esT4 + ((size_t)half * 128) * 32 + e;
  float acc = 0.f;
#pragma unroll 8
  for (int i = 0; i < 128; ++i) {
    float4 a = xr[i];
    float4 b = er[(size_t)i * 32];
    acc += a.x * b.x + a.y * b.y + a.z * b.z + a.w * b.w;
  }
  float r = acc + __shfl_xor(acc, 32);

  float m = r;
#pragma unroll
  for (int mk = 16; mk; mk >>= 1) m = fmaxf(m, __shfl_xor(m, mk));
  float sx = __expf(r - m);
#pragma unroll
  for (int mk = 16; mk; mk >>= 1) sx += __shfl_xor(sx, mk);
  float p = __expf(r - (m + __logf(sx)));
  if (!half) ps[w][e] = p;

  u32 packed = 0;
  float v = r;
#pragma unroll
  for (int it = 0; it < 4; ++it) {
    float bv = v; int bi = e;
#pragma unroll
    for (int mk = 16; mk; mk >>= 1) {
      float ov = __shfl_xor(bv, mk); int oi = __shfl_xor(bi, mk);
      if (ov > bv || (ov == bv && oi < bi)) { bv = ov; bi = oi; }
    }
    packed |= (u32)bi << (8 * it);
    if (lane == it) selval[t * 4 + it] = 1.f / (1.f + __expf(-bv));
    if (e == bi) v = -3.0e38f;
  }
  if (lane == 0) selpk[t] = packed;
  __syncthreads();
  if (tid < 32)
    blockpart[blockIdx.x * 32 + tid] = ps[0][tid] + ps[1][tid] + ps[2][tid] + ps[3][tid];
}

// ---------------- bucket build ----------------
__global__ __launch_bounds__(1024) void k_count(
    const u32* __restrict__ selpk, int* __restrict__ cnt, int* __restrict__ bucket)
{
  __shared__ int cl[32];
  int tid = threadIdx.x;
  if (tid < 32) cl[tid] = 0;
  __syncthreads();
  int ex[16], pos[16];
#pragma unroll
  for (int j = 0; j < 4; ++j) {
    int t = tid + (j << 10);
    u32 pk = selpk[t];
#pragma unroll
    for (int h = 0; h < 4; ++h) {
      int e = (pk >> (8 * h)) & 0xff;
      ex[j * 4 + h] = e;
      pos[j * 4 + h] = atomicAdd(&cl[e], 1);
    }
  }
#pragma unroll
  for (int j = 0; j < 4; ++j) {
    int t = tid + (j << 10);
#pragma unroll
    for (int h = 0; h < 4; ++h)
      bucket[ex[j * 4 + h] * TOKENS + pos[j * 4 + h]] = (t << 2) | h;
  }
  __syncthreads();
  if (tid < 32) cnt[tid] = cl[tid];
}

// ---------------- entropy regularizer ----------------
__global__ __launch_bounds__(256) void k_fin(const float* __restrict__ blockpart,
                                             float* __restrict__ out_reg)
{
  __shared__ float part[8][32];
  int tid = threadIdx.x;
  int e = tid & 31, c = tid >> 5;
  float s = 0.f;
  for (int b = c; b < 1024; b += 8) s += blockpart[b * 32 + e];
  part[c][e] = s;
  __syncthreads();
  if (tid < 32) {
    float S = 0.f;
#pragma unroll
    for (int i = 0; i < 8; ++i) S += part[i][tid];
    float Pm = S * (1.0f / TOKENS);
    float rp = __logf(Pm) * Pm;
#pragma unroll
    for (int mk = 16; mk; mk >>= 1) rp += __shfl_xor(rp, mk);
    if (tid == 0) *out_reg = rp;
  }
}

// ---------------- x f32 -> bf16 ----------------
__global__ __launch_bounds__(256) void k_cvt(const float* __restrict__ src,
                                             u16* __restrict__ dst)
{
  int i = (int)((blockIdx.x * 256 + threadIdx.x) << 3);
  float4 a = *(const float4*)(src + i), b = *(const float4*)(src + i + 4);
  *(uint4*)(dst + i) = make_uint4(pk2(a.x, a.y), pk2(a.z, a.w), pk2(b.x, b.y), pk2(b.z, b.w));
}

// ---------------- transpose-convert: src f32 [E][R][C] -> dst bf16 [E][C][R] ----------------
__global__ __launch_bounds__(256) void k_tr(const float* __restrict__ src,
                                            u16* __restrict__ dst, int R, int C)
{
  __shared__ float tile[64][68];
  int e = blockIdx.z;
  int r0 = blockIdx.y << 6, c0 = blockIdx.x << 6;
  int t = threadIdx.x;
  int rr = t >> 2, cb = (t & 3) << 4;
  const float* sp = src + ((size_t)e * R + r0 + rr) * C + c0 + cb;
#pragma unroll
  for (int j = 0; j < 4; ++j)
    *(float4*)&tile[rr][cb + (j << 2)] = *(const float4*)(sp + (j << 2));
  __syncthreads();
  int wr = t >> 2, wb = (t & 3) << 4;
  u32 q[8];
#pragma unroll
  for (int j = 0; j < 8; ++j)
    q[j] = pk2(tile[wb + (j << 1)][wr], tile[wb + (j << 1) + 1][wr]);
  u16* dp = dst + ((size_t)e * C + c0 + wr) * R + r0 + wb;
  *(uint4*)dp = make_uint4(q[0], q[1], q[2], q[3]);
  *(uint4*)(dp + 8) = make_uint4(q[4], q[5], q[6], q[7]);
}

// ======== fast GEMMs: global_load_lds staging, XOR-granule swizzle, 2-phase dbuf ========
#define GEMM_MACROS                                                                          \
  int wm = (w >> 1) << 6, wn = (w & 1) << 6;                                                 \
  int w32 = w << 5;                                                                          \
  int lg16 = (((l & 7) ^ (l >> 3)) << 4);

#define STAGE(BUF, K0) do {                                                                  \
  _Pragma("unroll") for (int i_ = 0; i_ < 4; ++i_)                                           \
    gl16(gA[i_] + ((K0) << 1), (void*)&Ab[BUF][(((w << 2) + i_) << 9)]);                     \
  _Pragma("unroll") for (int i_ = 0; i_ < 4; ++i_)                                           \
    gl16(gB[i_] + ((K0) << 1), (void*)&Bb[BUF][(((w << 2) + i_) << 9)]);                     \
} while (0)

#define COMPUTE(CUR) do {                                                                    \
  _Pragma("unroll") for (int kh_ = 0; kh_ < 2; ++kh_) {                                      \
    bf16x8 af_[4], bf_[4];                                                                   \
    int gg_ = (kh_ << 2) + (l >> 4);                                                         \
    _Pragma("unroll") for (int mi_ = 0; mi_ < 4; ++mi_) {                                    \
      int row_ = wm + (mi_ << 4) + (l & 15);                                                 \
      af_[mi_] = *(const bf16x8*)&Ab[CUR][(row_ << 6) + ((gg_ ^ (row_ & 7)) << 3)];          \
    }                                                                                        \
    _Pragma("unroll") for (int ni_ = 0; ni_ < 4; ++ni_) {                                    \
      int row_ = wn + (ni_ << 4) + (l & 15);                                                 \
      bf_[ni_] = *(const bf16x8*)&Bb[CUR][(row_ << 6) + ((gg_ ^ (row_ & 7)) << 3)];          \
    }                                                                                        \
    _Pragma("unroll") for (int mi_ = 0; mi_ < 4; ++mi_)                                      \
      _Pragma("unroll") for (int ni_ = 0; ni_ < 4; ++ni_)                                    \
        acc[mi_][ni_] = __builtin_amdgcn_mfma_f32_16x16x32_bf16(af_[mi_], bf_[ni_],          \
                                                                acc[mi_][ni_], 0, 0, 0);     \
  }                                                                                          \
} while (0)

#define VM0_BAR() do {                                                                       \
  asm volatile("s_waitcnt vmcnt(0)" ::: "memory");                                           \
  asm volatile("s_barrier" ::: "memory");                                                    \
} while (0)

// ---------------- up-projection: scores[slot] = relu(xb[t] @ kb[e]^T) * gate ----------------
__global__ __launch_bounds__(256, 2) void k_up(
    const u16* __restrict__ xb, const u16* __restrict__ kb,
    const float* __restrict__ selval, const int* __restrict__ cnt,
    const int* __restrict__ bucket, const u16* __restrict__ zeros,
    u16* __restrict__ scores)
{
  int bid = blockIdx.x;
  int pair = bid & 127, mz = bid >> 7;
  int e = pair >> 2, ns = pair & 3;
  int ne = cnt[e];
  if ((mz << 7) >= ne) return;
  int nb0 = ns << 7;
  int tid = threadIdx.x, l = tid & 63, w = tid >> 6;

  __shared__ __align__(16) u16 Ab[2][8192];
  __shared__ __align__(16) u16 Bb[2][8192];
  __shared__ int slot_l[128];
  __shared__ float gate_l[128];

  GEMM_MACROS;

  const char* gB[4];
#pragma unroll
  for (int i = 0; i < 4; ++i) {
    int n = nb0 + w32 + (i << 3) + (l >> 3);
    gB[i] = (const char*)(kb + ((size_t)e * ESIZE + n) * DMODEL) + lg16;
  }

  for (int mt = mz; (mt << 7) < ne; mt += 4) {
    int row0 = mt << 7;
    int rem = ne - row0; if (rem > 128) rem = 128;
    __syncthreads();
    if (tid < 128) {
      int slot = -1; float g = 0.f;
      if (tid < rem) { slot = bucket[e * TOKENS + row0 + tid]; g = selval[slot]; }
      slot_l[tid] = slot; gate_l[tid] = g;
    }
    __syncthreads();

    const char* gA[4];
#pragma unroll
    for (int i = 0; i < 4; ++i) {
      int s = slot_l[w32 + (i << 3) + (l >> 3)];
      gA[i] = ((s >= 0) ? (const char*)(xb + (size_t)(s >> 2) * DMODEL)
                        : (const char*)zeros) + lg16;
    }

    f32x4 acc[4][4];
#pragma unroll
    for (int i = 0; i < 4; ++i)
#pragma unroll
      for (int j = 0; j < 4; ++j) acc[i][j] = (f32x4){0.f, 0.f, 0.f, 0.f};

    STAGE(0, 0);
    VM0_BAR();
#pragma unroll 1
    for (int t = 0; t < 16; ++t) {
      int cur = t & 1;
      if (t < 15) STAGE(cur ^ 1, (t + 1) << 6);
      COMPUTE(cur);
      VM0_BAR();
    }

#pragma unroll
    for (int mi = 0; mi < 4; ++mi) {
      int rbase = wm + (mi << 4) + ((l >> 4) << 2);
#pragma unroll
      for (int rr = 0; rr < 4; ++rr) {
        int r = rbase + rr;
        if (r < rem) {
          float g = gate_l[r];
          u16* so = scores + (size_t)slot_l[r] * ESIZE + nb0 + wn + (l & 15);
#pragma unroll
          for (int ni = 0; ni < 4; ++ni)
            so[ni << 4] = f2b(fmaxf(acc[mi][ni][rr], 0.f) * g);
        }
      }
    }
  }
}

// ---------------- down-projection: stage[slot] = scores[slot] @ vb[e]^T ----------------
__global__ __launch_bounds__(256, 2) void k_down(
    const u16* __restrict__ scores, const u16* __restrict__ vb,
    const int* __restrict__ cnt, const int* __restrict__ bucket,
    const u16* __restrict__ zeros, u16* __restrict__ stage)
{
  int bid = blockIdx.x;
  int pair = bid & 255, mz = bid >> 8;
  int e = pair >> 3, ns = pair & 7;
  int ne = cnt[e];
  if ((mz << 7) >= ne) return;
  int nb0 = ns << 7;
  int tid = threadIdx.x, l = tid & 63, w = tid >> 6;

  __shared__ __align__(16) u16 Ab[2][8192];
  __shared__ __align__(16) u16 Bb[2][8192];
  __shared__ int slot_l[128];

  GEMM_MACROS;

  const char* gB[4];
#pragma unroll
  for (int i = 0; i < 4; ++i) {
    int n = nb0 + w32 + (i << 3) + (l >> 3);
    gB[i] = (const char*)(vb + ((size_t)e * DMODEL + n) * ESIZE) + lg16;
  }

  for (int mt = mz; (mt << 7) < ne; mt += 2) {
    int row0 = mt << 7;
    int rem = ne - row0; if (rem > 128) rem = 128;
    __syncthreads();
    if (tid < 128) {
      int slot = -1;
      if (tid < rem) slot = bucket[e * TOKENS + row0 + tid];
      slot_l[tid] = slot;
    }
    __syncthreads();

    const char* gA[4];
#pragma unroll
    for (int i = 0; i < 4; ++i) {
      int s = slot_l[w32 + (i << 3) + (l >> 3)];
      gA[i] = ((s >= 0) ? (const char*)(scores + (size_t)s * ESIZE)
                        : (const char*)zeros) + lg16;
    }

    f32x4 acc[4][4];
#pragma unroll
    for (int i = 0; i < 4; ++i)
#pragma unroll
      for (int j = 0; j < 4; ++j) acc[i][j] = (f32x4){0.f, 0.f, 0.f, 0.f};

    STAGE(0, 0);
    VM0_BAR();
#pragma unroll 1
    for (int t = 0; t < 8; ++t) {
      int cur = t & 1;
      if (t < 7) STAGE(cur ^ 1, (t + 1) << 6);
      COMPUTE(cur);
      VM0_BAR();
    }

#pragma unroll
    for (int mi = 0; mi < 4; ++mi) {
      int rbase = wm + (mi << 4) + ((l >> 4) << 2);
#pragma unroll
      for (int rr = 0; rr < 4; ++rr) {
        int r = rbase + rr;
        if (r < rem) {
          u16* so = stage + (size_t)slot_l[r] * DMODEL + nb0 + wn + (l & 15);
#pragma unroll
          for (int ni = 0; ni < 4; ++ni)
            so[ni << 4] = f2b(acc[mi][ni][rr]);
        }
      }
    }
  }
}

// ---------------- final: out[t] = sum_h stage[t*4+h] ----------------
__global__ __launch_bounds__(256) void k_final(const u16* __restrict__ stage,
                                               float* __restrict__ out)
{
  int tid = threadIdx.x;
  int t = (blockIdx.x << 1) + (tid >> 7);
  int d0 = (tid & 127) << 3;
  const u16* r0 = stage + ((size_t)t << 12) + d0;
  uint4 a0 = *(const uint4*)(r0);
  uint4 a1 = *(const uint4*)(r0 + 1024);
  uint4 a2 = *(const uint4*)(r0 + 2048);
  uint4 a3 = *(const uint4*)(r0 + 3072);
  float4 lo4, hi4;
  lo4.x = blo(a0.x) + blo(a1.x) + blo(a2.x) + blo(a3.x);
  lo4.y = bhi(a0.x) + bhi(a1.x) + bhi(a2.x) + bhi(a3.x);
  lo4.z = blo(a0.y) + blo(a1.y) + blo(a2.y) + blo(a3.y);
  lo4.w = bhi(a0.y) + bhi(a1.y) + bhi(a2.y) + bhi(a3.y);
  hi4.x = blo(a0.z) + blo(a1.z) + blo(a2.z) + blo(a3.z);
  hi4.y = bhi(a0.z) + bhi(a1.z) + bhi(a2.z) + bhi(a3.z);
  hi4.z = blo(a0.w) + blo(a1.w) + blo(a2.w) + blo(a3.w);
  hi4.w = bhi(a0.w) + bhi(a1.w) + bhi(a2.w) + bhi(a3.w);
  float* o = out + (size_t)t * DMODEL + d0;
  *(float4*)o = lo4;
  *(float4*)(o + 4) = hi4;
}

// ================= fallback (reg-staged) kernels, used if ws too small =================
__global__ __launch_bounds__(256, 2) void k_up_rs(
    const float* __restrict__ x, const float* __restrict__ keys,
    const float* __restrict__ selval, const int* __restrict__ cnt,
    const int* __restrict__ bucket, u16* __restrict__ scores)
{
  int bid = blockIdx.x;
  int pair = bid & 127, mz = bid >> 7;
  int e = pair >> 2, ns = pair & 3;
  int ne = cnt[e];
  if ((mz << 7) >= ne) return;
  int nb0 = ns << 7;
  int tid = threadIdx.x;

  __shared__ __align__(16) u16 Abuf[2][128 * 72];
  __shared__ __align__(16) u16 Bbuf[2][128 * 72];
  __shared__ int slot_l[128];
  __shared__ float gate_l[128];

  const float* Kb = keys + (size_t)e * (DMODEL * ESIZE) + nb0;
  int arow = tid >> 1, ac0 = (tid & 1) << 5;
  int bn = tid & 31, bk0 = (tid >> 5) << 3;
  int lane = tid & 63, w = tid >> 6;
  int wm = (w >> 1) << 6, wn = (w & 1) << 6;

  for (int mt = mz; (mt << 7) < ne; mt += 4) {
    int row0 = mt << 7;
    int rem = ne - row0; if (rem > 128) rem = 128;
    __syncthreads();
    if (tid < 128) {
      int slot = -1; float g = 0.f;
      if (tid < rem) { slot = bucket[e * TOKENS + row0 + tid]; g = selval[slot]; }
      slot_l[tid] = slot; gate_l[tid] = g;
    }
    __syncthreads();

    int aslot = slot_l[arow];
    const float* xr = (aslot >= 0) ? (x + (size_t)(aslot >> 2) * DMODEL + ac0) : nullptr;
    const float* bp = Kb + (size_t)bk0 * ESIZE + (bn << 2);

    f32x4 acc[4][4];
#pragma unroll
    for (int i = 0; i < 4; ++i)
#pragma unroll
      for (int j = 0; j < 4; ++j) acc[i][j] = (f32x4){0.f, 0.f, 0.f, 0.f};

    float4 ar[8], br[8];
#define LOADA_UP(K) do { if (xr) { const float4* p_ = (const float4*)(xr + (K)); \
    _Pragma("unroll") for (int i_ = 0; i_ < 8; ++i_) ar[i_] = p_[i_]; } \
    else { _Pragma("unroll") for (int i_ = 0; i_ < 8; ++i_) ar[i_] = make_float4(0.f,0.f,0.f,0.f); } } while (0)
#define LOADB_RS(K, LDB) do { const float* q_ = bp + (size_t)(K) * (LDB); \
    _Pragma("unroll") for (int r_ = 0; r_ < 8; ++r_) br[r_] = *(const float4*)(q_ + (size_t)r_ * (LDB)); } while (0)
#define CVTWR_A(NB) do { _Pragma("unroll") for (int g_ = 0; g_ < 4; ++g_) { \
    u32 q0_ = pk2(ar[2*g_].x, ar[2*g_].y),   q1_ = pk2(ar[2*g_].z, ar[2*g_].w); \
    u32 q2_ = pk2(ar[2*g_+1].x, ar[2*g_+1].y), q3_ = pk2(ar[2*g_+1].z, ar[2*g_+1].w); \
    *(uint4*)&Abuf[NB][swz(arow, ac0 + 8*g_)] = make_uint4(q0_,q1_,q2_,q3_); } } while (0)
#define CVTWR_B(NB) do { \
    { u32 q0_=pk2(br[0].x,br[1].x),q1_=pk2(br[2].x,br[3].x),q2_=pk2(br[4].x,br[5].x),q3_=pk2(br[6].x,br[7].x); \
      *(uint4*)&Bbuf[NB][swz((bn<<2)+0, bk0)] = make_uint4(q0_,q1_,q2_,q3_); } \
    { u32 q0_=pk2(br[0].y,br[1].y),q1_=pk2(br[2].y,br[3].y),q2_=pk2(br[4].y,br[5].y),q3_=pk2(br[6].y,br[7].y); \
      *(uint4*)&Bbuf[NB][swz((bn<<2)+1, bk0)] = make_uint4(q0_,q1_,q2_,q3_); } \
    { u32 q0_=pk2(br[0].z,br[1].z),q1_=pk2(br[2].z,br[3].z),q2_=pk2(br[4].z,br[5].z),q3_=pk2(br[6].z,br[7].z); \
      *(uint4*)&Bbuf[NB][swz((bn<<2)+2, bk0)] = make_uint4(q0_,q1_,q2_,q3_); } \
    { u32 q0_=pk2(br[0].w,br[1].w),q1_=pk2(br[2].w,br[3].w),q2_=pk2(br[4].w,br[5].w),q3_=pk2(br[6].w,br[7].w); \
      *(uint4*)&Bbuf[NB][swz((bn<<2)+3, bk0)] = make_uint4(q0_,q1_,q2_,q3_); } } while (0)
#define MFMA_RS(CUR) do { _Pragma("unroll") for (int kh_ = 0; kh_ < 2; ++kh_) { \
    int kk_ = (kh_ << 5) | ((lane >> 4) << 3); \
    bf16x8 af_[4], bf_[4]; \
    _Pragma("unroll") for (int mi_ = 0; mi_ < 4; ++mi_) \
      af_[mi_] = *(const bf16x8*)&Abuf[CUR][swz(wm + (mi_ << 4) + (lane & 15), kk_)]; \
    _Pragma("unroll") for (int ni_ = 0; ni_ < 4; ++ni_) \
      bf_[ni_] = *(const bf16x8*)&Bbuf[CUR][swz(wn + (ni_ << 4) + (lane & 15), kk_)]; \
    _Pragma("unroll") for (int mi_ = 0; mi_ < 4; ++mi_) \
      _Pragma("unroll") for (int ni_ = 0; ni_ < 4; ++ni_) \
        acc[mi_][ni_] = __builtin_amdgcn_mfma_f32_16x16x32_bf16(af_[mi_], bf_[ni_], acc[mi_][ni_], 0, 0, 0); \
  } } while (0)

    LOADA_UP(0); LOADB_RS(0, ESIZE);
    CVTWR_A(0); CVTWR_B(0);
    __syncthreads();
    int cur = 0;
    for (int k0 = 0; k0 < DMODEL; k0 += 64) {
      bool late = (k0 + 64 >= DMODEL);
      if (!late) { LOADA_UP(k0 + 64); LOADB_RS(k0 + 64, ESIZE); }
      MFMA_RS(cur);
      if (!late) { CVTWR_A(cur ^ 1); CVTWR_B(cur ^ 1); }
      __syncthreads();
      cur ^= 1;
    }

#pragma unroll
    for (int mi = 0; mi < 4; ++mi) {
      int rbase = wm + (mi << 4) + ((lane >> 4) << 2);
#pragma unroll
      for (int rr = 0; rr < 4; ++rr) {
        int r = rbase + rr;
        if (r < rem) {
          float g = gate_l[r];
          u16* so = scores + (size_t)slot_l[r] * ESIZE + nb0 + wn + (lane & 15);
#pragma unroll
          for (int ni = 0; ni < 4; ++ni)
            so[ni << 4] = f2b(fmaxf(acc[mi][ni][rr], 0.f) * g);
        }
      }
    }
#undef LOADA_UP
#undef LOADB_RS
#undef CVTWR_A
#undef CVTWR_B
#undef MFMA_RS
  }
}

__global__ __launch_bounds__(256, 2) void k_down_rs(
    const u16* __restrict__ scores, const float* __restrict__ values,
    const int* __restrict__ cnt, const int* __restrict__ bucket,
    u16* __restrict__ stage, float* __restrict__ out)
{
  int bid = blockIdx.x;
  int pair = bid & 255, mz = bid >> 8;
  int e = pair >> 3, ns = pair & 7;
  int ne = cnt[e];
  if ((mz << 7) >= ne) return;
  int nb0 = ns << 7;
  int tid = threadIdx.x;

  __shared__ __align__(16) u16 Abuf[2][128 * 72];
  __shared__ __align__(16) u16 Bbuf[2][128 * 72];
  __shared__ int slot_l[128];

  const float* Vb = values + (size_t)e * (ESIZE * DMODEL) + nb0;
  int arow = tid >> 1, ac0 = (tid & 1) << 5;
  int bn = tid & 31, bk0 = (tid >> 5) << 3;
  int lane = tid & 63, w = tid >> 6;
  int wm = (w >> 1) << 6, wn = (w & 1) << 6;

  for (int mt = mz; (mt << 7) < ne; mt += 2) {
    int row0 = mt << 7;
    int rem = ne - row0; if (rem > 128) rem = 128;
    __syncthreads();
    if (tid < 128) {
      int slot = -1;
      if (tid < rem) slot = bucket[e * TOKENS + row0 + tid];
      slot_l[tid] = slot;
    }
    __syncthreads();

    int aslot = slot_l[arow];
    const u16* sr = (aslot >= 0) ? (scores + (size_t)aslot * ESIZE + ac0) : nullptr;
    const float* bp = Vb + (size_t)bk0 * DMODEL + (bn << 2);

    f32x4 acc[4][4];
#pragma unroll
    for (int i = 0; i < 4; ++i)
#pragma unroll
      for (int j = 0; j < 4; ++j) acc[i][j] = (f32x4){0.f, 0.f, 0.f, 0.f};

    uint4 a4[4]; float4 br[8];
#define LOADA_DN(K) do { if (sr) { const uint4* p_ = (const uint4*)(sr + (K)); \
    _Pragma("unroll") for (int i_ = 0; i_ < 4; ++i_) a4[i_] = p_[i_]; } \
    else { _Pragma("unroll") for (int i_ = 0; i_ < 4; ++i_) a4[i_] = make_uint4(0,0,0,0); } } while (0)
#define LOADB_RS(K, LDB) do { const float* q_ = bp + (size_t)(K) * (LDB); \
    _Pragma("unroll") for (int r_ = 0; r_ < 8; ++r_) br[r_] = *(const float4*)(q_ + (size_t)r_ * (LDB)); } while (0)
#define WR_A(NB) do { _Pragma("unroll") for (int g_ = 0; g_ < 4; ++g_) \
    *(uint4*)&Abuf[NB][swz(arow, ac0 + 8*g_)] = a4[g_]; } while (0)
#define CVTWR_B(NB) do { \
    { u32 q0_=pk2(br[0].x,br[1].x),q1_=pk2(br[2].x,br[3].x),q2_=pk2(br[4].x,br[5].x),q3_=pk2(br[6].x,br[7].x); \
      *(uint4*)&Bbuf[NB][swz((bn<<2)+0, bk0)] = make_uint4(q0_,q1_,q2_,q3_); } \
    { u32 q0_=pk2(br[0].y,br[1].y),q1_=pk2(br[2].y,br[3].y),q2_=pk2(br[4].y,br[5].y),q3_=pk2(br[6].y,br[7].y); \
      *(uint4*)&Bbuf[NB][swz((bn<<2)+1, bk0)] = make_uint4(q0_,q1_,q2_,q3_); } \
    { u32 q0_=pk2(br[0].z,br[1].z),q1_=pk2(br[2].z,br[3].z),q2_=pk2(br[4].z,br[5].z),q3_=pk2(br[6].z,br[7].z); \
      *(uint4*)&Bbuf[NB][swz((bn<<2)+2, bk0)] = make_uint4(q0_,q1_,q2_,q3_); } \
    { u32 q0_=pk2(br[0].w,br[1].w),q1_=pk2(br[2].w,br[3].w),q2_=pk2(br[4].w,br[5].w),q3_=pk2(br[6].w,br[7].w); \
      *(uint4*)&Bbuf[NB][swz((bn<<2)+3, bk0)] = make_uint4(q0_,q1_,q2_,q3_); } } while (0)
#define MFMA_RS(CUR) do { _Pragma("unroll") for (int kh_ = 0; kh_ < 2; ++kh_) { \
    int kk_ = (kh_ << 5) | ((lane >> 4) << 3); \
    bf16x8 af_[4], bf_[4]; \
    _Pragma("unroll") for (int mi_ = 0; mi_ < 4; ++mi_) \
      af_[mi_] = *(const bf16x8*)&Abuf[CUR][swz(wm + (mi_ << 4) + (lane & 15), kk_)]; \
    _Pragma("unroll") for (int ni_ = 0; ni_ < 4; ++ni_) \
      bf_[ni_] = *(const bf16x8*)&Bbuf[CUR][swz(wn + (ni_ << 4) + (lane & 15), kk_)]; \
    _Pragma("unroll") for (int mi_ = 0; mi_ < 4; ++mi_) \
      _Pragma("unroll") for (int ni_ = 0; ni_ < 4; ++ni_) \
        acc[mi_][ni_] = __builtin_amdgcn_mfma_f32_16x16x32_bf16(af_[mi_], bf_[ni_], acc[mi_][ni_], 0, 0, 0); \
  } } while (0)

    LOADA_DN(0); LOADB_RS(0, DMODEL);
    WR_A(0); CVTWR_B(0);
    __syncthreads();
    int cur = 0;
    for (int k0 = 0; k0 < ESIZE; k0 += 64) {
      bool late = (k0 + 64 >= ESIZE);
      if (!late) { LOADA_DN(k0 + 64); LOADB_RS(k0 + 64, DMODEL); }
      MFMA_RS(cur);
      if (!late) { WR_A(cur ^ 1); CVTWR_B(cur ^ 1); }
      __syncthreads();
      cur ^= 1;
    }

#pragma unroll
    for (int mi = 0; mi < 4; ++mi) {
      int rbase = wm + (mi << 4) + ((lane >> 4) << 2);
#pragma unroll
      for (int rr = 0; rr < 4; ++rr) {
        int r = rbase + rr;
        if (r < rem) {
          if (stage) {
            u16* so = stage + (size_t)slot_l[r] * DMODEL + nb0 + wn + (lane & 15);
#pragma unroll
            for (int ni = 0; ni < 4; ++ni)
              so[ni << 4] = f2b(acc[mi][ni][rr]);
          } else {
            int t = slot_l[r] >> 2;
            float* oo = out + (size_t)t * DMODEL + nb0 + wn + (lane & 15);
#pragma unroll
            for (int ni = 0; ni < 4; ++ni)
              atomicAdd(&oo[ni << 4], acc[mi][ni][rr]);
          }
        }
      }
    }
#undef LOADA_DN
#undef LOADB_RS
#undef WR_A
#undef CVTWR_B
#undef MFMA_RS
  }
}

extern "C" void kernel_launch(void* const* d_in, const int* in_sizes, int n_in,
                              void* d_out, int out_size, void* d_ws, size_t ws_size,
                              hipStream_t stream) {
  (void)in_sizes; (void)n_in;
  const float* x      = (const float*)d_in[0];
  const float* keys   = (const float*)d_in[1];
  const float* values = (const float*)d_in[2];
  const float* es     = (const float*)d_in[3];
  float* out = (float*)d_out;

  char* W = (char*)d_ws;
  int*   cnt       = (int*)W;                        // 128 B
  u16*   zeros     = (u16*)(W + 4 * 1024);           // 4 KB
  u32*   selpk     = (u32*)(W + 16 * 1024);          // 16 KB
  float* selval    = (float*)(W + 64 * 1024);        // 64 KB
  float* blockpart = (float*)(W + 128 * 1024);       // 128 KB
  int*   bucket    = (int*)(W + 512 * 1024);         // 512 KB
  float* esT4      = (float*)(W + 1280 * 1024);      // 128 KB f32 [256][32][4]

  k_esT<<<32, 256, 0, stream>>>(es, esT4);
  k_route<<<TOKENS / 4, 256, 0, stream>>>(x, esT4, selval, selpk, blockpart);
  k_count<<<1, 1024, 0, stream>>>(selpk, cnt, bucket);
  k_fin<<<1, 256, 0, stream>>>(blockpart, out + (size_t)out_size - 1);

  if (ws_size >= (90ull << 20)) {
    u16* xb     = (u16*)(W + 2ull * 1024 * 1024);    // 8 MB  bf16 [4096][1024]
    u16* scores = (u16*)(W + 10ull * 1024 * 1024);   // 16 MB bf16 [16384][512]
    u16* kb     = (u16*)(W + 26ull * 1024 * 1024);   // 32 MB bf16 [32][512][1024]
    u16* vb     = (u16*)(W + 58ull * 1024 * 1024);   // 32 MB bf16 [32][1024][512]
    u16* stage  = kb;  // aliases kb: kb dead after k_up, stage written by k_down
    hipMemsetAsync(zeros, 0, 4096, stream);
    k_cvt<<<2048, 256, 0, stream>>>(x, xb);
    k_tr<<<dim3(ESIZE / 64, DMODEL / 64, NEXP), 256, 0, stream>>>(keys, kb, DMODEL, ESIZE);
    k_tr<<<dim3(DMODEL / 64, ESIZE / 64, NEXP), 256, 0, stream>>>(values, vb, ESIZE, DMODEL);
    k_up<<<512, 256, 0, stream>>>(xb, kb, selval, cnt, bucket, zeros, scores);
    k_down<<<512, 256, 0, stream>>>(scores, vb, cnt, bucket, zeros, stage);
    k_final<<<TOKENS / 2, 256, 0, stream>>>(stage, out);
  } else {
    u16* scores = (u16*)(W + 2ull * 1024 * 1024);
    bool big50 = ws_size >= (50ull << 20);
    u16* stage = big50 ? (u16*)(W + 18ull * 1024 * 1024) : nullptr;
    if (!big50)
      hipMemsetAsync(d_out, 0, (size_t)out_size * sizeof(float), stream);
    k_up_rs<<<512, 256, 0, stream>>>(x, keys, selval, cnt, bucket, scores);
    k_down_rs<<<512, 256, 0, stream>>>(scores, values, cnt, bucket, stage, out);
    if (big50)
      k_final<<<TOKENS / 2, 256, 0, stream>>>(stage, out);
  }
}

// Round 6
// 216.340 us; speedup vs baseline: 2.4156x; 1.0004x over previous
//
#include <hip/hip_runtime.h>
#include <hip/hip_bf16.h>

typedef unsigned short u16;
typedef unsigned int u32;
typedef __attribute__((ext_vector_type(4))) float f32x4;
typedef __attribute__((ext_vector_type(8))) short bf16x8;

#define TOKENS 4096
#define DMODEL 1024
#define NEXP 32
#define ESIZE 512

// round-to-nearest-even f32 -> bf16 bits
__device__ __forceinline__ u16 f2b(float f) {
  union { float f; u32 u; } v; v.f = f;
  u32 u = v.u;
  return (u16)((u + 0x7fffu + ((u >> 16) & 1u)) >> 16);
}

// packed f32x2 -> bf16x2
__device__ __forceinline__ u32 pk2(float a, float b) {
  union { __hip_bfloat162 h; u32 u; } v;
  v.h = __float22bfloat162_rn(make_float2(a, b));
  return v.u;
}

__device__ __forceinline__ float blo(u32 w) { union { u32 u; float f; } v; v.u = w << 16; return v.f; }
__device__ __forceinline__ float bhi(u32 w) { union { u32 u; float f; } v; v.u = w & 0xffff0000u; return v.f; }

// async global->LDS, 16B per lane; LDS dest = wave-uniform base + lane*16
typedef __attribute__((address_space(1))) const void as1_void;
typedef __attribute__((address_space(3))) void as3_void;
__device__ __forceinline__ void gl16(const void* g, void* l) {
  __builtin_amdgcn_global_load_lds((as1_void*)g, (as3_void*)l, 16, 0, 0);
}

// legacy swizzle for fallback kernels
__device__ __forceinline__ int swz(int row, int kk) {
  return row * 72 + ((((kk >> 3) ^ (row >> 2)) & 7) << 3) + (kk & 7);
}

// ---------------- es transpose: esT4[dblk][e][j] = es[e][4*dblk+j] ----------------
__global__ __launch_bounds__(256) void k_esT(const float* __restrict__ es,
                                             float* __restrict__ esT4)
{
  int tid = threadIdx.x;
  int dblk = (blockIdx.x << 3) + (tid >> 5);
  int e = tid & 31;
  float4 v = *(const float4*)(es + (size_t)e * DMODEL + (dblk << 2));
  *((float4*)esT4 + (size_t)dblk * 32 + e) = v;
}

// ---------------- routing: logits, top-4, gates, partials; fused x->bf16 ----------------
__global__ __launch_bounds__(256) void k_route(
    const float* __restrict__ x, const float* __restrict__ esT4,
    float* __restrict__ selval, u32* __restrict__ selpk,
    float* __restrict__ blockpart, u16* __restrict__ xb)
{
  __shared__ float ps[4][32];
  int tid = threadIdx.x;
  int w = tid >> 6, lane = tid & 63;
  int t = (blockIdx.x << 2) + w;
  int e = lane & 31, half = lane >> 5;
  const float4* xr = (const float4*)(x + (size_t)t * DMODEL) + half * 128;
  const float4* er = (const float4*)esT4 + ((size_t)half * 128) * 32 + e;
  u16* xrow = xb ? (xb + ((size_t)t << 10) + (half << 9)) : nullptr;
  float acc = 0.f;
#pragma unroll 8
  for (int i = 0; i < 128; ++i) {
    float4 a = xr[i];
    float4 b = er[(size_t)i * 32];
    acc += a.x * b.x + a.y * b.y + a.z * b.z + a.w * b.w;
    if (xrow && ((i & 31) == e)) {
      uint2 q; q.x = pk2(a.x, a.y); q.y = pk2(a.z, a.w);
      *(uint2*)(xrow + (i << 2)) = q;
    }
  }
  float r = acc + __shfl_xor(acc, 32);

  float m = r;
#pragma unroll
  for (int mk = 16; mk; mk >>= 1) m = fmaxf(m, __shfl_xor(m, mk));
  float sx = __expf(r - m);
#pragma unroll
  for (int mk = 16; mk; mk >>= 1) sx += __shfl_xor(sx, mk);
  float p = __expf(r - (m + __logf(sx)));
  if (!half) ps[w][e] = p;

  u32 packed = 0;
  float v = r;
#pragma unroll
  for (int it = 0; it < 4; ++it) {
    float bv = v; int bi = e;
#pragma unroll
    for (int mk = 16; mk; mk >>= 1) {
      float ov = __shfl_xor(bv, mk); int oi = __shfl_xor(bi, mk);
      if (ov > bv || (ov == bv && oi < bi)) { bv = ov; bi = oi; }
    }
    packed |= (u32)bi << (8 * it);
    if (lane == it) selval[t * 4 + it] = 1.f / (1.f + __expf(-bv));
    if (e == bi) v = -3.0e38f;
  }
  if (lane == 0) selpk[t] = packed;
  __syncthreads();
  if (tid < 32)
    blockpart[blockIdx.x * 32 + tid] = ps[0][tid] + ps[1][tid] + ps[2][tid] + ps[3][tid];
}

// ---------------- bucket build ----------------
__global__ __launch_bounds__(1024) void k_count(
    const u32* __restrict__ selpk, int* __restrict__ cnt, int* __restrict__ bucket)
{
  __shared__ int cl[32];
  int tid = threadIdx.x;
  if (tid < 32) cl[tid] = 0;
  __syncthreads();
  int ex[16], pos[16];
#pragma unroll
  for (int j = 0; j < 4; ++j) {
    int t = tid + (j << 10);
    u32 pk = selpk[t];
#pragma unroll
    for (int h = 0; h < 4; ++h) {
      int e = (pk >> (8 * h)) & 0xff;
      ex[j * 4 + h] = e;
      pos[j * 4 + h] = atomicAdd(&cl[e], 1);
    }
  }
#pragma unroll
  for (int j = 0; j < 4; ++j) {
    int t = tid + (j << 10);
#pragma unroll
    for (int h = 0; h < 4; ++h)
      bucket[ex[j * 4 + h] * TOKENS + pos[j * 4 + h]] = (t << 2) | h;
  }
  __syncthreads();
  if (tid < 32) cnt[tid] = cl[tid];
}

// ---------------- entropy regularizer ----------------
__global__ __launch_bounds__(256) void k_fin(const float* __restrict__ blockpart,
                                             float* __restrict__ out_reg)
{
  __shared__ float part[8][32];
  int tid = threadIdx.x;
  int e = tid & 31, c = tid >> 5;
  float s = 0.f;
  for (int b = c; b < 1024; b += 8) s += blockpart[b * 32 + e];
  part[c][e] = s;
  __syncthreads();
  if (tid < 32) {
    float S = 0.f;
#pragma unroll
    for (int i = 0; i < 8; ++i) S += part[i][tid];
    float Pm = S * (1.0f / TOKENS);
    float rp = __logf(Pm) * Pm;
#pragma unroll
    for (int mk = 16; mk; mk >>= 1) rp += __shfl_xor(rp, mk);
    if (tid == 0) *out_reg = rp;
  }
}

// ---------------- x f32 -> bf16 (fallback path only) ----------------
__global__ __launch_bounds__(256) void k_cvt(const float* __restrict__ src,
                                             u16* __restrict__ dst)
{
  int i = (int)((blockIdx.x * 256 + threadIdx.x) << 3);
  float4 a = *(const float4*)(src + i), b = *(const float4*)(src + i + 4);
  *(uint4*)(dst + i) = make_uint4(pk2(a.x, a.y), pk2(a.z, a.w), pk2(b.x, b.y), pk2(b.z, b.w));
}

// ---------------- transpose-convert: src f32 [E][R][C] -> dst bf16 [E][C][R] ----------------
__global__ __launch_bounds__(256) void k_tr(const float* __restrict__ src,
                                            u16* __restrict__ dst, int R, int C)
{
  __shared__ float tile[64][68];
  int e = blockIdx.z;
  int r0 = blockIdx.y << 6, c0 = blockIdx.x << 6;
  int t = threadIdx.x;
  int rr = t >> 2, cb = (t & 3) << 4;
  const float* sp = src + ((size_t)e * R + r0 + rr) * C + c0 + cb;
#pragma unroll
  for (int j = 0; j < 4; ++j)
    *(float4*)&tile[rr][cb + (j << 2)] = *(const float4*)(sp + (j << 2));
  __syncthreads();
  int wr = t >> 2, wb = (t & 3) << 4;
  u32 q[8];
#pragma unroll
  for (int j = 0; j < 8; ++j)
    q[j] = pk2(tile[wb + (j << 1)][wr], tile[wb + (j << 1) + 1][wr]);
  u16* dp = dst + ((size_t)e * C + c0 + wr) * R + r0 + wb;
  *(uint4*)dp = make_uint4(q[0], q[1], q[2], q[3]);
  *(uint4*)(dp + 8) = make_uint4(q[4], q[5], q[6], q[7]);
}

// ======== fast GEMMs: global_load_lds staging, XOR-granule swizzle, 2-phase dbuf ========
#define GEMM_MACROS                                                                          \
  int wm = (w >> 1) << 6, wn = (w & 1) << 6;                                                 \
  int w32 = w << 5;                                                                          \
  int lg16 = (((l & 7) ^ (l >> 3)) << 4);

#define STAGE(BUF, K0) do {                                                                  \
  _Pragma("unroll") for (int i_ = 0; i_ < 4; ++i_)                                           \
    gl16(gA[i_] + ((K0) << 1), (void*)&Ab[BUF][(((w << 2) + i_) << 9)]);                     \
  _Pragma("unroll") for (int i_ = 0; i_ < 4; ++i_)                                           \
    gl16(gB[i_] + ((K0) << 1), (void*)&Bb[BUF][(((w << 2) + i_) << 9)]);                     \
} while (0)

#define COMPUTE(CUR) do {                                                                    \
  _Pragma("unroll") for (int kh_ = 0; kh_ < 2; ++kh_) {                                      \
    bf16x8 af_[4], bf_[4];                                                                   \
    int gg_ = (kh_ << 2) + (l >> 4);                                                         \
    _Pragma("unroll") for (int mi_ = 0; mi_ < 4; ++mi_) {                                    \
      int row_ = wm + (mi_ << 4) + (l & 15);                                                 \
      af_[mi_] = *(const bf16x8*)&Ab[CUR][(row_ << 6) + ((gg_ ^ (row_ & 7)) << 3)];          \
    }                                                                                        \
    _Pragma("unroll") for (int ni_ = 0; ni_ < 4; ++ni_) {                                    \
      int row_ = wn + (ni_ << 4) + (l & 15);                                                 \
      bf_[ni_] = *(const bf16x8*)&Bb[CUR][(row_ << 6) + ((gg_ ^ (row_ & 7)) << 3)];          \
    }                                                                                        \
    _Pragma("unroll") for (int mi_ = 0; mi_ < 4; ++mi_)                                      \
      _Pragma("unroll") for (int ni_ = 0; ni_ < 4; ++ni_)                                    \
        acc[mi_][ni_] = __builtin_amdgcn_mfma_f32_16x16x32_bf16(af_[mi_], bf_[ni_],          \
                                                                acc[mi_][ni_], 0, 0, 0);     \
  }                                                                                          \
} while (0)

#define VM0_BAR() do {                                                                       \
  asm volatile("s_waitcnt vmcnt(0)" ::: "memory");                                           \
  asm volatile("s_barrier" ::: "memory");                                                    \
} while (0)

// XCD-affine decode: bid = ((e>>3)*16 + sub)*8 + (e&7)
// -> all 16 blocks of an expert land on one XCD (round-robin bid%8 = XCD heuristic).
#define XCD_DECODE(SUB_NS_BITS)                                                              \
  int bid = blockIdx.x;                                                                      \
  int q_ = bid >> 3, sub_ = q_ & 15;                                                         \
  int e = ((q_ >> 4) << 3) | (bid & 7);                                                      \
  int ns = sub_ & ((1 << (SUB_NS_BITS)) - 1);                                                \
  int mz = sub_ >> (SUB_NS_BITS);

// ---------------- up-projection: scores[slot] = relu(xb[t] @ kb[e]^T) * gate ----------------
__global__ __launch_bounds__(256, 2) void k_up(
    const u16* __restrict__ xb, const u16* __restrict__ kb,
    const float* __restrict__ selval, const int* __restrict__ cnt,
    const int* __restrict__ bucket, const u16* __restrict__ zeros,
    u16* __restrict__ scores)
{
  XCD_DECODE(2);                       // 4 ns x 4 mz
  int ne = cnt[e];
  if ((mz << 7) >= ne) return;
  int nb0 = ns << 7;
  int tid = threadIdx.x, l = tid & 63, w = tid >> 6;

  __shared__ __align__(16) u16 Ab[2][8192];
  __shared__ __align__(16) u16 Bb[2][8192];
  __shared__ int slot_l[128];
  __shared__ float gate_l[128];

  GEMM_MACROS;

  const char* gB[4];
#pragma unroll
  for (int i = 0; i < 4; ++i) {
    int n = nb0 + w32 + (i << 3) + (l >> 3);
    gB[i] = (const char*)(kb + ((size_t)e * ESIZE + n) * DMODEL) + lg16;
  }

  for (int mt = mz; (mt << 7) < ne; mt += 4) {
    int row0 = mt << 7;
    int rem = ne - row0; if (rem > 128) rem = 128;
    __syncthreads();
    if (tid < 128) {
      int slot = -1; float g = 0.f;
      if (tid < rem) { slot = bucket[e * TOKENS + row0 + tid]; g = selval[slot]; }
      slot_l[tid] = slot; gate_l[tid] = g;
    }
    __syncthreads();

    const char* gA[4];
#pragma unroll
    for (int i = 0; i < 4; ++i) {
      int s = slot_l[w32 + (i << 3) + (l >> 3)];
      gA[i] = ((s >= 0) ? (const char*)(xb + (size_t)(s >> 2) * DMODEL)
                        : (const char*)zeros) + lg16;
    }

    f32x4 acc[4][4];
#pragma unroll
    for (int i = 0; i < 4; ++i)
#pragma unroll
      for (int j = 0; j < 4; ++j) acc[i][j] = (f32x4){0.f, 0.f, 0.f, 0.f};

    STAGE(0, 0);
    VM0_BAR();
#pragma unroll 1
    for (int t = 0; t < 16; ++t) {
      int cur = t & 1;
      if (t < 15) STAGE(cur ^ 1, (t + 1) << 6);
      COMPUTE(cur);
      VM0_BAR();
    }

#pragma unroll
    for (int mi = 0; mi < 4; ++mi) {
      int rbase = wm + (mi << 4) + ((l >> 4) << 2);
#pragma unroll
      for (int rr = 0; rr < 4; ++rr) {
        int r = rbase + rr;
        if (r < rem) {
          float g = gate_l[r];
          u16* so = scores + (size_t)slot_l[r] * ESIZE + nb0 + wn + (l & 15);
#pragma unroll
          for (int ni = 0; ni < 4; ++ni)
            so[ni << 4] = f2b(fmaxf(acc[mi][ni][rr], 0.f) * g);
        }
      }
    }
  }
}

// ---------------- down-projection: stage[slot] = scores[slot] @ vb[e]^T ----------------
__global__ __launch_bounds__(256, 2) void k_down(
    const u16* __restrict__ scores, const u16* __restrict__ vb,
    const int* __restrict__ cnt, const int* __restrict__ bucket,
    const u16* __restrict__ zeros, u16* __restrict__ stage)
{
  XCD_DECODE(3);                       // 8 ns x 2 mz
  int ne = cnt[e];
  if ((mz << 7) >= ne) return;
  int nb0 = ns << 7;
  int tid = threadIdx.x, l = tid & 63, w = tid >> 6;

  __shared__ __align__(16) u16 Ab[2][8192];
  __shared__ __align__(16) u16 Bb[2][8192];
  __shared__ int slot_l[128];

  GEMM_MACROS;

  const char* gB[4];
#pragma unroll
  for (int i = 0; i < 4; ++i) {
    int n = nb0 + w32 + (i << 3) + (l >> 3);
    gB[i] = (const char*)(vb + ((size_t)e * DMODEL + n) * ESIZE) + lg16;
  }

  for (int mt = mz; (mt << 7) < ne; mt += 2) {
    int row0 = mt << 7;
    int rem = ne - row0; if (rem > 128) rem = 128;
    __syncthreads();
    if (tid < 128) {
      int slot = -1;
      if (tid < rem) slot = bucket[e * TOKENS + row0 + tid];
      slot_l[tid] = slot;
    }
    __syncthreads();

    const char* gA[4];
#pragma unroll
    for (int i = 0; i < 4; ++i) {
      int s = slot_l[w32 + (i << 3) + (l >> 3)];
      gA[i] = ((s >= 0) ? (const char*)(scores + (size_t)s * ESIZE)
                        : (const char*)zeros) + lg16;
    }

    f32x4 acc[4][4];
#pragma unroll
    for (int i = 0; i < 4; ++i)
#pragma unroll
      for (int j = 0; j < 4; ++j) acc[i][j] = (f32x4){0.f, 0.f, 0.f, 0.f};

    STAGE(0, 0);
    VM0_BAR();
#pragma unroll 1
    for (int t = 0; t < 8; ++t) {
      int cur = t & 1;
      if (t < 7) STAGE(cur ^ 1, (t + 1) << 6);
      COMPUTE(cur);
      VM0_BAR();
    }

#pragma unroll
    for (int mi = 0; mi < 4; ++mi) {
      int rbase = wm + (mi << 4) + ((l >> 4) << 2);
#pragma unroll
      for (int rr = 0; rr < 4; ++rr) {
        int r = rbase + rr;
        if (r < rem) {
          u16* so = stage + (size_t)slot_l[r] * DMODEL + nb0 + wn + (l & 15);
#pragma unroll
          for (int ni = 0; ni < 4; ++ni)
            so[ni << 4] = f2b(acc[mi][ni][rr]);
        }
      }
    }
  }
}

// ---------------- final: out[t] = sum_h stage[t*4+h] ----------------
__global__ __launch_bounds__(256) void k_final(const u16* __restrict__ stage,
                                               float* __restrict__ out)
{
  int tid = threadIdx.x;
  int t = (blockIdx.x << 1) + (tid >> 7);
  int d0 = (tid & 127) << 3;
  const u16* r0 = stage + ((size_t)t << 12) + d0;
  uint4 a0 = *(const uint4*)(r0);
  uint4 a1 = *(const uint4*)(r0 + 1024);
  uint4 a2 = *(const uint4*)(r0 + 2048);
  uint4 a3 = *(const uint4*)(r0 + 3072);
  float4 lo4, hi4;
  lo4.x = blo(a0.x) + blo(a1.x) + blo(a2.x) + blo(a3.x);
  lo4.y = bhi(a0.x) + bhi(a1.x) + bhi(a2.x) + bhi(a3.x);
  lo4.z = blo(a0.y) + blo(a1.y) + blo(a2.y) + blo(a3.y);
  lo4.w = bhi(a0.y) + bhi(a1.y) + bhi(a2.y) + bhi(a3.y);
  hi4.x = blo(a0.z) + blo(a1.z) + blo(a2.z) + blo(a3.z);
  hi4.y = bhi(a0.z) + bhi(a1.z) + bhi(a2.z) + bhi(a3.z);
  hi4.z = blo(a0.w) + blo(a1.w) + blo(a2.w) + blo(a3.w);
  hi4.w = bhi(a0.w) + bhi(a1.w) + bhi(a2.w) + bhi(a3.w);
  float* o = out + (size_t)t * DMODEL + d0;
  *(float4*)o = lo4;
  *(float4*)(o + 4) = hi4;
}

// ================= fallback (reg-staged) kernels, used if ws too small =================
__global__ __launch_bounds__(256, 2) void k_up_rs(
    const float* __restrict__ x, const float* __restrict__ keys,
    const float* __restrict__ selval, const int* __restrict__ cnt,
    const int* __restrict__ bucket, u16* __restrict__ scores)
{
  int bid = blockIdx.x;
  int pair = bid & 127, mz = bid >> 7;
  int e = pair >> 2, ns = pair & 3;
  int ne = cnt[e];
  if ((mz << 7) >= ne) return;
  int nb0 = ns << 7;
  int tid = threadIdx.x;

  __shared__ __align__(16) u16 Abuf[2][128 * 72];
  __shared__ __align__(16) u16 Bbuf[2][128 * 72];
  __shared__ int slot_l[128];
  __shared__ float gate_l[128];

  const float* Kb = keys + (size_t)e * (DMODEL * ESIZE) + nb0;
  int arow = tid >> 1, ac0 = (tid & 1) << 5;
  int bn = tid & 31, bk0 = (tid >> 5) << 3;
  int lane = tid & 63, w = tid >> 6;
  int wm = (w >> 1) << 6, wn = (w & 1) << 6;

  for (int mt = mz; (mt << 7) < ne; mt += 4) {
    int row0 = mt << 7;
    int rem = ne - row0; if (rem > 128) rem = 128;
    __syncthreads();
    if (tid < 128) {
      int slot = -1; float g = 0.f;
      if (tid < rem) { slot = bucket[e * TOKENS + row0 + tid]; g = selval[slot]; }
      slot_l[tid] = slot; gate_l[tid] = g;
    }
    __syncthreads();

    int aslot = slot_l[arow];
    const float* xr = (aslot >= 0) ? (x + (size_t)(aslot >> 2) * DMODEL + ac0) : nullptr;
    const float* bp = Kb + (size_t)bk0 * ESIZE + (bn << 2);

    f32x4 acc[4][4];
#pragma unroll
    for (int i = 0; i < 4; ++i)
#pragma unroll
      for (int j = 0; j < 4; ++j) acc[i][j] = (f32x4){0.f, 0.f, 0.f, 0.f};

    float4 ar[8], br[8];
#define LOADA_UP(K) do { if (xr) { const float4* p_ = (const float4*)(xr + (K)); \
    _Pragma("unroll") for (int i_ = 0; i_ < 8; ++i_) ar[i_] = p_[i_]; } \
    else { _Pragma("unroll") for (int i_ = 0; i_ < 8; ++i_) ar[i_] = make_float4(0.f,0.f,0.f,0.f); } } while (0)
#define LOADB_RS(K, LDB) do { const float* q_ = bp + (size_t)(K) * (LDB); \
    _Pragma("unroll") for (int r_ = 0; r_ < 8; ++r_) br[r_] = *(const float4*)(q_ + (size_t)r_ * (LDB)); } while (0)
#define CVTWR_A(NB) do { _Pragma("unroll") for (int g_ = 0; g_ < 4; ++g_) { \
    u32 q0_ = pk2(ar[2*g_].x, ar[2*g_].y),   q1_ = pk2(ar[2*g_].z, ar[2*g_].w); \
    u32 q2_ = pk2(ar[2*g_+1].x, ar[2*g_+1].y), q3_ = pk2(ar[2*g_+1].z, ar[2*g_+1].w); \
    *(uint4*)&Abuf[NB][swz(arow, ac0 + 8*g_)] = make_uint4(q0_,q1_,q2_,q3_); } } while (0)
#define CVTWR_B(NB) do { \
    { u32 q0_=pk2(br[0].x,br[1].x),q1_=pk2(br[2].x,br[3].x),q2_=pk2(br[4].x,br[5].x),q3_=pk2(br[6].x,br[7].x); \
      *(uint4*)&Bbuf[NB][swz((bn<<2)+0, bk0)] = make_uint4(q0_,q1_,q2_,q3_); } \
    { u32 q0_=pk2(br[0].y,br[1].y),q1_=pk2(br[2].y,br[3].y),q2_=pk2(br[4].y,br[5].y),q3_=pk2(br[6].y,br[7].y); \
      *(uint4*)&Bbuf[NB][swz((bn<<2)+1, bk0)] = make_uint4(q0_,q1_,q2_,q3_); } \
    { u32 q0_=pk2(br[0].z,br[1].z),q1_=pk2(br[2].z,br[3].z),q2_=pk2(br[4].z,br[5].z),q3_=pk2(br[6].z,br[7].z); \
      *(uint4*)&Bbuf[NB][swz((bn<<2)+2, bk0)] = make_uint4(q0_,q1_,q2_,q3_); } \
    { u32 q0_=pk2(br[0].w,br[1].w),q1_=pk2(br[2].w,br[3].w),q2_=pk2(br[4].w,br[5].w),q3_=pk2(br[6].w,br[7].w); \
      *(uint4*)&Bbuf[NB][swz((bn<<2)+3, bk0)] = make_uint4(q0_,q1_,q2_,q3_); } } while (0)
#define MFMA_RS(CUR) do { _Pragma("unroll") for (int kh_ = 0; kh_ < 2; ++kh_) { \
    int kk_ = (kh_ << 5) | ((lane >> 4) << 3); \
    bf16x8 af_[4], bf_[4]; \
    _Pragma("unroll") for (int mi_ = 0; mi_ < 4; ++mi_) \
      af_[mi_] = *(const bf16x8*)&Abuf[CUR][swz(wm + (mi_ << 4) + (lane & 15), kk_)]; \
    _Pragma("unroll") for (int ni_ = 0; ni_ < 4; ++ni_) \
      bf_[ni_] = *(const bf16x8*)&Bbuf[CUR][swz(wn + (ni_ << 4) + (lane & 15), kk_)]; \
    _Pragma("unroll") for (int mi_ = 0; mi_ < 4; ++mi_) \
      _Pragma("unroll") for (int ni_ = 0; ni_ < 4; ++ni_) \
        acc[mi_][ni_] = __builtin_amdgcn_mfma_f32_16x16x32_bf16(af_[mi_], bf_[ni_], acc[mi_][ni_], 0, 0, 0); \
  } } while (0)

    LOADA_UP(0); LOADB_RS(0, ESIZE);
    CVTWR_A(0); CVTWR_B(0);
    __syncthreads();
    int cur = 0;
    for (int k0 = 0; k0 < DMODEL; k0 += 64) {
      bool late = (k0 + 64 >= DMODEL);
      if (!late) { LOADA_UP(k0 + 64); LOADB_RS(k0 + 64, ESIZE); }
      MFMA_RS(cur);
      if (!late) { CVTWR_A(cur ^ 1); CVTWR_B(cur ^ 1); }
      __syncthreads();
      cur ^= 1;
    }

#pragma unroll
    for (int mi = 0; mi < 4; ++mi) {
      int rbase = wm + (mi << 4) + ((lane >> 4) << 2);
#pragma unroll
      for (int rr = 0; rr < 4; ++rr) {
        int r = rbase + rr;
        if (r < rem) {
          float g = gate_l[r];
          u16* so = scores + (size_t)slot_l[r] * ESIZE + nb0 + wn + (lane & 15);
#pragma unroll
          for (int ni = 0; ni < 4; ++ni)
            so[ni << 4] = f2b(fmaxf(acc[mi][ni][rr], 0.f) * g);
        }
      }
    }
#undef LOADA_UP
#undef LOADB_RS
#undef CVTWR_A
#undef CVTWR_B
#undef MFMA_RS
  }
}

__global__ __launch_bounds__(256, 2) void k_down_rs(
    const u16* __restrict__ scores, const float* __restrict__ values,
    const int* __restrict__ cnt, const int* __restrict__ bucket,
    u16* __restrict__ stage, float* __restrict__ out)
{
  int bid = blockIdx.x;
  int pair = bid & 255, mz = bid >> 8;
  int e = pair >> 3, ns = pair & 7;
  int ne = cnt[e];
  if ((mz << 7) >= ne) return;
  int nb0 = ns << 7;
  int tid = threadIdx.x;

  __shared__ __align__(16) u16 Abuf[2][128 * 72];
  __shared__ __align__(16) u16 Bbuf[2][128 * 72];
  __shared__ int slot_l[128];

  const float* Vb = values + (size_t)e * (ESIZE * DMODEL) + nb0;
  int arow = tid >> 1, ac0 = (tid & 1) << 5;
  int bn = tid & 31, bk0 = (tid >> 5) << 3;
  int lane = tid & 63, w = tid >> 6;
  int wm = (w >> 1) << 6, wn = (w & 1) << 6;

  for (int mt = mz; (mt << 7) < ne; mt += 2) {
    int row0 = mt << 7;
    int rem = ne - row0; if (rem > 128) rem = 128;
    __syncthreads();
    if (tid < 128) {
      int slot = -1;
      if (tid < rem) slot = bucket[e * TOKENS + row0 + tid];
      slot_l[tid] = slot;
    }
    __syncthreads();

    int aslot = slot_l[arow];
    const u16* sr = (aslot >= 0) ? (scores + (size_t)aslot * ESIZE + ac0) : nullptr;
    const float* bp = Vb + (size_t)bk0 * DMODEL + (bn << 2);

    f32x4 acc[4][4];
#pragma unroll
    for (int i = 0; i < 4; ++i)
#pragma unroll
      for (int j = 0; j < 4; ++j) acc[i][j] = (f32x4){0.f, 0.f, 0.f, 0.f};

    uint4 a4[4]; float4 br[8];
#define LOADA_DN(K) do { if (sr) { const uint4* p_ = (const uint4*)(sr + (K)); \
    _Pragma("unroll") for (int i_ = 0; i_ < 4; ++i_) a4[i_] = p_[i_]; } \
    else { _Pragma("unroll") for (int i_ = 0; i_ < 4; ++i_) a4[i_] = make_uint4(0,0,0,0); } } while (0)
#define LOADB_RS(K, LDB) do { const float* q_ = bp + (size_t)(K) * (LDB); \
    _Pragma("unroll") for (int r_ = 0; r_ < 8; ++r_) br[r_] = *(const float4*)(q_ + (size_t)r_ * (LDB)); } while (0)
#define WR_A(NB) do { _Pragma("unroll") for (int g_ = 0; g_ < 4; ++g_) \
    *(uint4*)&Abuf[NB][swz(arow, ac0 + 8*g_)] = a4[g_]; } while (0)
#define CVTWR_B(NB) do { \
    { u32 q0_=pk2(br[0].x,br[1].x),q1_=pk2(br[2].x,br[3].x),q2_=pk2(br[4].x,br[5].x),q3_=pk2(br[6].x,br[7].x); \
      *(uint4*)&Bbuf[NB][swz((bn<<2)+0, bk0)] = make_uint4(q0_,q1_,q2_,q3_); } \
    { u32 q0_=pk2(br[0].y,br[1].y),q1_=pk2(br[2].y,br[3].y),q2_=pk2(br[4].y,br[5].y),q3_=pk2(br[6].y,br[7].y); \
      *(uint4*)&Bbuf[NB][swz((bn<<2)+1, bk0)] = make_uint4(q0_,q1_,q2_,q3_); } \
    { u32 q0_=pk2(br[0].z,br[1].z),q1_=pk2(br[2].z,br[3].z),q2_=pk2(br[4].z,br[5].z),q3_=pk2(br[6].z,br[7].z); \
      *(uint4*)&Bbuf[NB][swz((bn<<2)+2, bk0)] = make_uint4(q0_,q1_,q2_,q3_); } \
    { u32 q0_=pk2(br[0].w,br[1].w),q1_=pk2(br[2].w,br[3].w),q2_=pk2(br[4].w,br[5].w),q3_=pk2(br[6].w,br[7].w); \
      *(uint4*)&Bbuf[NB][swz((bn<<2)+3, bk0)] = make_uint4(q0_,q1_,q2_,q3_); } } while (0)
#define MFMA_RS(CUR) do { _Pragma("unroll") for (int kh_ = 0; kh_ < 2; ++kh_) { \
    int kk_ = (kh_ << 5) | ((lane >> 4) << 3); \
    bf16x8 af_[4], bf_[4]; \
    _Pragma("unroll") for (int mi_ = 0; mi_ < 4; ++mi_) \
      af_[mi_] = *(const bf16x8*)&Abuf[CUR][swz(wm + (mi_ << 4) + (lane & 15), kk_)]; \
    _Pragma("unroll") for (int ni_ = 0; ni_ < 4; ++ni_) \
      bf_[ni_] = *(const bf16x8*)&Bbuf[CUR][swz(wn + (ni_ << 4) + (lane & 15), kk_)]; \
    _Pragma("unroll") for (int mi_ = 0; mi_ < 4; ++mi_) \
      _Pragma("unroll") for (int ni_ = 0; ni_ < 4; ++ni_) \
        acc[mi_][ni_] = __builtin_amdgcn_mfma_f32_16x16x32_bf16(af_[mi_], bf_[ni_], acc[mi_][ni_], 0, 0, 0); \
  } } while (0)

    LOADA_DN(0); LOADB_RS(0, DMODEL);
    WR_A(0); CVTWR_B(0);
    __syncthreads();
    int cur = 0;
    for (int k0 = 0; k0 < ESIZE; k0 += 64) {
      bool late = (k0 + 64 >= ESIZE);
      if (!late) { LOADA_DN(k0 + 64); LOADB_RS(k0 + 64, DMODEL); }
      MFMA_RS(cur);
      if (!late) { WR_A(cur ^ 1); CVTWR_B(cur ^ 1); }
      __syncthreads();
      cur ^= 1;
    }

#pragma unroll
    for (int mi = 0; mi < 4; ++mi) {
      int rbase = wm + (mi << 4) + ((lane >> 4) << 2);
#pragma unroll
      for (int rr = 0; rr < 4; ++rr) {
        int r = rbase + rr;
        if (r < rem) {
          if (stage) {
            u16* so = stage + (size_t)slot_l[r] * DMODEL + nb0 + wn + (lane & 15);
#pragma unroll
            for (int ni = 0; ni < 4; ++ni)
              so[ni << 4] = f2b(acc[mi][ni][rr]);
          } else {
            int t = slot_l[r] >> 2;
            float* oo = out + (size_t)t * DMODEL + nb0 + wn + (lane & 15);
#pragma unroll
            for (int ni = 0; ni < 4; ++ni)
              atomicAdd(&oo[ni << 4], acc[mi][ni][rr]);
          }
        }
      }
    }
#undef LOADA_DN
#undef LOADB_RS
#undef WR_A
#undef CVTWR_B
#undef MFMA_RS
  }
}

extern "C" void kernel_launch(void* const* d_in, const int* in_sizes, int n_in,
                              void* d_out, int out_size, void* d_ws, size_t ws_size,
                              hipStream_t stream) {
  (void)in_sizes; (void)n_in;
  const float* x      = (const float*)d_in[0];
  const float* keys   = (const float*)d_in[1];
  const float* values = (const float*)d_in[2];
  const float* es     = (const float*)d_in[3];
  float* out = (float*)d_out;

  char* W = (char*)d_ws;
  int*   cnt       = (int*)W;                        // 128 B
  u16*   zeros     = (u16*)(W + 4 * 1024);           // 4 KB
  u32*   selpk     = (u32*)(W + 16 * 1024);          // 16 KB
  float* selval    = (float*)(W + 64 * 1024);        // 64 KB
  float* blockpart = (float*)(W + 128 * 1024);       // 128 KB
  int*   bucket    = (int*)(W + 512 * 1024);         // 512 KB
  float* esT4      = (float*)(W + 1280 * 1024);      // 128 KB f32 [256][32][4]

  bool big = ws_size >= (90ull << 20);
  u16* xb = big ? (u16*)(W + 2ull * 1024 * 1024) : nullptr;  // 8 MB bf16 [4096][1024]

  k_esT<<<32, 256, 0, stream>>>(es, esT4);
  k_route<<<TOKENS / 4, 256, 0, stream>>>(x, esT4, selval, selpk, blockpart, xb);
  k_count<<<1, 1024, 0, stream>>>(selpk, cnt, bucket);
  k_fin<<<1, 256, 0, stream>>>(blockpart, out + (size_t)out_size - 1);

  if (big) {
    u16* scores = (u16*)(W + 10ull * 1024 * 1024);   // 16 MB bf16 [16384][512]
    u16* kb     = (u16*)(W + 26ull * 1024 * 1024);   // 32 MB bf16 [32][512][1024]
    u16* vb     = (u16*)(W + 58ull * 1024 * 1024);   // 32 MB bf16 [32][1024][512]
    u16* stage  = kb;  // aliases kb: kb dead after k_up, stage written by k_down
    hipMemsetAsync(zeros, 0, 4096, stream);
    k_tr<<<dim3(ESIZE / 64, DMODEL / 64, NEXP), 256, 0, stream>>>(keys, kb, DMODEL, ESIZE);
    k_tr<<<dim3(DMODEL / 64, ESIZE / 64, NEXP), 256, 0, stream>>>(values, vb, ESIZE, DMODEL);
    k_up<<<512, 256, 0, stream>>>(xb, kb, selval, cnt, bucket, zeros, scores);
    k_down<<<512, 256, 0, stream>>>(scores, vb, cnt, bucket, zeros, stage);
    k_final<<<TOKENS / 2, 256, 0, stream>>>(stage, out);
  } else {
    u16* scores = (u16*)(W + 2ull * 1024 * 1024);
    bool big50 = ws_size >= (50ull << 20);
    u16* stage = big50 ? (u16*)(W + 18ull * 1024 * 1024) : nullptr;
    if (!big50)
      hipMemsetAsync(d_out, 0, (size_t)out_size * sizeof(float), stream);
    k_up_rs<<<512, 256, 0, stream>>>(x, keys, selval, cnt, bucket, scores);
    k_down_rs<<<512, 256, 0, stream>>>(scores, values, cnt, bucket, stage, out);
    if (big50)
      k_final<<<TOKENS / 2, 256, 0, stream>>>(stage, out);
  }
}

// Round 7
// 201.425 us; speedup vs baseline: 2.5945x; 1.0740x over previous
//
#include <hip/hip_runtime.h>
#include <hip/hip_bf16.h>

typedef unsigned short u16;
typedef unsigned int u32;
typedef __attribute__((ext_vector_type(4))) float f32x4;
typedef __attribute__((ext_vector_type(8))) short bf16x8;

#define TOKENS 4096
#define DMODEL 1024
#define NEXP 32
#define ESIZE 512

// round-to-nearest-even f32 -> bf16 bits
__device__ __forceinline__ u16 f2b(float f) {
  union { float f; u32 u; } v; v.f = f;
  u32 u = v.u;
  return (u16)((u + 0x7fffu + ((u >> 16) & 1u)) >> 16);
}

// packed f32x2 -> bf16x2
__device__ __forceinline__ u32 pk2(float a, float b) {
  union { __hip_bfloat162 h; u32 u; } v;
  v.h = __float22bfloat162_rn(make_float2(a, b));
  return v.u;
}

__device__ __forceinline__ float blo(u32 w) { union { u32 u; float f; } v; v.u = w << 16; return v.f; }
__device__ __forceinline__ float bhi(u32 w) { union { u32 u; float f; } v; v.u = w & 0xffff0000u; return v.f; }

// async global->LDS, 16B per lane; LDS dest = wave-uniform base + lane*16
typedef __attribute__((address_space(1))) const void as1_void;
typedef __attribute__((address_space(3))) void as3_void;
__device__ __forceinline__ void gl16(const void* g, void* l) {
  __builtin_amdgcn_global_load_lds((as1_void*)g, (as3_void*)l, 16, 0, 0);
}

// legacy swizzle for fallback kernels
__device__ __forceinline__ int swz(int row, int kk) {
  return row * 72 + ((((kk >> 3) ^ (row >> 2)) & 7) << 3) + (kk & 7);
}

// ---------------- es transpose: esT4[dblk][e][j] = es[e][4*dblk+j] ----------------
__global__ __launch_bounds__(256) void k_esT(const float* __restrict__ es,
                                             float* __restrict__ esT4)
{
  int tid = threadIdx.x;
  int dblk = (blockIdx.x << 3) + (tid >> 5);
  int e = tid & 31;
  float4 v = *(const float4*)(es + (size_t)e * DMODEL + (dblk << 2));
  *((float4*)esT4 + (size_t)dblk * 32 + e) = v;
}

// ---------------- routing: 8 tokens/wave, es reuse; fused x->bf16 epilogue ----------------
// esT4 layout: float4[256 dblk][32 e]. Per iteration: one 512B es slice reused by
// 8 broadcast x loads (9 independent loads in flight -> latency amortized).
__global__ __launch_bounds__(128) void k_route(
    const float* __restrict__ x, const float* __restrict__ esT4,
    float* __restrict__ selval, u32* __restrict__ selpk,
    float* __restrict__ blockpart, u16* __restrict__ xb)
{
  __shared__ float ps[2][32];
  int tid = threadIdx.x;
  int w = tid >> 6, lane = tid & 63;
  int e = lane & 31, half = lane >> 5;
  int t0 = (blockIdx.x << 4) + (w << 3);   // this wave's 8 tokens

  const float4* er = (const float4*)esT4 + ((size_t)half * 128) * 32 + e;
  const float4* xr = (const float4*)(x + ((size_t)t0 << 10)) + (half << 7);

  float acc[8];
#pragma unroll
  for (int tk = 0; tk < 8; ++tk) acc[tk] = 0.f;

#pragma unroll 2
  for (int i = 0; i < 128; ++i) {
    float4 b = er[(size_t)i * 32];
#pragma unroll
    for (int tk = 0; tk < 8; ++tk) {
      float4 a = xr[(tk << 8) + i];
      acc[tk] += a.x * b.x + a.y * b.y + a.z * b.z + a.w * b.w;
    }
  }

  float psum = 0.f;
#pragma unroll
  for (int tk = 0; tk < 8; ++tk) {
    int t = t0 + tk;
    float r = acc[tk] + __shfl_xor(acc[tk], 32);

    float m = r;
#pragma unroll
    for (int mk = 16; mk; mk >>= 1) m = fmaxf(m, __shfl_xor(m, mk));
    float sx = __expf(r - m);
#pragma unroll
    for (int mk = 16; mk; mk >>= 1) sx += __shfl_xor(sx, mk);
    psum += __expf(r - (m + __logf(sx)));

    u32 packed = 0;
    float v = r;
#pragma unroll
    for (int it = 0; it < 4; ++it) {
      float bv = v; int bi = e;
#pragma unroll
      for (int mk = 16; mk; mk >>= 1) {
        float ov = __shfl_xor(bv, mk); int oi = __shfl_xor(bi, mk);
        if (ov > bv || (ov == bv && oi < bi)) { bv = ov; bi = oi; }
      }
      packed |= (u32)bi << (8 * it);
      if (lane == it) selval[t * 4 + it] = 1.f / (1.f + __expf(-bv));
      if (e == bi) v = -3.0e38f;
    }
    if (lane == 0) selpk[t] = packed;
  }
  if (!half) ps[w][e] = psum;
  __syncthreads();
  if (tid < 32)
    blockpart[blockIdx.x * 32 + tid] = ps[0][tid] + ps[1][tid];

  // fused x -> bf16 for this block's 16 rows (coalesced, no divergence)
  if (xb) {
    const float4* src = (const float4*)x + ((size_t)blockIdx.x << 12);
    u16* dst = xb + ((size_t)blockIdx.x << 14);
#pragma unroll
    for (int j = 0; j < 32; ++j) {
      int idx = (j << 7) + tid;
      float4 a = src[idx];
      *(uint2*)(dst + (idx << 2)) = make_uint2(pk2(a.x, a.y), pk2(a.z, a.w));
    }
  }
}

// ---------------- bucket build ----------------
__global__ __launch_bounds__(1024) void k_count(
    const u32* __restrict__ selpk, int* __restrict__ cnt, int* __restrict__ bucket)
{
  __shared__ int cl[32];
  int tid = threadIdx.x;
  if (tid < 32) cl[tid] = 0;
  __syncthreads();
  int ex[16], pos[16];
#pragma unroll
  for (int j = 0; j < 4; ++j) {
    int t = tid + (j << 10);
    u32 pk = selpk[t];
#pragma unroll
    for (int h = 0; h < 4; ++h) {
      int e = (pk >> (8 * h)) & 0xff;
      ex[j * 4 + h] = e;
      pos[j * 4 + h] = atomicAdd(&cl[e], 1);
    }
  }
#pragma unroll
  for (int j = 0; j < 4; ++j) {
    int t = tid + (j << 10);
#pragma unroll
    for (int h = 0; h < 4; ++h)
      bucket[ex[j * 4 + h] * TOKENS + pos[j * 4 + h]] = (t << 2) | h;
  }
  __syncthreads();
  if (tid < 32) cnt[tid] = cl[tid];
}

// ---------------- entropy regularizer ----------------
__global__ __launch_bounds__(256) void k_fin(const float* __restrict__ blockpart,
                                             float* __restrict__ out_reg)
{
  __shared__ float part[8][32];
  int tid = threadIdx.x;
  int e = tid & 31, c = tid >> 5;
  float s = 0.f;
  for (int b = c; b < 256; b += 8) s += blockpart[b * 32 + e];
  part[c][e] = s;
  __syncthreads();
  if (tid < 32) {
    float S = 0.f;
#pragma unroll
    for (int i = 0; i < 8; ++i) S += part[i][tid];
    float Pm = S * (1.0f / TOKENS);
    float rp = __logf(Pm) * Pm;
#pragma unroll
    for (int mk = 16; mk; mk >>= 1) rp += __shfl_xor(rp, mk);
    if (tid == 0) *out_reg = rp;
  }
}

// ---------------- transpose-convert: src f32 [E][R][C] -> dst bf16 [E][C][R] ----------------
__global__ __launch_bounds__(256) void k_tr(const float* __restrict__ src,
                                            u16* __restrict__ dst, int R, int C)
{
  __shared__ float tile[64][68];
  int e = blockIdx.z;
  int r0 = blockIdx.y << 6, c0 = blockIdx.x << 6;
  int t = threadIdx.x;
  int rr = t >> 2, cb = (t & 3) << 4;
  const float* sp = src + ((size_t)e * R + r0 + rr) * C + c0 + cb;
#pragma unroll
  for (int j = 0; j < 4; ++j)
    *(float4*)&tile[rr][cb + (j << 2)] = *(const float4*)(sp + (j << 2));
  __syncthreads();
  int wr = t >> 2, wb = (t & 3) << 4;
  u32 q[8];
#pragma unroll
  for (int j = 0; j < 8; ++j)
    q[j] = pk2(tile[wb + (j << 1)][wr], tile[wb + (j << 1) + 1][wr]);
  u16* dp = dst + ((size_t)e * C + c0 + wr) * R + r0 + wb;
  *(uint4*)dp = make_uint4(q[0], q[1], q[2], q[3]);
  *(uint4*)(dp + 8) = make_uint4(q[4], q[5], q[6], q[7]);
}

// ======== fast GEMMs: global_load_lds staging, XOR-granule swizzle, 2-phase dbuf ========
#define GEMM_MACROS                                                                          \
  int wm = (w >> 1) << 6, wn = (w & 1) << 6;                                                 \
  int w32 = w << 5;                                                                          \
  int lg16 = (((l & 7) ^ (l >> 3)) << 4);

#define STAGE(BUF, K0) do {                                                                  \
  _Pragma("unroll") for (int i_ = 0; i_ < 4; ++i_)                                           \
    gl16(gA[i_] + ((K0) << 1), (void*)&Ab[BUF][(((w << 2) + i_) << 9)]);                     \
  _Pragma("unroll") for (int i_ = 0; i_ < 4; ++i_)                                           \
    gl16(gB[i_] + ((K0) << 1), (void*)&Bb[BUF][(((w << 2) + i_) << 9)]);                     \
} while (0)

#define COMPUTE(CUR) do {                                                                    \
  _Pragma("unroll") for (int kh_ = 0; kh_ < 2; ++kh_) {                                      \
    bf16x8 af_[4], bf_[4];                                                                   \
    int gg_ = (kh_ << 2) + (l >> 4);                                                         \
    _Pragma("unroll") for (int mi_ = 0; mi_ < 4; ++mi_) {                                    \
      int row_ = wm + (mi_ << 4) + (l & 15);                                                 \
      af_[mi_] = *(const bf16x8*)&Ab[CUR][(row_ << 6) + ((gg_ ^ (row_ & 7)) << 3)];          \
    }                                                                                        \
    _Pragma("unroll") for (int ni_ = 0; ni_ < 4; ++ni_) {                                    \
      int row_ = wn + (ni_ << 4) + (l & 15);                                                 \
      bf_[ni_] = *(const bf16x8*)&Bb[CUR][(row_ << 6) + ((gg_ ^ (row_ & 7)) << 3)];          \
    }                                                                                        \
    _Pragma("unroll") for (int mi_ = 0; mi_ < 4; ++mi_)                                      \
      _Pragma("unroll") for (int ni_ = 0; ni_ < 4; ++ni_)                                    \
        acc[mi_][ni_] = __builtin_amdgcn_mfma_f32_16x16x32_bf16(af_[mi_], bf_[ni_],          \
                                                                acc[mi_][ni_], 0, 0, 0);     \
  }                                                                                          \
} while (0)

#define VM0_BAR() do {                                                                       \
  asm volatile("s_waitcnt vmcnt(0)" ::: "memory");                                           \
  asm volatile("s_barrier" ::: "memory");                                                    \
} while (0)

// XCD-affine decode: bid = ((e>>3)*16 + sub)*8 + (e&7)
// -> all 16 blocks of an expert land on one XCD (round-robin bid%8 = XCD heuristic).
#define XCD_DECODE(SUB_NS_BITS)                                                              \
  int bid = blockIdx.x;                                                                      \
  int q_ = bid >> 3, sub_ = q_ & 15;                                                         \
  int e = ((q_ >> 4) << 3) | (bid & 7);                                                      \
  int ns = sub_ & ((1 << (SUB_NS_BITS)) - 1);                                                \
  int mz = sub_ >> (SUB_NS_BITS);

// ---------------- up-projection: scores[slot] = relu(xb[t] @ kb[e]^T) * gate ----------------
__global__ __launch_bounds__(256, 2) void k_up(
    const u16* __restrict__ xb, const u16* __restrict__ kb,
    const float* __restrict__ selval, const int* __restrict__ cnt,
    const int* __restrict__ bucket, const u16* __restrict__ zeros,
    u16* __restrict__ scores)
{
  XCD_DECODE(2);                       // 4 ns x 4 mz
  int ne = cnt[e];
  if ((mz << 7) >= ne) return;
  int nb0 = ns << 7;
  int tid = threadIdx.x, l = tid & 63, w = tid >> 6;

  __shared__ __align__(16) u16 Ab[2][8192];
  __shared__ __align__(16) u16 Bb[2][8192];
  __shared__ int slot_l[128];
  __shared__ float gate_l[128];

  GEMM_MACROS;

  const char* gB[4];
#pragma unroll
  for (int i = 0; i < 4; ++i) {
    int n = nb0 + w32 + (i << 3) + (l >> 3);
    gB[i] = (const char*)(kb + ((size_t)e * ESIZE + n) * DMODEL) + lg16;
  }

  for (int mt = mz; (mt << 7) < ne; mt += 4) {
    int row0 = mt << 7;
    int rem = ne - row0; if (rem > 128) rem = 128;
    __syncthreads();
    if (tid < 128) {
      int slot = -1; float g = 0.f;
      if (tid < rem) { slot = bucket[e * TOKENS + row0 + tid]; g = selval[slot]; }
      slot_l[tid] = slot; gate_l[tid] = g;
    }
    __syncthreads();

    const char* gA[4];
#pragma unroll
    for (int i = 0; i < 4; ++i) {
      int s = slot_l[w32 + (i << 3) + (l >> 3)];
      gA[i] = ((s >= 0) ? (const char*)(xb + (size_t)(s >> 2) * DMODEL)
                        : (const char*)zeros) + lg16;
    }

    f32x4 acc[4][4];
#pragma unroll
    for (int i = 0; i < 4; ++i)
#pragma unroll
      for (int j = 0; j < 4; ++j) acc[i][j] = (f32x4){0.f, 0.f, 0.f, 0.f};

    STAGE(0, 0);
    VM0_BAR();
#pragma unroll 1
    for (int t = 0; t < 16; ++t) {
      int cur = t & 1;
      if (t < 15) STAGE(cur ^ 1, (t + 1) << 6);
      COMPUTE(cur);
      VM0_BAR();
    }

#pragma unroll
    for (int mi = 0; mi < 4; ++mi) {
      int rbase = wm + (mi << 4) + ((l >> 4) << 2);
#pragma unroll
      for (int rr = 0; rr < 4; ++rr) {
        int r = rbase + rr;
        if (r < rem) {
          float g = gate_l[r];
          u16* so = scores + (size_t)slot_l[r] * ESIZE + nb0 + wn + (l & 15);
#pragma unroll
          for (int ni = 0; ni < 4; ++ni)
            so[ni << 4] = f2b(fmaxf(acc[mi][ni][rr], 0.f) * g);
        }
      }
    }
  }
}

// ---------------- down-projection: stage[slot] = scores[slot] @ vb[e]^T ----------------
__global__ __launch_bounds__(256, 2) void k_down(
    const u16* __restrict__ scores, const u16* __restrict__ vb,
    const int* __restrict__ cnt, const int* __restrict__ bucket,
    const u16* __restrict__ zeros, u16* __restrict__ stage)
{
  XCD_DECODE(3);                       // 8 ns x 2 mz
  int ne = cnt[e];
  if ((mz << 7) >= ne) return;
  int nb0 = ns << 7;
  int tid = threadIdx.x, l = tid & 63, w = tid >> 6;

  __shared__ __align__(16) u16 Ab[2][8192];
  __shared__ __align__(16) u16 Bb[2][8192];
  __shared__ int slot_l[128];

  GEMM_MACROS;

  const char* gB[4];
#pragma unroll
  for (int i = 0; i < 4; ++i) {
    int n = nb0 + w32 + (i << 3) + (l >> 3);
    gB[i] = (const char*)(vb + ((size_t)e * DMODEL + n) * ESIZE) + lg16;
  }

  for (int mt = mz; (mt << 7) < ne; mt += 2) {
    int row0 = mt << 7;
    int rem = ne - row0; if (rem > 128) rem = 128;
    __syncthreads();
    if (tid < 128) {
      int slot = -1;
      if (tid < rem) slot = bucket[e * TOKENS + row0 + tid];
      slot_l[tid] = slot;
    }
    __syncthreads();

    const char* gA[4];
#pragma unroll
    for (int i = 0; i < 4; ++i) {
      int s = slot_l[w32 + (i << 3) + (l >> 3)];
      gA[i] = ((s >= 0) ? (const char*)(scores + (size_t)s * ESIZE)
                        : (const char*)zeros) + lg16;
    }

    f32x4 acc[4][4];
#pragma unroll
    for (int i = 0; i < 4; ++i)
#pragma unroll
      for (int j = 0; j < 4; ++j) acc[i][j] = (f32x4){0.f, 0.f, 0.f, 0.f};

    STAGE(0, 0);
    VM0_BAR();
#pragma unroll 1
    for (int t = 0; t < 8; ++t) {
      int cur = t & 1;
      if (t < 7) STAGE(cur ^ 1, (t + 1) << 6);
      COMPUTE(cur);
      VM0_BAR();
    }

#pragma unroll
    for (int mi = 0; mi < 4; ++mi) {
      int rbase = wm + (mi << 4) + ((l >> 4) << 2);
#pragma unroll
      for (int rr = 0; rr < 4; ++rr) {
        int r = rbase + rr;
        if (r < rem) {
          u16* so = stage + (size_t)slot_l[r] * DMODEL + nb0 + wn + (l & 15);
#pragma unroll
          for (int ni = 0; ni < 4; ++ni)
            so[ni << 4] = f2b(acc[mi][ni][rr]);
        }
      }
    }
  }
}

// ---------------- final: out[t] = sum_h stage[t*4+h] ----------------
__global__ __launch_bounds__(256) void k_final(const u16* __restrict__ stage,
                                               float* __restrict__ out)
{
  int tid = threadIdx.x;
  int t = (blockIdx.x << 1) + (tid >> 7);
  int d0 = (tid & 127) << 3;
  const u16* r0 = stage + ((size_t)t << 12) + d0;
  uint4 a0 = *(const uint4*)(r0);
  uint4 a1 = *(const uint4*)(r0 + 1024);
  uint4 a2 = *(const uint4*)(r0 + 2048);
  uint4 a3 = *(const uint4*)(r0 + 3072);
  float4 lo4, hi4;
  lo4.x = blo(a0.x) + blo(a1.x) + blo(a2.x) + blo(a3.x);
  lo4.y = bhi(a0.x) + bhi(a1.x) + bhi(a2.x) + bhi(a3.x);
  lo4.z = blo(a0.y) + blo(a1.y) + blo(a2.y) + blo(a3.y);
  lo4.w = bhi(a0.y) + bhi(a1.y) + bhi(a2.y) + bhi(a3.y);
  hi4.x = blo(a0.z) + blo(a1.z) + blo(a2.z) + blo(a3.z);
  hi4.y = bhi(a0.z) + bhi(a1.z) + bhi(a2.z) + bhi(a3.z);
  hi4.z = blo(a0.w) + blo(a1.w) + blo(a2.w) + blo(a3.w);
  hi4.w = bhi(a0.w) + bhi(a1.w) + bhi(a2.w) + bhi(a3.w);
  float* o = out + (size_t)t * DMODEL + d0;
  *(float4*)o = lo4;
  *(float4*)(o + 4) = hi4;
}

// ================= fallback (reg-staged) kernels, used if ws too small =================
__global__ __launch_bounds__(256, 2) void k_up_rs(
    const float* __restrict__ x, const float* __restrict__ keys,
    const float* __restrict__ selval, const int* __restrict__ cnt,
    const int* __restrict__ bucket, u16* __restrict__ scores)
{
  int bid = blockIdx.x;
  int pair = bid & 127, mz = bid >> 7;
  int e = pair >> 2, ns = pair & 3;
  int ne = cnt[e];
  if ((mz << 7) >= ne) return;
  int nb0 = ns << 7;
  int tid = threadIdx.x;

  __shared__ __align__(16) u16 Abuf[2][128 * 72];
  __shared__ __align__(16) u16 Bbuf[2][128 * 72];
  __shared__ int slot_l[128];
  __shared__ float gate_l[128];

  const float* Kb = keys + (size_t)e * (DMODEL * ESIZE) + nb0;
  int arow = tid >> 1, ac0 = (tid & 1) << 5;
  int bn = tid & 31, bk0 = (tid >> 5) << 3;
  int lane = tid & 63, w = tid >> 6;
  int wm = (w >> 1) << 6, wn = (w & 1) << 6;

  for (int mt = mz; (mt << 7) < ne; mt += 4) {
    int row0 = mt << 7;
    int rem = ne - row0; if (rem > 128) rem = 128;
    __syncthreads();
    if (tid < 128) {
      int slot = -1; float g = 0.f;
      if (tid < rem) { slot = bucket[e * TOKENS + row0 + tid]; g = selval[slot]; }
      slot_l[tid] = slot; gate_l[tid] = g;
    }
    __syncthreads();

    int aslot = slot_l[arow];
    const float* xr = (aslot >= 0) ? (x + (size_t)(aslot >> 2) * DMODEL + ac0) : nullptr;
    const float* bp = Kb + (size_t)bk0 * ESIZE + (bn << 2);

    f32x4 acc[4][4];
#pragma unroll
    for (int i = 0; i < 4; ++i)
#pragma unroll
      for (int j = 0; j < 4; ++j) acc[i][j] = (f32x4){0.f, 0.f, 0.f, 0.f};

    float4 ar[8], br[8];
#define LOADA_UP(K) do { if (xr) { const float4* p_ = (const float4*)(xr + (K)); \
    _Pragma("unroll") for (int i_ = 0; i_ < 8; ++i_) ar[i_] = p_[i_]; } \
    else { _Pragma("unroll") for (int i_ = 0; i_ < 8; ++i_) ar[i_] = make_float4(0.f,0.f,0.f,0.f); } } while (0)
#define LOADB_RS(K, LDB) do { const float* q_ = bp + (size_t)(K) * (LDB); \
    _Pragma("unroll") for (int r_ = 0; r_ < 8; ++r_) br[r_] = *(const float4*)(q_ + (size_t)r_ * (LDB)); } while (0)
#define CVTWR_A(NB) do { _Pragma("unroll") for (int g_ = 0; g_ < 4; ++g_) { \
    u32 q0_ = pk2(ar[2*g_].x, ar[2*g_].y),   q1_ = pk2(ar[2*g_].z, ar[2*g_].w); \
    u32 q2_ = pk2(ar[2*g_+1].x, ar[2*g_+1].y), q3_ = pk2(ar[2*g_+1].z, ar[2*g_+1].w); \
    *(uint4*)&Abuf[NB][swz(arow, ac0 + 8*g_)] = make_uint4(q0_,q1_,q2_,q3_); } } while (0)
#define CVTWR_B(NB) do { \
    { u32 q0_=pk2(br[0].x,br[1].x),q1_=pk2(br[2].x,br[3].x),q2_=pk2(br[4].x,br[5].x),q3_=pk2(br[6].x,br[7].x); \
      *(uint4*)&Bbuf[NB][swz((bn<<2)+0, bk0)] = make_uint4(q0_,q1_,q2_,q3_); } \
    { u32 q0_=pk2(br[0].y,br[1].y),q1_=pk2(br[2].y,br[3].y),q2_=pk2(br[4].y,br[5].y),q3_=pk2(br[6].y,br[7].y); \
      *(uint4*)&Bbuf[NB][swz((bn<<2)+1, bk0)] = make_uint4(q0_,q1_,q2_,q3_); } \
    { u32 q0_=pk2(br[0].z,br[1].z),q1_=pk2(br[2].z,br[3].z),q2_=pk2(br[4].z,br[5].z),q3_=pk2(br[6].z,br[7].z); \
      *(uint4*)&Bbuf[NB][swz((bn<<2)+2, bk0)] = make_uint4(q0_,q1_,q2_,q3_); } \
    { u32 q0_=pk2(br[0].w,br[1].w),q1_=pk2(br[2].w,br[3].w),q2_=pk2(br[4].w,br[5].w),q3_=pk2(br[6].w,br[7].w); \
      *(uint4*)&Bbuf[NB][swz((bn<<2)+3, bk0)] = make_uint4(q0_,q1_,q2_,q3_); } } while (0)
#define MFMA_RS(CUR) do { _Pragma("unroll") for (int kh_ = 0; kh_ < 2; ++kh_) { \
    int kk_ = (kh_ << 5) | ((lane >> 4) << 3); \
    bf16x8 af_[4], bf_[4]; \
    _Pragma("unroll") for (int mi_ = 0; mi_ < 4; ++mi_) \
      af_[mi_] = *(const bf16x8*)&Abuf[CUR][swz(wm + (mi_ << 4) + (lane & 15), kk_)]; \
    _Pragma("unroll") for (int ni_ = 0; ni_ < 4; ++ni_) \
      bf_[ni_] = *(const bf16x8*)&Bbuf[CUR][swz(wn + (ni_ << 4) + (lane & 15), kk_)]; \
    _Pragma("unroll") for (int mi_ = 0; mi_ < 4; ++mi_) \
      _Pragma("unroll") for (int ni_ = 0; ni_ < 4; ++ni_) \
        acc[mi_][ni_] = __builtin_amdgcn_mfma_f32_16x16x32_bf16(af_[mi_], bf_[ni_], acc[mi_][ni_], 0, 0, 0); \
  } } while (0)

    LOADA_UP(0); LOADB_RS(0, ESIZE);
    CVTWR_A(0); CVTWR_B(0);
    __syncthreads();
    int cur = 0;
    for (int k0 = 0; k0 < DMODEL; k0 += 64) {
      bool late = (k0 + 64 >= DMODEL);
      if (!late) { LOADA_UP(k0 + 64); LOADB_RS(k0 + 64, ESIZE); }
      MFMA_RS(cur);
      if (!late) { CVTWR_A(cur ^ 1); CVTWR_B(cur ^ 1); }
      __syncthreads();
      cur ^= 1;
    }

#pragma unroll
    for (int mi = 0; mi < 4; ++mi) {
      int rbase = wm + (mi << 4) + ((lane >> 4) << 2);
#pragma unroll
      for (int rr = 0; rr < 4; ++rr) {
        int r = rbase + rr;
        if (r < rem) {
          float g = gate_l[r];
          u16* so = scores + (size_t)slot_l[r] * ESIZE + nb0 + wn + (lane & 15);
#pragma unroll
          for (int ni = 0; ni < 4; ++ni)
            so[ni << 4] = f2b(fmaxf(acc[mi][ni][rr], 0.f) * g);
        }
      }
    }
#undef LOADA_UP
#undef LOADB_RS
#undef CVTWR_A
#undef CVTWR_B
#undef MFMA_RS
  }
}

__global__ __launch_bounds__(256, 2) void k_down_rs(
    const u16* __restrict__ scores, const float* __restrict__ values,
    const int* __restrict__ cnt, const int* __restrict__ bucket,
    u16* __restrict__ stage, float* __restrict__ out)
{
  int bid = blockIdx.x;
  int pair = bid & 255, mz = bid >> 8;
  int e = pair >> 3, ns = pair & 7;
  int ne = cnt[e];
  if ((mz << 7) >= ne) return;
  int nb0 = ns << 7;
  int tid = threadIdx.x;

  __shared__ __align__(16) u16 Abuf[2][128 * 72];
  __shared__ __align__(16) u16 Bbuf[2][128 * 72];
  __shared__ int slot_l[128];

  const float* Vb = values + (size_t)e * (ESIZE * DMODEL) + nb0;
  int arow = tid >> 1, ac0 = (tid & 1) << 5;
  int bn = tid & 31, bk0 = (tid >> 5) << 3;
  int lane = tid & 63, w = tid >> 6;
  int wm = (w >> 1) << 6, wn = (w & 1) << 6;

  for (int mt = mz; (mt << 7) < ne; mt += 2) {
    int row0 = mt << 7;
    int rem = ne - row0; if (rem > 128) rem = 128;
    __syncthreads();
    if (tid < 128) {
      int slot = -1;
      if (tid < rem) slot = bucket[e * TOKENS + row0 + tid];
      slot_l[tid] = slot;
    }
    __syncthreads();

    int aslot = slot_l[arow];
    const u16* sr = (aslot >= 0) ? (scores + (size_t)aslot * ESIZE + ac0) : nullptr;
    const float* bp = Vb + (size_t)bk0 * DMODEL + (bn << 2);

    f32x4 acc[4][4];
#pragma unroll
    for (int i = 0; i < 4; ++i)
#pragma unroll
      for (int j = 0; j < 4; ++j) acc[i][j] = (f32x4){0.f, 0.f, 0.f, 0.f};

    uint4 a4[4]; float4 br[8];
#define LOADA_DN(K) do { if (sr) { const uint4* p_ = (const uint4*)(sr + (K)); \
    _Pragma("unroll") for (int i_ = 0; i_ < 4; ++i_) a4[i_] = p_[i_]; } \
    else { _Pragma("unroll") for (int i_ = 0; i_ < 4; ++i_) a4[i_] = make_uint4(0,0,0,0); } } while (0)
#define LOADB_RS(K, LDB) do { const float* q_ = bp + (size_t)(K) * (LDB); \
    _Pragma("unroll") for (int r_ = 0; r_ < 8; ++r_) br[r_] = *(const float4*)(q_ + (size_t)r_ * (LDB)); } while (0)
#define WR_A(NB) do { _Pragma("unroll") for (int g_ = 0; g_ < 4; ++g_) \
    *(uint4*)&Abuf[NB][swz(arow, ac0 + 8*g_)] = a4[g_]; } while (0)
#define CVTWR_B(NB) do { \
    { u32 q0_=pk2(br[0].x,br[1].x),q1_=pk2(br[2].x,br[3].x),q2_=pk2(br[4].x,br[5].x),q3_=pk2(br[6].x,br[7].x); \
      *(uint4*)&Bbuf[NB][swz((bn<<2)+0, bk0)] = make_uint4(q0_,q1_,q2_,q3_); } \
    { u32 q0_=pk2(br[0].y,br[1].y),q1_=pk2(br[2].y,br[3].y),q2_=pk2(br[4].y,br[5].y),q3_=pk2(br[6].y,br[7].y); \
      *(uint4*)&Bbuf[NB][swz((bn<<2)+1, bk0)] = make_uint4(q0_,q1_,q2_,q3_); } \
    { u32 q0_=pk2(br[0].z,br[1].z),q1_=pk2(br[2].z,br[3].z),q2_=pk2(br[4].z,br[5].z),q3_=pk2(br[6].z,br[7].z); \
      *(uint4*)&Bbuf[NB][swz((bn<<2)+2, bk0)] = make_uint4(q0_,q1_,q2_,q3_); } \
    { u32 q0_=pk2(br[0].w,br[1].w),q1_=pk2(br[2].w,br[3].w),q2_=pk2(br[4].w,br[5].w),q3_=pk2(br[6].w,br[7].w); \
      *(uint4*)&Bbuf[NB][swz((bn<<2)+3, bk0)] = make_uint4(q0_,q1_,q2_,q3_); } } while (0)
#define MFMA_RS(CUR) do { _Pragma("unroll") for (int kh_ = 0; kh_ < 2; ++kh_) { \
    int kk_ = (kh_ << 5) | ((lane >> 4) << 3); \
    bf16x8 af_[4], bf_[4]; \
    _Pragma("unroll") for (int mi_ = 0; mi_ < 4; ++mi_) \
      af_[mi_] = *(const bf16x8*)&Abuf[CUR][swz(wm + (mi_ << 4) + (lane & 15), kk_)]; \
    _Pragma("unroll") for (int ni_ = 0; ni_ < 4; ++ni_) \
      bf_[ni_] = *(const bf16x8*)&Bbuf[CUR][swz(wn + (ni_ << 4) + (lane & 15), kk_)]; \
    _Pragma("unroll") for (int mi_ = 0; mi_ < 4; ++mi_) \
      _Pragma("unroll") for (int ni_ = 0; ni_ < 4; ++ni_) \
        acc[mi_][ni_] = __builtin_amdgcn_mfma_f32_16x16x32_bf16(af_[mi_], bf_[ni_], acc[mi_][ni_], 0, 0, 0); \
  } } while (0)

    LOADA_DN(0); LOADB_RS(0, DMODEL);
    WR_A(0); CVTWR_B(0);
    __syncthreads();
    int cur = 0;
    for (int k0 = 0; k0 < ESIZE; k0 += 64) {
      bool late = (k0 + 64 >= ESIZE);
      if (!late) { LOADA_DN(k0 + 64); LOADB_RS(k0 + 64, DMODEL); }
      MFMA_RS(cur);
      if (!late) { WR_A(cur ^ 1); CVTWR_B(cur ^ 1); }
      __syncthreads();
      cur ^= 1;
    }

#pragma unroll
    for (int mi = 0; mi < 4; ++mi) {
      int rbase = wm + (mi << 4) + ((lane >> 4) << 2);
#pragma unroll
      for (int rr = 0; rr < 4; ++rr) {
        int r = rbase + rr;
        if (r < rem) {
          if (stage) {
            u16* so = stage + (size_t)slot_l[r] * DMODEL + nb0 + wn + (lane & 15);
#pragma unroll
            for (int ni = 0; ni < 4; ++ni)
              so[ni << 4] = f2b(acc[mi][ni][rr]);
          } else {
            int t = slot_l[r] >> 2;
            float* oo = out + (size_t)t * DMODEL + nb0 + wn + (lane & 15);
#pragma unroll
            for (int ni = 0; ni < 4; ++ni)
              atomicAdd(&oo[ni << 4], acc[mi][ni][rr]);
          }
        }
      }
    }
#undef LOADA_DN
#undef LOADB_RS
#undef WR_A
#undef CVTWR_B
#undef MFMA_RS
  }
}

extern "C" void kernel_launch(void* const* d_in, const int* in_sizes, int n_in,
                              void* d_out, int out_size, void* d_ws, size_t ws_size,
                              hipStream_t stream) {
  (void)in_sizes; (void)n_in;
  const float* x      = (const float*)d_in[0];
  const float* keys   = (const float*)d_in[1];
  const float* values = (const float*)d_in[2];
  const float* es     = (const float*)d_in[3];
  float* out = (float*)d_out;

  char* W = (char*)d_ws;
  int*   cnt       = (int*)W;                        // 128 B
  u16*   zeros     = (u16*)(W + 4 * 1024);           // 4 KB
  u32*   selpk     = (u32*)(W + 16 * 1024);          // 16 KB
  float* selval    = (float*)(W + 64 * 1024);        // 64 KB
  float* blockpart = (float*)(W + 128 * 1024);       // 32 KB f32 [256][32]
  int*   bucket    = (int*)(W + 512 * 1024);         // 512 KB
  float* esT4      = (float*)(W + 1280 * 1024);      // 128 KB f32 [256][32][4]

  bool big = ws_size >= (90ull << 20);
  u16* xb = big ? (u16*)(W + 2ull * 1024 * 1024) : nullptr;  // 8 MB bf16 [4096][1024]

  k_esT<<<32, 256, 0, stream>>>(es, esT4);
  k_route<<<TOKENS / 16, 128, 0, stream>>>(x, esT4, selval, selpk, blockpart, xb);
  k_count<<<1, 1024, 0, stream>>>(selpk, cnt, bucket);
  k_fin<<<1, 256, 0, stream>>>(blockpart, out + (size_t)out_size - 1);

  if (big) {
    u16* scores = (u16*)(W + 10ull * 1024 * 1024);   // 16 MB bf16 [16384][512]
    u16* kb     = (u16*)(W + 26ull * 1024 * 1024);   // 32 MB bf16 [32][512][1024]
    u16* vb     = (u16*)(W + 58ull * 1024 * 1024);   // 32 MB bf16 [32][1024][512]
    u16* stage  = kb;  // aliases kb: kb dead after k_up, stage written by k_down
    hipMemsetAsync(zeros, 0, 4096, stream);
    k_tr<<<dim3(ESIZE / 64, DMODEL / 64, NEXP), 256, 0, stream>>>(keys, kb, DMODEL, ESIZE);
    k_tr<<<dim3(DMODEL / 64, ESIZE / 64, NEXP), 256, 0, stream>>>(values, vb, ESIZE, DMODEL);
    k_up<<<512, 256, 0, stream>>>(xb, kb, selval, cnt, bucket, zeros, scores);
    k_down<<<512, 256, 0, stream>>>(scores, vb, cnt, bucket, zeros, stage);
    k_final<<<TOKENS / 2, 256, 0, stream>>>(stage, out);
  } else {
    u16* scores = (u16*)(W + 2ull * 1024 * 1024);
    bool big50 = ws_size >= (50ull << 20);
    u16* stage = big50 ? (u16*)(W + 18ull * 1024 * 1024) : nullptr;
    if (!big50)
      hipMemsetAsync(d_out, 0, (size_t)out_size * sizeof(float), stream);
    k_up_rs<<<512, 256, 0, stream>>>(x, keys, selval, cnt, bucket, scores);
    k_down_rs<<<512, 256, 0, stream>>>(scores, values, cnt, bucket, stage, out);
    if (big50)
      k_final<<<TOKENS / 2, 256, 0, stream>>>(stage, out);
  }
}

// Round 8
// 174.936 us; speedup vs baseline: 2.9873x; 1.1514x over previous
//
#include <hip/hip_runtime.h>
#include <hip/hip_bf16.h>

typedef unsigned short u16;
typedef unsigned int u32;
typedef __attribute__((ext_vector_type(4))) float f32x4;
typedef __attribute__((ext_vector_type(8))) short bf16x8;

#define TOKENS 4096
#define DMODEL 1024
#define NEXP 32
#define ESIZE 512

// round-to-nearest-even f32 -> bf16 bits
__device__ __forceinline__ u16 f2b(float f) {
  union { float f; u32 u; } v; v.f = f;
  u32 u = v.u;
  return (u16)((u + 0x7fffu + ((u >> 16) & 1u)) >> 16);
}

// packed f32x2 -> bf16x2
__device__ __forceinline__ u32 pk2(float a, float b) {
  union { __hip_bfloat162 h; u32 u; } v;
  v.h = __float22bfloat162_rn(make_float2(a, b));
  return v.u;
}

__device__ __forceinline__ float blo(u32 w) { union { u32 u; float f; } v; v.u = w << 16; return v.f; }
__device__ __forceinline__ float bhi(u32 w) { union { u32 u; float f; } v; v.u = w & 0xffff0000u; return v.f; }

// async global->LDS, 16B per lane; LDS dest = wave-uniform base + lane*16
typedef __attribute__((address_space(1))) const void as1_void;
typedef __attribute__((address_space(3))) void as3_void;
__device__ __forceinline__ void gl16(const void* g, void* l) {
  __builtin_amdgcn_global_load_lds((as1_void*)g, (as3_void*)l, 16, 0, 0);
}

// legacy swizzle for fallback kernels
__device__ __forceinline__ int swz(int row, int kk) {
  return row * 72 + ((((kk >> 3) ^ (row >> 2)) & 7) << 3) + (kk & 7);
}

// ---------------- es transpose: esT4[dblk][e][j] = es[e][4*dblk+j] ----------------
__global__ __launch_bounds__(256) void k_esT(const float* __restrict__ es,
                                             float* __restrict__ esT4)
{
  int tid = threadIdx.x;
  int dblk = (blockIdx.x << 3) + (tid >> 5);
  int e = tid & 31;
  float4 v = *(const float4*)(es + (size_t)e * DMODEL + (dblk << 2));
  *((float4*)esT4 + (size_t)dblk * 32 + e) = v;
}

// ---------------- routing: K-split across 4 waves, 8 tokens/block ----------------
// Wave w computes K-quarter [w*256,(w+1)*256) of all 8 token dots (lane=expert,
// h=K-eighth). Per iter: 1 coalesced 512B es load + 8 broadcast x loads -> 9-deep ILP.
// Phase 2: tid -> (token tk = tid>>5, expert ge = tid&31), f32 softmax/top-4 in
// aligned 32-lane groups (shfl_xor masks <=16 stay in-group).
__global__ __launch_bounds__(256) void k_route(
    const float* __restrict__ x, const float* __restrict__ esT4,
    float* __restrict__ selval, u32* __restrict__ selpk,
    float* __restrict__ blockpart, u16* __restrict__ xb)
{
  __shared__ float part[4][8][32];
  __shared__ float ps[8][32];
  int tid = threadIdx.x;
  int w = tid >> 6, lane = tid & 63;
  int e = lane & 31, h = lane >> 5;
  int t0 = blockIdx.x << 3;

  const float4* ev = (const float4*)esT4 + (size_t)((w << 6) + (h << 5)) * 32 + e;
  const float4* xv = (const float4*)x + ((size_t)t0 << 8) + (w << 6) + (h << 5);

  float acc[8];
#pragma unroll
  for (int tk = 0; tk < 8; ++tk) acc[tk] = 0.f;

#pragma unroll 2
  for (int i = 0; i < 32; ++i) {
    float4 b = ev[(size_t)i * 32];
#pragma unroll
    for (int tk = 0; tk < 8; ++tk) {
      float4 a = xv[(tk << 8) + i];
      acc[tk] += a.x * b.x + a.y * b.y + a.z * b.z + a.w * b.w;
    }
  }
#pragma unroll
  for (int tk = 0; tk < 8; ++tk) {
    float s = acc[tk] + __shfl_xor(acc[tk], 32);  // sum the two K-eighths
    if (h == 0) part[w][tk][e] = s;
  }
  __syncthreads();

  int tk = tid >> 5, ge = tid & 31;
  {
    float r = part[0][tk][ge] + part[1][tk][ge] + part[2][tk][ge] + part[3][tk][ge];
    int t = t0 + tk;

    float m = r;
#pragma unroll
    for (int mk = 16; mk; mk >>= 1) m = fmaxf(m, __shfl_xor(m, mk));
    float sx = __expf(r - m);
#pragma unroll
    for (int mk = 16; mk; mk >>= 1) sx += __shfl_xor(sx, mk);
    ps[tk][ge] = __expf(r - (m + __logf(sx)));

    u32 packed = 0;
    float v = r;
#pragma unroll
    for (int it = 0; it < 4; ++it) {
      float bv = v; int bi = ge;
#pragma unroll
      for (int mk = 16; mk; mk >>= 1) {
        float ov = __shfl_xor(bv, mk); int oi = __shfl_xor(bi, mk);
        if (ov > bv || (ov == bv && oi < bi)) { bv = ov; bi = oi; }
      }
      packed |= (u32)bi << (8 * it);
      if (ge == it) selval[t * 4 + it] = 1.f / (1.f + __expf(-bv));
      if (ge == bi) v = -3.0e38f;
    }
    if (ge == 0) selpk[t] = packed;
  }
  __syncthreads();
  if (tid < 32) {
    float s = 0.f;
#pragma unroll
    for (int j = 0; j < 8; ++j) s += ps[j][tid];
    blockpart[blockIdx.x * 32 + tid] = s;
  }

  // fused x -> bf16 for this block's 8 rows (coalesced)
  if (xb) {
    const float4* src = (const float4*)x + ((size_t)blockIdx.x << 11);
    u16* dst = xb + ((size_t)blockIdx.x << 13);
#pragma unroll
    for (int j = 0; j < 8; ++j) {
      int idx = (j << 8) + tid;
      float4 a = src[idx];
      *(uint2*)(dst + (idx << 2)) = make_uint2(pk2(a.x, a.y), pk2(a.z, a.w));
    }
  }
}

// ---------------- bucket build ----------------
__global__ __launch_bounds__(1024) void k_count(
    const u32* __restrict__ selpk, int* __restrict__ cnt, int* __restrict__ bucket)
{
  __shared__ int cl[32];
  int tid = threadIdx.x;
  if (tid < 32) cl[tid] = 0;
  __syncthreads();
  int ex[16], pos[16];
#pragma unroll
  for (int j = 0; j < 4; ++j) {
    int t = tid + (j << 10);
    u32 pk = selpk[t];
#pragma unroll
    for (int h = 0; h < 4; ++h) {
      int e = (pk >> (8 * h)) & 0xff;
      ex[j * 4 + h] = e;
      pos[j * 4 + h] = atomicAdd(&cl[e], 1);
    }
  }
#pragma unroll
  for (int j = 0; j < 4; ++j) {
    int t = tid + (j << 10);
#pragma unroll
    for (int h = 0; h < 4; ++h)
      bucket[ex[j * 4 + h] * TOKENS + pos[j * 4 + h]] = (t << 2) | h;
  }
  __syncthreads();
  if (tid < 32) cnt[tid] = cl[tid];
}

// ---------------- entropy regularizer ----------------
__global__ __launch_bounds__(256) void k_fin(const float* __restrict__ blockpart,
                                             float* __restrict__ out_reg)
{
  __shared__ float part[8][32];
  int tid = threadIdx.x;
  int e = tid & 31, c = tid >> 5;
  float s = 0.f;
  for (int b = c; b < 512; b += 8) s += blockpart[b * 32 + e];
  part[c][e] = s;
  __syncthreads();
  if (tid < 32) {
    float S = 0.f;
#pragma unroll
    for (int i = 0; i < 8; ++i) S += part[i][tid];
    float Pm = S * (1.0f / TOKENS);
    float rp = __logf(Pm) * Pm;
#pragma unroll
    for (int mk = 16; mk; mk >>= 1) rp += __shfl_xor(rp, mk);
    if (tid == 0) *out_reg = rp;
  }
}

// ---------------- transpose-convert: src f32 [E][R][C] -> dst bf16 [E][C][R] ----------------
__global__ __launch_bounds__(256) void k_tr(const float* __restrict__ src,
                                            u16* __restrict__ dst, int R, int C)
{
  __shared__ float tile[64][68];
  int e = blockIdx.z;
  int r0 = blockIdx.y << 6, c0 = blockIdx.x << 6;
  int t = threadIdx.x;
  int rr = t >> 2, cb = (t & 3) << 4;
  const float* sp = src + ((size_t)e * R + r0 + rr) * C + c0 + cb;
#pragma unroll
  for (int j = 0; j < 4; ++j)
    *(float4*)&tile[rr][cb + (j << 2)] = *(const float4*)(sp + (j << 2));
  __syncthreads();
  int wr = t >> 2, wb = (t & 3) << 4;
  u32 q[8];
#pragma unroll
  for (int j = 0; j < 8; ++j)
    q[j] = pk2(tile[wb + (j << 1)][wr], tile[wb + (j << 1) + 1][wr]);
  u16* dp = dst + ((size_t)e * C + c0 + wr) * R + r0 + wb;
  *(uint4*)dp = make_uint4(q[0], q[1], q[2], q[3]);
  *(uint4*)(dp + 8) = make_uint4(q[4], q[5], q[6], q[7]);
}

// ======== fast GEMMs: global_load_lds staging, XOR-granule swizzle, 2-phase dbuf ========
#define GEMM_MACROS                                                                          \
  int wm = (w >> 1) << 6, wn = (w & 1) << 6;                                                 \
  int w32 = w << 5;                                                                          \
  int lg16 = (((l & 7) ^ (l >> 3)) << 4);

#define STAGE(BUF, K0) do {                                                                  \
  _Pragma("unroll") for (int i_ = 0; i_ < 4; ++i_)                                           \
    gl16(gA[i_] + ((K0) << 1), (void*)&Ab[BUF][(((w << 2) + i_) << 9)]);                     \
  _Pragma("unroll") for (int i_ = 0; i_ < 4; ++i_)                                           \
    gl16(gB[i_] + ((K0) << 1), (void*)&Bb[BUF][(((w << 2) + i_) << 9)]);                     \
} while (0)

#define COMPUTE(CUR) do {                                                                    \
  _Pragma("unroll") for (int kh_ = 0; kh_ < 2; ++kh_) {                                      \
    bf16x8 af_[4], bf_[4];                                                                   \
    int gg_ = (kh_ << 2) + (l >> 4);                                                         \
    _Pragma("unroll") for (int mi_ = 0; mi_ < 4; ++mi_) {                                    \
      int row_ = wm + (mi_ << 4) + (l & 15);                                                 \
      af_[mi_] = *(const bf16x8*)&Ab[CUR][(row_ << 6) + ((gg_ ^ (row_ & 7)) << 3)];          \
    }                                                                                        \
    _Pragma("unroll") for (int ni_ = 0; ni_ < 4; ++ni_) {                                    \
      int row_ = wn + (ni_ << 4) + (l & 15);                                                 \
      bf_[ni_] = *(const bf16x8*)&Bb[CUR][(row_ << 6) + ((gg_ ^ (row_ & 7)) << 3)];          \
    }                                                                                        \
    _Pragma("unroll") for (int mi_ = 0; mi_ < 4; ++mi_)                                      \
      _Pragma("unroll") for (int ni_ = 0; ni_ < 4; ++ni_)                                    \
        acc[mi_][ni_] = __builtin_amdgcn_mfma_f32_16x16x32_bf16(af_[mi_], bf_[ni_],          \
                                                                acc[mi_][ni_], 0, 0, 0);     \
  }                                                                                          \
} while (0)

#define VM0_BAR() do {                                                                       \
  asm volatile("s_waitcnt vmcnt(0)" ::: "memory");                                           \
  asm volatile("s_barrier" ::: "memory");                                                    \
} while (0)

// XCD-affine decode: bid = ((e>>3)*16 + sub)*8 + (e&7)
// -> all 16 blocks of an expert land on one XCD (round-robin bid%8 = XCD heuristic).
#define XCD_DECODE(SUB_NS_BITS)                                                              \
  int bid = blockIdx.x;                                                                      \
  int q_ = bid >> 3, sub_ = q_ & 15;                                                         \
  int e = ((q_ >> 4) << 3) | (bid & 7);                                                      \
  int ns = sub_ & ((1 << (SUB_NS_BITS)) - 1);                                                \
  int mz = sub_ >> (SUB_NS_BITS);

// ---------------- up-projection: scores[slot] = relu(xb[t] @ kb[e]^T) * gate ----------------
__global__ __launch_bounds__(256, 2) void k_up(
    const u16* __restrict__ xb, const u16* __restrict__ kb,
    const float* __restrict__ selval, const int* __restrict__ cnt,
    const int* __restrict__ bucket, const u16* __restrict__ zeros,
    u16* __restrict__ scores)
{
  XCD_DECODE(2);                       // 4 ns x 4 mz
  int ne = cnt[e];
  if ((mz << 7) >= ne) return;
  int nb0 = ns << 7;
  int tid = threadIdx.x, l = tid & 63, w = tid >> 6;

  __shared__ __align__(16) u16 Ab[2][8192];
  __shared__ __align__(16) u16 Bb[2][8192];
  __shared__ int slot_l[128];
  __shared__ float gate_l[128];

  GEMM_MACROS;

  const char* gB[4];
#pragma unroll
  for (int i = 0; i < 4; ++i) {
    int n = nb0 + w32 + (i << 3) + (l >> 3);
    gB[i] = (const char*)(kb + ((size_t)e * ESIZE + n) * DMODEL) + lg16;
  }

  for (int mt = mz; (mt << 7) < ne; mt += 4) {
    int row0 = mt << 7;
    int rem = ne - row0; if (rem > 128) rem = 128;
    __syncthreads();
    if (tid < 128) {
      int slot = -1; float g = 0.f;
      if (tid < rem) { slot = bucket[e * TOKENS + row0 + tid]; g = selval[slot]; }
      slot_l[tid] = slot; gate_l[tid] = g;
    }
    __syncthreads();

    const char* gA[4];
#pragma unroll
    for (int i = 0; i < 4; ++i) {
      int s = slot_l[w32 + (i << 3) + (l >> 3)];
      gA[i] = ((s >= 0) ? (const char*)(xb + (size_t)(s >> 2) * DMODEL)
                        : (const char*)zeros) + lg16;
    }

    f32x4 acc[4][4];
#pragma unroll
    for (int i = 0; i < 4; ++i)
#pragma unroll
      for (int j = 0; j < 4; ++j) acc[i][j] = (f32x4){0.f, 0.f, 0.f, 0.f};

    STAGE(0, 0);
    VM0_BAR();
#pragma unroll 1
    for (int t = 0; t < 16; ++t) {
      int cur = t & 1;
      if (t < 15) STAGE(cur ^ 1, (t + 1) << 6);
      COMPUTE(cur);
      VM0_BAR();
    }

#pragma unroll
    for (int mi = 0; mi < 4; ++mi) {
      int rbase = wm + (mi << 4) + ((l >> 4) << 2);
#pragma unroll
      for (int rr = 0; rr < 4; ++rr) {
        int r = rbase + rr;
        if (r < rem) {
          float g = gate_l[r];
          u16* so = scores + (size_t)slot_l[r] * ESIZE + nb0 + wn + (l & 15);
#pragma unroll
          for (int ni = 0; ni < 4; ++ni)
            so[ni << 4] = f2b(fmaxf(acc[mi][ni][rr], 0.f) * g);
        }
      }
    }
  }
}

// ---------------- down-projection: stage[slot] = scores[slot] @ vb[e]^T ----------------
__global__ __launch_bounds__(256, 2) void k_down(
    const u16* __restrict__ scores, const u16* __restrict__ vb,
    const int* __restrict__ cnt, const int* __restrict__ bucket,
    const u16* __restrict__ zeros, u16* __restrict__ stage)
{
  XCD_DECODE(3);                       // 8 ns x 2 mz
  int ne = cnt[e];
  if ((mz << 7) >= ne) return;
  int nb0 = ns << 7;
  int tid = threadIdx.x, l = tid & 63, w = tid >> 6;

  __shared__ __align__(16) u16 Ab[2][8192];
  __shared__ __align__(16) u16 Bb[2][8192];
  __shared__ int slot_l[128];

  GEMM_MACROS;

  const char* gB[4];
#pragma unroll
  for (int i = 0; i < 4; ++i) {
    int n = nb0 + w32 + (i << 3) + (l >> 3);
    gB[i] = (const char*)(vb + ((size_t)e * DMODEL + n) * ESIZE) + lg16;
  }

  for (int mt = mz; (mt << 7) < ne; mt += 2) {
    int row0 = mt << 7;
    int rem = ne - row0; if (rem > 128) rem = 128;
    __syncthreads();
    if (tid < 128) {
      int slot = -1;
      if (tid < rem) slot = bucket[e * TOKENS + row0 + tid];
      slot_l[tid] = slot;
    }
    __syncthreads();

    const char* gA[4];
#pragma unroll
    for (int i = 0; i < 4; ++i) {
      int s = slot_l[w32 + (i << 3) + (l >> 3)];
      gA[i] = ((s >= 0) ? (const char*)(scores + (size_t)s * ESIZE)
                        : (const char*)zeros) + lg16;
    }

    f32x4 acc[4][4];
#pragma unroll
    for (int i = 0; i < 4; ++i)
#pragma unroll
      for (int j = 0; j < 4; ++j) acc[i][j] = (f32x4){0.f, 0.f, 0.f, 0.f};

    STAGE(0, 0);
    VM0_BAR();
#pragma unroll 1
    for (int t = 0; t < 8; ++t) {
      int cur = t & 1;
      if (t < 7) STAGE(cur ^ 1, (t + 1) << 6);
      COMPUTE(cur);
      VM0_BAR();
    }

#pragma unroll
    for (int mi = 0; mi < 4; ++mi) {
      int rbase = wm + (mi << 4) + ((l >> 4) << 2);
#pragma unroll
      for (int rr = 0; rr < 4; ++rr) {
        int r = rbase + rr;
        if (r < rem) {
          u16* so = stage + (size_t)slot_l[r] * DMODEL + nb0 + wn + (l & 15);
#pragma unroll
          for (int ni = 0; ni < 4; ++ni)
            so[ni << 4] = f2b(acc[mi][ni][rr]);
        }
      }
    }
  }
}

// ---------------- final: out[t] = sum_h stage[t*4+h] ----------------
__global__ __launch_bounds__(256) void k_final(const u16* __restrict__ stage,
                                               float* __restrict__ out)
{
  int tid = threadIdx.x;
  int t = (blockIdx.x << 1) + (tid >> 7);
  int d0 = (tid & 127) << 3;
  const u16* r0 = stage + ((size_t)t << 12) + d0;
  uint4 a0 = *(const uint4*)(r0);
  uint4 a1 = *(const uint4*)(r0 + 1024);
  uint4 a2 = *(const uint4*)(r0 + 2048);
  uint4 a3 = *(const uint4*)(r0 + 3072);
  float4 lo4, hi4;
  lo4.x = blo(a0.x) + blo(a1.x) + blo(a2.x) + blo(a3.x);
  lo4.y = bhi(a0.x) + bhi(a1.x) + bhi(a2.x) + bhi(a3.x);
  lo4.z = blo(a0.y) + blo(a1.y) + blo(a2.y) + blo(a3.y);
  lo4.w = bhi(a0.y) + bhi(a1.y) + bhi(a2.y) + bhi(a3.y);
  hi4.x = blo(a0.z) + blo(a1.z) + blo(a2.z) + blo(a3.z);
  hi4.y = bhi(a0.z) + bhi(a1.z) + bhi(a2.z) + bhi(a3.z);
  hi4.z = blo(a0.w) + blo(a1.w) + blo(a2.w) + blo(a3.w);
  hi4.w = bhi(a0.w) + bhi(a1.w) + bhi(a2.w) + bhi(a3.w);
  float* o = out + (size_t)t * DMODEL + d0;
  *(float4*)o = lo4;
  *(float4*)(o + 4) = hi4;
}

// ================= fallback (reg-staged) kernels, used if ws too small =================
__global__ __launch_bounds__(256, 2) void k_up_rs(
    const float* __restrict__ x, const float* __restrict__ keys,
    const float* __restrict__ selval, const int* __restrict__ cnt,
    const int* __restrict__ bucket, u16* __restrict__ scores)
{
  int bid = blockIdx.x;
  int pair = bid & 127, mz = bid >> 7;
  int e = pair >> 2, ns = pair & 3;
  int ne = cnt[e];
  if ((mz << 7) >= ne) return;
  int nb0 = ns << 7;
  int tid = threadIdx.x;

  __shared__ __align__(16) u16 Abuf[2][128 * 72];
  __shared__ __align__(16) u16 Bbuf[2][128 * 72];
  __shared__ int slot_l[128];
  __shared__ float gate_l[128];

  const float* Kb = keys + (size_t)e * (DMODEL * ESIZE) + nb0;
  int arow = tid >> 1, ac0 = (tid & 1) << 5;
  int bn = tid & 31, bk0 = (tid >> 5) << 3;
  int lane = tid & 63, w = tid >> 6;
  int wm = (w >> 1) << 6, wn = (w & 1) << 6;

  for (int mt = mz; (mt << 7) < ne; mt += 4) {
    int row0 = mt << 7;
    int rem = ne - row0; if (rem > 128) rem = 128;
    __syncthreads();
    if (tid < 128) {
      int slot = -1; float g = 0.f;
      if (tid < rem) { slot = bucket[e * TOKENS + row0 + tid]; g = selval[slot]; }
      slot_l[tid] = slot; gate_l[tid] = g;
    }
    __syncthreads();

    int aslot = slot_l[arow];
    const float* xr = (aslot >= 0) ? (x + (size_t)(aslot >> 2) * DMODEL + ac0) : nullptr;
    const float* bp = Kb + (size_t)bk0 * ESIZE + (bn << 2);

    f32x4 acc[4][4];
#pragma unroll
    for (int i = 0; i < 4; ++i)
#pragma unroll
      for (int j = 0; j < 4; ++j) acc[i][j] = (f32x4){0.f, 0.f, 0.f, 0.f};

    float4 ar[8], br[8];
#define LOADA_UP(K) do { if (xr) { const float4* p_ = (const float4*)(xr + (K)); \
    _Pragma("unroll") for (int i_ = 0; i_ < 8; ++i_) ar[i_] = p_[i_]; } \
    else { _Pragma("unroll") for (int i_ = 0; i_ < 8; ++i_) ar[i_] = make_float4(0.f,0.f,0.f,0.f); } } while (0)
#define LOADB_RS(K, LDB) do { const float* q_ = bp + (size_t)(K) * (LDB); \
    _Pragma("unroll") for (int r_ = 0; r_ < 8; ++r_) br[r_] = *(const float4*)(q_ + (size_t)r_ * (LDB)); } while (0)
#define CVTWR_A(NB) do { _Pragma("unroll") for (int g_ = 0; g_ < 4; ++g_) { \
    u32 q0_ = pk2(ar[2*g_].x, ar[2*g_].y),   q1_ = pk2(ar[2*g_].z, ar[2*g_].w); \
    u32 q2_ = pk2(ar[2*g_+1].x, ar[2*g_+1].y), q3_ = pk2(ar[2*g_+1].z, ar[2*g_+1].w); \
    *(uint4*)&Abuf[NB][swz(arow, ac0 + 8*g_)] = make_uint4(q0_,q1_,q2_,q3_); } } while (0)
#define CVTWR_B(NB) do { \
    { u32 q0_=pk2(br[0].x,br[1].x),q1_=pk2(br[2].x,br[3].x),q2_=pk2(br[4].x,br[5].x),q3_=pk2(br[6].x,br[7].x); \
      *(uint4*)&Bbuf[NB][swz((bn<<2)+0, bk0)] = make_uint4(q0_,q1_,q2_,q3_); } \
    { u32 q0_=pk2(br[0].y,br[1].y),q1_=pk2(br[2].y,br[3].y),q2_=pk2(br[4].y,br[5].y),q3_=pk2(br[6].y,br[7].y); \
      *(uint4*)&Bbuf[NB][swz((bn<<2)+1, bk0)] = make_uint4(q0_,q1_,q2_,q3_); } \
    { u32 q0_=pk2(br[0].z,br[1].z),q1_=pk2(br[2].z,br[3].z),q2_=pk2(br[4].z,br[5].z),q3_=pk2(br[6].z,br[7].z); \
      *(uint4*)&Bbuf[NB][swz((bn<<2)+2, bk0)] = make_uint4(q0_,q1_,q2_,q3_); } \
    { u32 q0_=pk2(br[0].w,br[1].w),q1_=pk2(br[2].w,br[3].w),q2_=pk2(br[4].w,br[5].w),q3_=pk2(br[6].w,br[7].w); \
      *(uint4*)&Bbuf[NB][swz((bn<<2)+3, bk0)] = make_uint4(q0_,q1_,q2_,q3_); } } while (0)
#define MFMA_RS(CUR) do { _Pragma("unroll") for (int kh_ = 0; kh_ < 2; ++kh_) { \
    int kk_ = (kh_ << 5) | ((lane >> 4) << 3); \
    bf16x8 af_[4], bf_[4]; \
    _Pragma("unroll") for (int mi_ = 0; mi_ < 4; ++mi_) \
      af_[mi_] = *(const bf16x8*)&Abuf[CUR][swz(wm + (mi_ << 4) + (lane & 15), kk_)]; \
    _Pragma("unroll") for (int ni_ = 0; ni_ < 4; ++ni_) \
      bf_[ni_] = *(const bf16x8*)&Bbuf[CUR][swz(wn + (ni_ << 4) + (lane & 15), kk_)]; \
    _Pragma("unroll") for (int mi_ = 0; mi_ < 4; ++mi_) \
      _Pragma("unroll") for (int ni_ = 0; ni_ < 4; ++ni_) \
        acc[mi_][ni_] = __builtin_amdgcn_mfma_f32_16x16x32_bf16(af_[mi_], bf_[ni_], acc[mi_][ni_], 0, 0, 0); \
  } } while (0)

    LOADA_UP(0); LOADB_RS(0, ESIZE);
    CVTWR_A(0); CVTWR_B(0);
    __syncthreads();
    int cur = 0;
    for (int k0 = 0; k0 < DMODEL; k0 += 64) {
      bool late = (k0 + 64 >= DMODEL);
      if (!late) { LOADA_UP(k0 + 64); LOADB_RS(k0 + 64, ESIZE); }
      MFMA_RS(cur);
      if (!late) { CVTWR_A(cur ^ 1); CVTWR_B(cur ^ 1); }
      __syncthreads();
      cur ^= 1;
    }

#pragma unroll
    for (int mi = 0; mi < 4; ++mi) {
      int rbase = wm + (mi << 4) + ((lane >> 4) << 2);
#pragma unroll
      for (int rr = 0; rr < 4; ++rr) {
        int r = rbase + rr;
        if (r < rem) {
          float g = gate_l[r];
          u16* so = scores + (size_t)slot_l[r] * ESIZE + nb0 + wn + (lane & 15);
#pragma unroll
          for (int ni = 0; ni < 4; ++ni)
            so[ni << 4] = f2b(fmaxf(acc[mi][ni][rr], 0.f) * g);
        }
      }
    }
#undef LOADA_UP
#undef LOADB_RS
#undef CVTWR_A
#undef CVTWR_B
#undef MFMA_RS
  }
}

__global__ __launch_bounds__(256, 2) void k_down_rs(
    const u16* __restrict__ scores, const float* __restrict__ values,
    const int* __restrict__ cnt, const int* __restrict__ bucket,
    u16* __restrict__ stage, float* __restrict__ out)
{
  int bid = blockIdx.x;
  int pair = bid & 255, mz = bid >> 8;
  int e = pair >> 3, ns = pair & 7;
  int ne = cnt[e];
  if ((mz << 7) >= ne) return;
  int nb0 = ns << 7;
  int tid = threadIdx.x;

  __shared__ __align__(16) u16 Abuf[2][128 * 72];
  __shared__ __align__(16) u16 Bbuf[2][128 * 72];
  __shared__ int slot_l[128];

  const float* Vb = values + (size_t)e * (ESIZE * DMODEL) + nb0;
  int arow = tid >> 1, ac0 = (tid & 1) << 5;
  int bn = tid & 31, bk0 = (tid >> 5) << 3;
  int lane = tid & 63, w = tid >> 6;
  int wm = (w >> 1) << 6, wn = (w & 1) << 6;

  for (int mt = mz; (mt << 7) < ne; mt += 2) {
    int row0 = mt << 7;
    int rem = ne - row0; if (rem > 128) rem = 128;
    __syncthreads();
    if (tid < 128) {
      int slot = -1;
      if (tid < rem) slot = bucket[e * TOKENS + row0 + tid];
      slot_l[tid] = slot;
    }
    __syncthreads();

    int aslot = slot_l[arow];
    const u16* sr = (aslot >= 0) ? (scores + (size_t)aslot * ESIZE + ac0) : nullptr;
    const float* bp = Vb + (size_t)bk0 * DMODEL + (bn << 2);

    f32x4 acc[4][4];
#pragma unroll
    for (int i = 0; i < 4; ++i)
#pragma unroll
      for (int j = 0; j < 4; ++j) acc[i][j] = (f32x4){0.f, 0.f, 0.f, 0.f};

    uint4 a4[4]; float4 br[8];
#define LOADA_DN(K) do { if (sr) { const uint4* p_ = (const uint4*)(sr + (K)); \
    _Pragma("unroll") for (int i_ = 0; i_ < 4; ++i_) a4[i_] = p_[i_]; } \
    else { _Pragma("unroll") for (int i_ = 0; i_ < 4; ++i_) a4[i_] = make_uint4(0,0,0,0); } } while (0)
#define LOADB_RS(K, LDB) do { const float* q_ = bp + (size_t)(K) * (LDB); \
    _Pragma("unroll") for (int r_ = 0; r_ < 8; ++r_) br[r_] = *(const float4*)(q_ + (size_t)r_ * (LDB)); } while (0)
#define WR_A(NB) do { _Pragma("unroll") for (int g_ = 0; g_ < 4; ++g_) \
    *(uint4*)&Abuf[NB][swz(arow, ac0 + 8*g_)] = a4[g_]; } while (0)
#define CVTWR_B(NB) do { \
    { u32 q0_=pk2(br[0].x,br[1].x),q1_=pk2(br[2].x,br[3].x),q2_=pk2(br[4].x,br[5].x),q3_=pk2(br[6].x,br[7].x); \
      *(uint4*)&Bbuf[NB][swz((bn<<2)+0, bk0)] = make_uint4(q0_,q1_,q2_,q3_); } \
    { u32 q0_=pk2(br[0].y,br[1].y),q1_=pk2(br[2].y,br[3].y),q2_=pk2(br[4].y,br[5].y),q3_=pk2(br[6].y,br[7].y); \
      *(uint4*)&Bbuf[NB][swz((bn<<2)+1, bk0)] = make_uint4(q0_,q1_,q2_,q3_); } \
    { u32 q0_=pk2(br[0].z,br[1].z),q1_=pk2(br[2].z,br[3].z),q2_=pk2(br[4].z,br[5].z),q3_=pk2(br[6].z,br[7].z); \
      *(uint4*)&Bbuf[NB][swz((bn<<2)+2, bk0)] = make_uint4(q0_,q1_,q2_,q3_); } \
    { u32 q0_=pk2(br[0].w,br[1].w),q1_=pk2(br[2].w,br[3].w),q2_=pk2(br[4].w,br[5].w),q3_=pk2(br[6].w,br[7].w); \
      *(uint4*)&Bbuf[NB][swz((bn<<2)+3, bk0)] = make_uint4(q0_,q1_,q2_,q3_); } } while (0)
#define MFMA_RS(CUR) do { _Pragma("unroll") for (int kh_ = 0; kh_ < 2; ++kh_) { \
    int kk_ = (kh_ << 5) | ((lane >> 4) << 3); \
    bf16x8 af_[4], bf_[4]; \
    _Pragma("unroll") for (int mi_ = 0; mi_ < 4; ++mi_) \
      af_[mi_] = *(const bf16x8*)&Abuf[CUR][swz(wm + (mi_ << 4) + (lane & 15), kk_)]; \
    _Pragma("unroll") for (int ni_ = 0; ni_ < 4; ++ni_) \
      bf_[ni_] = *(const bf16x8*)&Bbuf[CUR][swz(wn + (ni_ << 4) + (lane & 15), kk_)]; \
    _Pragma("unroll") for (int mi_ = 0; mi_ < 4; ++mi_) \
      _Pragma("unroll") for (int ni_ = 0; ni_ < 4; ++ni_) \
        acc[mi_][ni_] = __builtin_amdgcn_mfma_f32_16x16x32_bf16(af_[mi_], bf_[ni_], acc[mi_][ni_], 0, 0, 0); \
  } } while (0)

    LOADA_DN(0); LOADB_RS(0, DMODEL);
    WR_A(0); CVTWR_B(0);
    __syncthreads();
    int cur = 0;
    for (int k0 = 0; k0 < ESIZE; k0 += 64) {
      bool late = (k0 + 64 >= ESIZE);
      if (!late) { LOADA_DN(k0 + 64); LOADB_RS(k0 + 64, DMODEL); }
      MFMA_RS(cur);
      if (!late) { WR_A(cur ^ 1); CVTWR_B(cur ^ 1); }
      __syncthreads();
      cur ^= 1;
    }

#pragma unroll
    for (int mi = 0; mi < 4; ++mi) {
      int rbase = wm + (mi << 4) + ((lane >> 4) << 2);
#pragma unroll
      for (int rr = 0; rr < 4; ++rr) {
        int r = rbase + rr;
        if (r < rem) {
          if (stage) {
            u16* so = stage + (size_t)slot_l[r] * DMODEL + nb0 + wn + (lane & 15);
#pragma unroll
            for (int ni = 0; ni < 4; ++ni)
              so[ni << 4] = f2b(acc[mi][ni][rr]);
          } else {
            int t = slot_l[r] >> 2;
            float* oo = out + (size_t)t * DMODEL + nb0 + wn + (lane & 15);
#pragma unroll
            for (int ni = 0; ni < 4; ++ni)
              atomicAdd(&oo[ni << 4], acc[mi][ni][rr]);
          }
        }
      }
    }
#undef LOADA_DN
#undef LOADB_RS
#undef WR_A
#undef CVTWR_B
#undef MFMA_RS
  }
}

extern "C" void kernel_launch(void* const* d_in, const int* in_sizes, int n_in,
                              void* d_out, int out_size, void* d_ws, size_t ws_size,
                              hipStream_t stream) {
  (void)in_sizes; (void)n_in;
  const float* x      = (const float*)d_in[0];
  const float* keys   = (const float*)d_in[1];
  const float* values = (const float*)d_in[2];
  const float* es     = (const float*)d_in[3];
  float* out = (float*)d_out;

  char* W = (char*)d_ws;
  int*   cnt       = (int*)W;                        // 128 B
  u16*   zeros     = (u16*)(W + 4 * 1024);           // 4 KB
  u32*   selpk     = (u32*)(W + 16 * 1024);          // 16 KB
  float* selval    = (float*)(W + 64 * 1024);        // 64 KB
  float* blockpart = (float*)(W + 128 * 1024);       // 64 KB f32 [512][32]
  int*   bucket    = (int*)(W + 512 * 1024);         // 512 KB
  float* esT4      = (float*)(W + 1280 * 1024);      // 128 KB f32 [256][32][4]

  bool big = ws_size >= (90ull << 20);
  u16* xb = big ? (u16*)(W + 2ull * 1024 * 1024) : nullptr;  // 8 MB bf16 [4096][1024]

  k_esT<<<32, 256, 0, stream>>>(es, esT4);
  k_route<<<TOKENS / 8, 256, 0, stream>>>(x, esT4, selval, selpk, blockpart, xb);
  k_count<<<1, 1024, 0, stream>>>(selpk, cnt, bucket);
  k_fin<<<1, 256, 0, stream>>>(blockpart, out + (size_t)out_size - 1);

  if (big) {
    u16* scores = (u16*)(W + 10ull * 1024 * 1024);   // 16 MB bf16 [16384][512]
    u16* kb     = (u16*)(W + 26ull * 1024 * 1024);   // 32 MB bf16 [32][512][1024]
    u16* vb     = (u16*)(W + 58ull * 1024 * 1024);   // 32 MB bf16 [32][1024][512]
    u16* stage  = kb;  // aliases kb: kb dead after k_up, stage written by k_down
    hipMemsetAsync(zeros, 0, 4096, stream);
    k_tr<<<dim3(ESIZE / 64, DMODEL / 64, NEXP), 256, 0, stream>>>(keys, kb, DMODEL, ESIZE);
    k_tr<<<dim3(DMODEL / 64, ESIZE / 64, NEXP), 256, 0, stream>>>(values, vb, ESIZE, DMODEL);
    k_up<<<512, 256, 0, stream>>>(xb, kb, selval, cnt, bucket, zeros, scores);
    k_down<<<512, 256, 0, stream>>>(scores, vb, cnt, bucket, zeros, stage);
    k_final<<<TOKENS / 2, 256, 0, stream>>>(stage, out);
  } else {
    u16* scores = (u16*)(W + 2ull * 1024 * 1024);
    bool big50 = ws_size >= (50ull << 20);
    u16* stage = big50 ? (u16*)(W + 18ull * 1024 * 1024) : nullptr;
    if (!big50)
      hipMemsetAsync(d_out, 0, (size_t)out_size * sizeof(float), stream);
    k_up_rs<<<512, 256, 0, stream>>>(x, keys, selval, cnt, bucket, scores);
    k_down_rs<<<512, 256, 0, stream>>>(scores, values, cnt, bucket, stage, out);
    if (big50)
      k_final<<<TOKENS / 2, 256, 0, stream>>>(stage, out);
  }
}

// Round 9
// 171.848 us; speedup vs baseline: 3.0410x; 1.0180x over previous
//
#include <hip/hip_runtime.h>
#include <hip/hip_bf16.h>

typedef unsigned short u16;
typedef unsigned int u32;
typedef __attribute__((ext_vector_type(4))) float f32x4;
typedef __attribute__((ext_vector_type(8))) short bf16x8;

#define TOKENS 4096
#define DMODEL 1024
#define NEXP 32
#define ESIZE 512

// round-to-nearest-even f32 -> bf16 bits
__device__ __forceinline__ u16 f2b(float f) {
  union { float f; u32 u; } v; v.f = f;
  u32 u = v.u;
  return (u16)((u + 0x7fffu + ((u >> 16) & 1u)) >> 16);
}

// packed f32x2 -> bf16x2
__device__ __forceinline__ u32 pk2(float a, float b) {
  union { __hip_bfloat162 h; u32 u; } v;
  v.h = __float22bfloat162_rn(make_float2(a, b));
  return v.u;
}

__device__ __forceinline__ float blo(u32 w) { union { u32 u; float f; } v; v.u = w << 16; return v.f; }
__device__ __forceinline__ float bhi(u32 w) { union { u32 u; float f; } v; v.u = w & 0xffff0000u; return v.f; }

// async global->LDS, 16B per lane; LDS dest = wave-uniform base + lane*16
typedef __attribute__((address_space(1))) const void as1_void;
typedef __attribute__((address_space(3))) void as3_void;
__device__ __forceinline__ void gl16(const void* g, void* l) {
  __builtin_amdgcn_global_load_lds((as1_void*)g, (as3_void*)l, 16, 0, 0);
}

// legacy swizzle for fallback kernels
__device__ __forceinline__ int swz(int row, int kk) {
  return row * 72 + ((((kk >> 3) ^ (row >> 2)) & 7) << 3) + (kk & 7);
}

// ---------------- es transpose: esT4[dblk][e][j] = es[e][4*dblk+j] ----------------
__global__ __launch_bounds__(256) void k_esT(const float* __restrict__ es,
                                             float* __restrict__ esT4)
{
  int tid = threadIdx.x;
  int dblk = (blockIdx.x << 3) + (tid >> 5);
  int e = tid & 31;
  float4 v = *(const float4*)(es + (size_t)e * DMODEL + (dblk << 2));
  *((float4*)esT4 + (size_t)dblk * 32 + e) = v;
}

// ---------------- routing: K-split across 4 waves, 8 tokens/block ----------------
__global__ __launch_bounds__(256) void k_route(
    const float* __restrict__ x, const float* __restrict__ esT4,
    float* __restrict__ selval, u32* __restrict__ selpk,
    float* __restrict__ blockpart, u16* __restrict__ xb)
{
  __shared__ float part[4][8][32];
  __shared__ float ps[8][32];
  int tid = threadIdx.x;
  int w = tid >> 6, lane = tid & 63;
  int e = lane & 31, h = lane >> 5;
  int t0 = blockIdx.x << 3;

  const float4* ev = (const float4*)esT4 + (size_t)((w << 6) + (h << 5)) * 32 + e;
  const float4* xv = (const float4*)x + ((size_t)t0 << 8) + (w << 6) + (h << 5);

  float acc[8];
#pragma unroll
  for (int tk = 0; tk < 8; ++tk) acc[tk] = 0.f;

#pragma unroll 2
  for (int i = 0; i < 32; ++i) {
    float4 b = ev[(size_t)i * 32];
#pragma unroll
    for (int tk = 0; tk < 8; ++tk) {
      float4 a = xv[(tk << 8) + i];
      acc[tk] += a.x * b.x + a.y * b.y + a.z * b.z + a.w * b.w;
    }
  }
#pragma unroll
  for (int tk = 0; tk < 8; ++tk) {
    float s = acc[tk] + __shfl_xor(acc[tk], 32);  // sum the two K-eighths
    if (h == 0) part[w][tk][e] = s;
  }
  __syncthreads();

  int tk = tid >> 5, ge = tid & 31;
  {
    float r = part[0][tk][ge] + part[1][tk][ge] + part[2][tk][ge] + part[3][tk][ge];
    int t = t0 + tk;

    float m = r;
#pragma unroll
    for (int mk = 16; mk; mk >>= 1) m = fmaxf(m, __shfl_xor(m, mk));
    float sx = __expf(r - m);
#pragma unroll
    for (int mk = 16; mk; mk >>= 1) sx += __shfl_xor(sx, mk);
    ps[tk][ge] = __expf(r - (m + __logf(sx)));

    u32 packed = 0;
    float v = r;
#pragma unroll
    for (int it = 0; it < 4; ++it) {
      float bv = v; int bi = ge;
#pragma unroll
      for (int mk = 16; mk; mk >>= 1) {
        float ov = __shfl_xor(bv, mk); int oi = __shfl_xor(bi, mk);
        if (ov > bv || (ov == bv && oi < bi)) { bv = ov; bi = oi; }
      }
      packed |= (u32)bi << (8 * it);
      if (ge == it) selval[t * 4 + it] = 1.f / (1.f + __expf(-bv));
      if (ge == bi) v = -3.0e38f;
    }
    if (ge == 0) selpk[t] = packed;
  }
  __syncthreads();
  if (tid < 32) {
    float s = 0.f;
#pragma unroll
    for (int j = 0; j < 8; ++j) s += ps[j][tid];
    blockpart[blockIdx.x * 32 + tid] = s;
  }

  // fused x -> bf16 for this block's 8 rows (coalesced)
  if (xb) {
    const float4* src = (const float4*)x + ((size_t)blockIdx.x << 11);
    u16* dst = xb + ((size_t)blockIdx.x << 13);
#pragma unroll
    for (int j = 0; j < 8; ++j) {
      int idx = (j << 8) + tid;
      float4 a = src[idx];
      *(uint2*)(dst + (idx << 2)) = make_uint2(pk2(a.x, a.y), pk2(a.z, a.w));
    }
  }
}

// ---------------- bucket build ----------------
__global__ __launch_bounds__(1024) void k_count(
    const u32* __restrict__ selpk, int* __restrict__ cnt, int* __restrict__ bucket)
{
  __shared__ int cl[32];
  int tid = threadIdx.x;
  if (tid < 32) cl[tid] = 0;
  __syncthreads();
  int ex[16], pos[16];
#pragma unroll
  for (int j = 0; j < 4; ++j) {
    int t = tid + (j << 10);
    u32 pk = selpk[t];
#pragma unroll
    for (int h = 0; h < 4; ++h) {
      int e = (pk >> (8 * h)) & 0xff;
      ex[j * 4 + h] = e;
      pos[j * 4 + h] = atomicAdd(&cl[e], 1);
    }
  }
#pragma unroll
  for (int j = 0; j < 4; ++j) {
    int t = tid + (j << 10);
#pragma unroll
    for (int h = 0; h < 4; ++h)
      bucket[ex[j * 4 + h] * TOKENS + pos[j * 4 + h]] = (t << 2) | h;
  }
  __syncthreads();
  if (tid < 32) cnt[tid] = cl[tid];
}

// ---------------- entropy regularizer ----------------
__global__ __launch_bounds__(256) void k_fin(const float* __restrict__ blockpart,
                                             float* __restrict__ out_reg)
{
  __shared__ float part[8][32];
  int tid = threadIdx.x;
  int e = tid & 31, c = tid >> 5;
  float s = 0.f;
  for (int b = c; b < 512; b += 8) s += blockpart[b * 32 + e];
  part[c][e] = s;
  __syncthreads();
  if (tid < 32) {
    float S = 0.f;
#pragma unroll
    for (int i = 0; i < 8; ++i) S += part[i][tid];
    float Pm = S * (1.0f / TOKENS);
    float rp = __logf(Pm) * Pm;
#pragma unroll
    for (int mk = 16; mk; mk >>= 1) rp += __shfl_xor(rp, mk);
    if (tid == 0) *out_reg = rp;
  }
}

// ---------------- transpose-convert: src f32 [E][R][C] -> dst bf16 [E][C][R] ----------------
__global__ __launch_bounds__(256) void k_tr(const float* __restrict__ src,
                                            u16* __restrict__ dst, int R, int C)
{
  __shared__ float tile[64][68];
  int e = blockIdx.z;
  int r0 = blockIdx.y << 6, c0 = blockIdx.x << 6;
  int t = threadIdx.x;
  int rr = t >> 2, cb = (t & 3) << 4;
  const float* sp = src + ((size_t)e * R + r0 + rr) * C + c0 + cb;
#pragma unroll
  for (int j = 0; j < 4; ++j)
    *(float4*)&tile[rr][cb + (j << 2)] = *(const float4*)(sp + (j << 2));
  __syncthreads();
  int wr = t >> 2, wb = (t & 3) << 4;
  u32 q[8];
#pragma unroll
  for (int j = 0; j < 8; ++j)
    q[j] = pk2(tile[wb + (j << 1)][wr], tile[wb + (j << 1) + 1][wr]);
  u16* dp = dst + ((size_t)e * C + c0 + wr) * R + r0 + wb;
  *(uint4*)dp = make_uint4(q[0], q[1], q[2], q[3]);
  *(uint4*)(dp + 8) = make_uint4(q[4], q[5], q[6], q[7]);
}

// ======== fast GEMMs: global_load_lds staging, XOR-granule swizzle ========
// 2-deep counted-vmcnt pipeline (T3+T4): 16 loads in flight, wait vmcnt(8)
// (oldest 8 = current tile) -> barrier -> MFMA -> barrier -> stage t+2.
// vmcnt retires in-order per wave, so stray older stores only make the
// counted wait conservative, never unsafe.
#define GEMM_MACROS                                                                          \
  int wm = (w >> 1) << 6, wn = (w & 1) << 6;                                                 \
  int w32 = w << 5;                                                                          \
  int lg16 = (((l & 7) ^ (l >> 3)) << 4);

#define STAGE(BUF, K0) do {                                                                  \
  _Pragma("unroll") for (int i_ = 0; i_ < 4; ++i_)                                           \
    gl16(gA[i_] + ((K0) << 1), (void*)&Ab[BUF][(((w << 2) + i_) << 9)]);                     \
  _Pragma("unroll") for (int i_ = 0; i_ < 4; ++i_)                                           \
    gl16(gB[i_] + ((K0) << 1), (void*)&Bb[BUF][(((w << 2) + i_) << 9)]);                     \
} while (0)

#define COMPUTE(CUR) do {                                                                    \
  _Pragma("unroll") for (int kh_ = 0; kh_ < 2; ++kh_) {                                      \
    bf16x8 af_[4], bf_[4];                                                                   \
    int gg_ = (kh_ << 2) + (l >> 4);                                                         \
    _Pragma("unroll") for (int mi_ = 0; mi_ < 4; ++mi_) {                                    \
      int row_ = wm + (mi_ << 4) + (l & 15);                                                 \
      af_[mi_] = *(const bf16x8*)&Ab[CUR][(row_ << 6) + ((gg_ ^ (row_ & 7)) << 3)];          \
    }                                                                                        \
    _Pragma("unroll") for (int ni_ = 0; ni_ < 4; ++ni_) {                                    \
      int row_ = wn + (ni_ << 4) + (l & 15);                                                 \
      bf_[ni_] = *(const bf16x8*)&Bb[CUR][(row_ << 6) + ((gg_ ^ (row_ & 7)) << 3)];          \
    }                                                                                        \
    _Pragma("unroll") for (int mi_ = 0; mi_ < 4; ++mi_)                                      \
      _Pragma("unroll") for (int ni_ = 0; ni_ < 4; ++ni_)                                    \
        acc[mi_][ni_] = __builtin_amdgcn_mfma_f32_16x16x32_bf16(af_[mi_], bf_[ni_],          \
                                                                acc[mi_][ni_], 0, 0, 0);     \
  }                                                                                          \
} while (0)

// counted-vmcnt K-loop over NT tiles of 64
#define KLOOP(NT) do {                                                                       \
  STAGE(0, 0);                                                                               \
  STAGE(1, 64);                                                                              \
  _Pragma("unroll 1")                                                                        \
  for (int t_ = 0; t_ < (NT); ++t_) {                                                        \
    int cur_ = t_ & 1;                                                                       \
    if (t_ + 1 < (NT)) { asm volatile("s_waitcnt vmcnt(8)" ::: "memory"); }                  \
    else               { asm volatile("s_waitcnt vmcnt(0)" ::: "memory"); }                  \
    asm volatile("s_barrier" ::: "memory");                                                  \
    COMPUTE(cur_);                                                                           \
    asm volatile("s_barrier" ::: "memory");                                                  \
    if (t_ + 2 < (NT)) STAGE(cur_, (t_ + 2) << 6);                                           \
  }                                                                                          \
} while (0)

// XCD-affine decode: bid = ((e>>3)*16 + sub)*8 + (e&7)
#define XCD_DECODE(SUB_NS_BITS)                                                              \
  int bid = blockIdx.x;                                                                      \
  int q_ = bid >> 3, sub_ = q_ & 15;                                                         \
  int e = ((q_ >> 4) << 3) | (bid & 7);                                                      \
  int ns = sub_ & ((1 << (SUB_NS_BITS)) - 1);                                                \
  int mz = sub_ >> (SUB_NS_BITS);

// ---------------- up-projection: scores[slot] = relu(xb[t] @ kb[e]^T) * gate ----------------
__global__ __launch_bounds__(256, 2) void k_up(
    const u16* __restrict__ xb, const u16* __restrict__ kb,
    const float* __restrict__ selval, const int* __restrict__ cnt,
    const int* __restrict__ bucket, const u16* __restrict__ zeros,
    u16* __restrict__ scores)
{
  XCD_DECODE(2);                       // 4 ns x 4 mz
  int ne = cnt[e];
  if ((mz << 7) >= ne) return;
  int nb0 = ns << 7;
  int tid = threadIdx.x, l = tid & 63, w = tid >> 6;

  __shared__ __align__(16) u16 Ab[2][8192];
  __shared__ __align__(16) u16 Bb[2][8192];
  __shared__ int slot_l[128];
  __shared__ float gate_l[128];

  GEMM_MACROS;

  const char* gB[4];
#pragma unroll
  for (int i = 0; i < 4; ++i) {
    int n = nb0 + w32 + (i << 3) + (l >> 3);
    gB[i] = (const char*)(kb + ((size_t)e * ESIZE + n) * DMODEL) + lg16;
  }

  for (int mt = mz; (mt << 7) < ne; mt += 4) {
    int row0 = mt << 7;
    int rem = ne - row0; if (rem > 128) rem = 128;
    __syncthreads();
    if (tid < 128) {
      int slot = -1; float g = 0.f;
      if (tid < rem) { slot = bucket[e * TOKENS + row0 + tid]; g = selval[slot]; }
      slot_l[tid] = slot; gate_l[tid] = g;
    }
    __syncthreads();

    const char* gA[4];
#pragma unroll
    for (int i = 0; i < 4; ++i) {
      int s = slot_l[w32 + (i << 3) + (l >> 3)];
      gA[i] = ((s >= 0) ? (const char*)(xb + (size_t)(s >> 2) * DMODEL)
                        : (const char*)zeros) + lg16;
    }

    f32x4 acc[4][4];
#pragma unroll
    for (int i = 0; i < 4; ++i)
#pragma unroll
      for (int j = 0; j < 4; ++j) acc[i][j] = (f32x4){0.f, 0.f, 0.f, 0.f};

    KLOOP(16);

#pragma unroll
    for (int mi = 0; mi < 4; ++mi) {
      int rbase = wm + (mi << 4) + ((l >> 4) << 2);
#pragma unroll
      for (int rr = 0; rr < 4; ++rr) {
        int r = rbase + rr;
        if (r < rem) {
          float g = gate_l[r];
          u16* so = scores + (size_t)slot_l[r] * ESIZE + nb0 + wn + (l & 15);
#pragma unroll
          for (int ni = 0; ni < 4; ++ni)
            so[ni << 4] = f2b(fmaxf(acc[mi][ni][rr], 0.f) * g);
        }
      }
    }
  }
}

// ---------------- down-projection: stage[slot] = scores[slot] @ vb[e]^T ----------------
__global__ __launch_bounds__(256, 2) void k_down(
    const u16* __restrict__ scores, const u16* __restrict__ vb,
    const int* __restrict__ cnt, const int* __restrict__ bucket,
    const u16* __restrict__ zeros, u16* __restrict__ stage)
{
  XCD_DECODE(3);                       // 8 ns x 2 mz
  int ne = cnt[e];
  if ((mz << 7) >= ne) return;
  int nb0 = ns << 7;
  int tid = threadIdx.x, l = tid & 63, w = tid >> 6;

  __shared__ __align__(16) u16 Ab[2][8192];
  __shared__ __align__(16) u16 Bb[2][8192];
  __shared__ int slot_l[128];

  GEMM_MACROS;

  const char* gB[4];
#pragma unroll
  for (int i = 0; i < 4; ++i) {
    int n = nb0 + w32 + (i << 3) + (l >> 3);
    gB[i] = (const char*)(vb + ((size_t)e * DMODEL + n) * ESIZE) + lg16;
  }

  for (int mt = mz; (mt << 7) < ne; mt += 2) {
    int row0 = mt << 7;
    int rem = ne - row0; if (rem > 128) rem = 128;
    __syncthreads();
    if (tid < 128) {
      int slot = -1;
      if (tid < rem) slot = bucket[e * TOKENS + row0 + tid];
      slot_l[tid] = slot;
    }
    __syncthreads();

    const char* gA[4];
#pragma unroll
    for (int i = 0; i < 4; ++i) {
      int s = slot_l[w32 + (i << 3) + (l >> 3)];
      gA[i] = ((s >= 0) ? (const char*)(scores + (size_t)s * ESIZE)
                        : (const char*)zeros) + lg16;
    }

    f32x4 acc[4][4];
#pragma unroll
    for (int i = 0; i < 4; ++i)
#pragma unroll
      for (int j = 0; j < 4; ++j) acc[i][j] = (f32x4){0.f, 0.f, 0.f, 0.f};

    KLOOP(8);

#pragma unroll
    for (int mi = 0; mi < 4; ++mi) {
      int rbase = wm + (mi << 4) + ((l >> 4) << 2);
#pragma unroll
      for (int rr = 0; rr < 4; ++rr) {
        int r = rbase + rr;
        if (r < rem) {
          u16* so = stage + (size_t)slot_l[r] * DMODEL + nb0 + wn + (l & 15);
#pragma unroll
          for (int ni = 0; ni < 4; ++ni)
            so[ni << 4] = f2b(acc[mi][ni][rr]);
        }
      }
    }
  }
}

// ---------------- final: out[t] = sum_h stage[t*4+h] ----------------
__global__ __launch_bounds__(256) void k_final(const u16* __restrict__ stage,
                                               float* __restrict__ out)
{
  int tid = threadIdx.x;
  int t = (blockIdx.x << 1) + (tid >> 7);
  int d0 = (tid & 127) << 3;
  const u16* r0 = stage + ((size_t)t << 12) + d0;
  uint4 a0 = *(const uint4*)(r0);
  uint4 a1 = *(const uint4*)(r0 + 1024);
  uint4 a2 = *(const uint4*)(r0 + 2048);
  uint4 a3 = *(const uint4*)(r0 + 3072);
  float4 lo4, hi4;
  lo4.x = blo(a0.x) + blo(a1.x) + blo(a2.x) + blo(a3.x);
  lo4.y = bhi(a0.x) + bhi(a1.x) + bhi(a2.x) + bhi(a3.x);
  lo4.z = blo(a0.y) + blo(a1.y) + blo(a2.y) + blo(a3.y);
  lo4.w = bhi(a0.y) + bhi(a1.y) + bhi(a2.y) + bhi(a3.y);
  hi4.x = blo(a0.z) + blo(a1.z) + blo(a2.z) + blo(a3.z);
  hi4.y = bhi(a0.z) + bhi(a1.z) + bhi(a2.z) + bhi(a3.z);
  hi4.z = blo(a0.w) + blo(a1.w) + blo(a2.w) + blo(a3.w);
  hi4.w = bhi(a0.w) + bhi(a1.w) + bhi(a2.w) + bhi(a3.w);
  float* o = out + (size_t)t * DMODEL + d0;
  *(float4*)o = lo4;
  *(float4*)(o + 4) = hi4;
}

// ================= fallback (reg-staged) kernels, used if ws too small =================
__global__ __launch_bounds__(256, 2) void k_up_rs(
    const float* __restrict__ x, const float* __restrict__ keys,
    const float* __restrict__ selval, const int* __restrict__ cnt,
    const int* __restrict__ bucket, u16* __restrict__ scores)
{
  int bid = blockIdx.x;
  int pair = bid & 127, mz = bid >> 7;
  int e = pair >> 2, ns = pair & 3;
  int ne = cnt[e];
  if ((mz << 7) >= ne) return;
  int nb0 = ns << 7;
  int tid = threadIdx.x;

  __shared__ __align__(16) u16 Abuf[2][128 * 72];
  __shared__ __align__(16) u16 Bbuf[2][128 * 72];
  __shared__ int slot_l[128];
  __shared__ float gate_l[128];

  const float* Kb = keys + (size_t)e * (DMODEL * ESIZE) + nb0;
  int arow = tid >> 1, ac0 = (tid & 1) << 5;
  int bn = tid & 31, bk0 = (tid >> 5) << 3;
  int lane = tid & 63, w = tid >> 6;
  int wm = (w >> 1) << 6, wn = (w & 1) << 6;

  for (int mt = mz; (mt << 7) < ne; mt += 4) {
    int row0 = mt << 7;
    int rem = ne - row0; if (rem > 128) rem = 128;
    __syncthreads();
    if (tid < 128) {
      int slot = -1; float g = 0.f;
      if (tid < rem) { slot = bucket[e * TOKENS + row0 + tid]; g = selval[slot]; }
      slot_l[tid] = slot; gate_l[tid] = g;
    }
    __syncthreads();

    int aslot = slot_l[arow];
    const float* xr = (aslot >= 0) ? (x + (size_t)(aslot >> 2) * DMODEL + ac0) : nullptr;
    const float* bp = Kb + (size_t)bk0 * ESIZE + (bn << 2);

    f32x4 acc[4][4];
#pragma unroll
    for (int i = 0; i < 4; ++i)
#pragma unroll
      for (int j = 0; j < 4; ++j) acc[i][j] = (f32x4){0.f, 0.f, 0.f, 0.f};

    float4 ar[8], br[8];
#define LOADA_UP(K) do { if (xr) { const float4* p_ = (const float4*)(xr + (K)); \
    _Pragma("unroll") for (int i_ = 0; i_ < 8; ++i_) ar[i_] = p_[i_]; } \
    else { _Pragma("unroll") for (int i_ = 0; i_ < 8; ++i_) ar[i_] = make_float4(0.f,0.f,0.f,0.f); } } while (0)
#define LOADB_RS(K, LDB) do { const float* q_ = bp + (size_t)(K) * (LDB); \
    _Pragma("unroll") for (int r_ = 0; r_ < 8; ++r_) br[r_] = *(const float4*)(q_ + (size_t)r_ * (LDB)); } while (0)
#define CVTWR_A(NB) do { _Pragma("unroll") for (int g_ = 0; g_ < 4; ++g_) { \
    u32 q0_ = pk2(ar[2*g_].x, ar[2*g_].y),   q1_ = pk2(ar[2*g_].z, ar[2*g_].w); \
    u32 q2_ = pk2(ar[2*g_+1].x, ar[2*g_+1].y), q3_ = pk2(ar[2*g_+1].z, ar[2*g_+1].w); \
    *(uint4*)&Abuf[NB][swz(arow, ac0 + 8*g_)] = make_uint4(q0_,q1_,q2_,q3_); } } while (0)
#define CVTWR_B(NB) do { \
    { u32 q0_=pk2(br[0].x,br[1].x),q1_=pk2(br[2].x,br[3].x),q2_=pk2(br[4].x,br[5].x),q3_=pk2(br[6].x,br[7].x); \
      *(uint4*)&Bbuf[NB][swz((bn<<2)+0, bk0)] = make_uint4(q0_,q1_,q2_,q3_); } \
    { u32 q0_=pk2(br[0].y,br[1].y),q1_=pk2(br[2].y,br[3].y),q2_=pk2(br[4].y,br[5].y),q3_=pk2(br[6].y,br[7].y); \
      *(uint4*)&Bbuf[NB][swz((bn<<2)+1, bk0)] = make_uint4(q0_,q1_,q2_,q3_); } \
    { u32 q0_=pk2(br[0].z,br[1].z),q1_=pk2(br[2].z,br[3].z),q2_=pk2(br[4].z,br[5].z),q3_=pk2(br[6].z,br[7].z); \
      *(uint4*)&Bbuf[NB][swz((bn<<2)+2, bk0)] = make_uint4(q0_,q1_,q2_,q3_); } \
    { u32 q0_=pk2(br[0].w,br[1].w),q1_=pk2(br[2].w,br[3].w),q2_=pk2(br[4].w,br[5].w),q3_=pk2(br[6].w,br[7].w); \
      *(uint4*)&Bbuf[NB][swz((bn<<2)+3, bk0)] = make_uint4(q0_,q1_,q2_,q3_); } } while (0)
#define MFMA_RS(CUR) do { _Pragma("unroll") for (int kh_ = 0; kh_ < 2; ++kh_) { \
    int kk_ = (kh_ << 5) | ((lane >> 4) << 3); \
    bf16x8 af_[4], bf_[4]; \
    _Pragma("unroll") for (int mi_ = 0; mi_ < 4; ++mi_) \
      af_[mi_] = *(const bf16x8*)&Abuf[CUR][swz(wm + (mi_ << 4) + (lane & 15), kk_)]; \
    _Pragma("unroll") for (int ni_ = 0; ni_ < 4; ++ni_) \
      bf_[ni_] = *(const bf16x8*)&Bbuf[CUR][swz(wn + (ni_ << 4) + (lane & 15), kk_)]; \
    _Pragma("unroll") for (int mi_ = 0; mi_ < 4; ++mi_) \
      _Pragma("unroll") for (int ni_ = 0; ni_ < 4; ++ni_) \
        acc[mi_][ni_] = __builtin_amdgcn_mfma_f32_16x16x32_bf16(af_[mi_], bf_[ni_], acc[mi_][ni_], 0, 0, 0); \
  } } while (0)

    LOADA_UP(0); LOADB_RS(0, ESIZE);
    CVTWR_A(0); CVTWR_B(0);
    __syncthreads();
    int cur = 0;
    for (int k0 = 0; k0 < DMODEL; k0 += 64) {
      bool late = (k0 + 64 >= DMODEL);
      if (!late) { LOADA_UP(k0 + 64); LOADB_RS(k0 + 64, ESIZE); }
      MFMA_RS(cur);
      if (!late) { CVTWR_A(cur ^ 1); CVTWR_B(cur ^ 1); }
      __syncthreads();
      cur ^= 1;
    }

#pragma unroll
    for (int mi = 0; mi < 4; ++mi) {
      int rbase = wm + (mi << 4) + ((lane >> 4) << 2);
#pragma unroll
      for (int rr = 0; rr < 4; ++rr) {
        int r = rbase + rr;
        if (r < rem) {
          float g = gate_l[r];
          u16* so = scores + (size_t)slot_l[r] * ESIZE + nb0 + wn + (lane & 15);
#pragma unroll
          for (int ni = 0; ni < 4; ++ni)
            so[ni << 4] = f2b(fmaxf(acc[mi][ni][rr], 0.f) * g);
        }
      }
    }
#undef LOADA_UP
#undef LOADB_RS
#undef CVTWR_A
#undef CVTWR_B
#undef MFMA_RS
  }
}

__global__ __launch_bounds__(256, 2) void k_down_rs(
    const u16* __restrict__ scores, const float* __restrict__ values,
    const int* __restrict__ cnt, const int* __restrict__ bucket,
    u16* __restrict__ stage, float* __restrict__ out)
{
  int bid = blockIdx.x;
  int pair = bid & 255, mz = bid >> 8;
  int e = pair >> 3, ns = pair & 7;
  int ne = cnt[e];
  if ((mz << 7) >= ne) return;
  int nb0 = ns << 7;
  int tid = threadIdx.x;

  __shared__ __align__(16) u16 Abuf[2][128 * 72];
  __shared__ __align__(16) u16 Bbuf[2][128 * 72];
  __shared__ int slot_l[128];

  const float* Vb = values + (size_t)e * (ESIZE * DMODEL) + nb0;
  int arow = tid >> 1, ac0 = (tid & 1) << 5;
  int bn = tid & 31, bk0 = (tid >> 5) << 3;
  int lane = tid & 63, w = tid >> 6;
  int wm = (w >> 1) << 6, wn = (w & 1) << 6;

  for (int mt = mz; (mt << 7) < ne; mt += 2) {
    int row0 = mt << 7;
    int rem = ne - row0; if (rem > 128) rem = 128;
    __syncthreads();
    if (tid < 128) {
      int slot = -1;
      if (tid < rem) slot = bucket[e * TOKENS + row0 + tid];
      slot_l[tid] = slot;
    }
    __syncthreads();

    int aslot = slot_l[arow];
    const u16* sr = (aslot >= 0) ? (scores + (size_t)aslot * ESIZE + ac0) : nullptr;
    const float* bp = Vb + (size_t)bk0 * DMODEL + (bn << 2);

    f32x4 acc[4][4];
#pragma unroll
    for (int i = 0; i < 4; ++i)
#pragma unroll
      for (int j = 0; j < 4; ++j) acc[i][j] = (f32x4){0.f, 0.f, 0.f, 0.f};

    uint4 a4[4]; float4 br[8];
#define LOADA_DN(K) do { if (sr) { const uint4* p_ = (const uint4*)(sr + (K)); \
    _Pragma("unroll") for (int i_ = 0; i_ < 4; ++i_) a4[i_] = p_[i_]; } \
    else { _Pragma("unroll") for (int i_ = 0; i_ < 4; ++i_) a4[i_] = make_uint4(0,0,0,0); } } while (0)
#define LOADB_RS(K, LDB) do { const float* q_ = bp + (size_t)(K) * (LDB); \
    _Pragma("unroll") for (int r_ = 0; r_ < 8; ++r_) br[r_] = *(const float4*)(q_ + (size_t)r_ * (LDB)); } while (0)
#define WR_A(NB) do { _Pragma("unroll") for (int g_ = 0; g_ < 4; ++g_) \
    *(uint4*)&Abuf[NB][swz(arow, ac0 + 8*g_)] = a4[g_]; } while (0)
#define CVTWR_B(NB) do { \
    { u32 q0_=pk2(br[0].x,br[1].x),q1_=pk2(br[2].x,br[3].x),q2_=pk2(br[4].x,br[5].x),q3_=pk2(br[6].x,br[7].x); \
      *(uint4*)&Bbuf[NB][swz((bn<<2)+0, bk0)] = make_uint4(q0_,q1_,q2_,q3_); } \
    { u32 q0_=pk2(br[0].y,br[1].y),q1_=pk2(br[2].y,br[3].y),q2_=pk2(br[4].y,br[5].y),q3_=pk2(br[6].y,br[7].y); \
      *(uint4*)&Bbuf[NB][swz((bn<<2)+1, bk0)] = make_uint4(q0_,q1_,q2_,q3_); } \
    { u32 q0_=pk2(br[0].z,br[1].z),q1_=pk2(br[2].z,br[3].z),q2_=pk2(br[4].z,br[5].z),q3_=pk2(br[6].z,br[7].z); \
      *(uint4*)&Bbuf[NB][swz((bn<<2)+2, bk0)] = make_uint4(q0_,q1_,q2_,q3_); } \
    { u32 q0_=pk2(br[0].w,br[1].w),q1_=pk2(br[2].w,br[3].w),q2_=pk2(br[4].w,br[5].w),q3_=pk2(br[6].w,br[7].w); \
      *(uint4*)&Bbuf[NB][swz((bn<<2)+3, bk0)] = make_uint4(q0_,q1_,q2_,q3_); } } while (0)
#define MFMA_RS(CUR) do { _Pragma("unroll") for (int kh_ = 0; kh_ < 2; ++kh_) { \
    int kk_ = (kh_ << 5) | ((lane >> 4) << 3); \
    bf16x8 af_[4], bf_[4]; \
    _Pragma("unroll") for (int mi_ = 0; mi_ < 4; ++mi_) \
      af_[mi_] = *(const bf16x8*)&Abuf[CUR][swz(wm + (mi_ << 4) + (lane & 15), kk_)]; \
    _Pragma("unroll") for (int ni_ = 0; ni_ < 4; ++ni_) \
      bf_[ni_] = *(const bf16x8*)&Bbuf[CUR][swz(wn + (ni_ << 4) + (lane & 15), kk_)]; \
    _Pragma("unroll") for (int mi_ = 0; mi_ < 4; ++mi_) \
      _Pragma("unroll") for (int ni_ = 0; ni_ < 4; ++ni_) \
        acc[mi_][ni_] = __builtin_amdgcn_mfma_f32_16x16x32_bf16(af_[mi_], bf_[ni_], acc[mi_][ni_], 0, 0, 0); \
  } } while (0)

    LOADA_DN(0); LOADB_RS(0, DMODEL);
    WR_A(0); CVTWR_B(0);
    __syncthreads();
    int cur = 0;
    for (int k0 = 0; k0 < ESIZE; k0 += 64) {
      bool late = (k0 + 64 >= ESIZE);
      if (!late) { LOADA_DN(k0 + 64); LOADB_RS(k0 + 64, DMODEL); }
      MFMA_RS(cur);
      if (!late) { WR_A(cur ^ 1); CVTWR_B(cur ^ 1); }
      __syncthreads();
      cur ^= 1;
    }

#pragma unroll
    for (int mi = 0; mi < 4; ++mi) {
      int rbase = wm + (mi << 4) + ((lane >> 4) << 2);
#pragma unroll
      for (int rr = 0; rr < 4; ++rr) {
        int r = rbase + rr;
        if (r < rem) {
          if (stage) {
            u16* so = stage + (size_t)slot_l[r] * DMODEL + nb0 + wn + (lane & 15);
#pragma unroll
            for (int ni = 0; ni < 4; ++ni)
              so[ni << 4] = f2b(acc[mi][ni][rr]);
          } else {
            int t = slot_l[r] >> 2;
            float* oo = out + (size_t)t * DMODEL + nb0 + wn + (lane & 15);
#pragma unroll
            for (int ni = 0; ni < 4; ++ni)
              atomicAdd(&oo[ni << 4], acc[mi][ni][rr]);
          }
        }
      }
    }
#undef LOADA_DN
#undef LOADB_RS
#undef WR_A
#undef CVTWR_B
#undef MFMA_RS
  }
}

extern "C" void kernel_launch(void* const* d_in, const int* in_sizes, int n_in,
                              void* d_out, int out_size, void* d_ws, size_t ws_size,
                              hipStream_t stream) {
  (void)in_sizes; (void)n_in;
  const float* x      = (const float*)d_in[0];
  const float* keys   = (const float*)d_in[1];
  const float* values = (const float*)d_in[2];
  const float* es     = (const float*)d_in[3];
  float* out = (float*)d_out;

  char* W = (char*)d_ws;
  int*   cnt       = (int*)W;                        // 128 B
  u16*   zeros     = (u16*)(W + 4 * 1024);           // 4 KB
  u32*   selpk     = (u32*)(W + 16 * 1024);          // 16 KB
  float* selval    = (float*)(W + 64 * 1024);        // 64 KB
  float* blockpart = (float*)(W + 128 * 1024);       // 64 KB f32 [512][32]
  int*   bucket    = (int*)(W + 512 * 1024);         // 512 KB
  float* esT4      = (float*)(W + 1280 * 1024);      // 128 KB f32 [256][32][4]

  bool big = ws_size >= (90ull << 20);
  u16* xb = big ? (u16*)(W + 2ull * 1024 * 1024) : nullptr;  // 8 MB bf16 [4096][1024]

  k_esT<<<32, 256, 0, stream>>>(es, esT4);
  k_route<<<TOKENS / 8, 256, 0, stream>>>(x, esT4, selval, selpk, blockpart, xb);
  k_count<<<1, 1024, 0, stream>>>(selpk, cnt, bucket);
  k_fin<<<1, 256, 0, stream>>>(blockpart, out + (size_t)out_size - 1);

  if (big) {
    u16* scores = (u16*)(W + 10ull * 1024 * 1024);   // 16 MB bf16 [16384][512]
    u16* kb     = (u16*)(W + 26ull * 1024 * 1024);   // 32 MB bf16 [32][512][1024]
    u16* vb     = (u16*)(W + 58ull * 1024 * 1024);   // 32 MB bf16 [32][1024][512]
    u16* stage  = kb;  // aliases kb: kb dead after k_up, stage written by k_down
    hipMemsetAsync(zeros, 0, 4096, stream);
    k_tr<<<dim3(ESIZE / 64, DMODEL / 64, NEXP), 256, 0, stream>>>(keys, kb, DMODEL, ESIZE);
    k_tr<<<dim3(DMODEL / 64, ESIZE / 64, NEXP), 256, 0, stream>>>(values, vb, ESIZE, DMODEL);
    k_up<<<512, 256, 0, stream>>>(xb, kb, selval, cnt, bucket, zeros, scores);
    k_down<<<512, 256, 0, stream>>>(scores, vb, cnt, bucket, zeros, stage);
    k_final<<<TOKENS / 2, 256, 0, stream>>>(stage, out);
  } else {
    u16* scores = (u16*)(W + 2ull * 1024 * 1024);
    bool big50 = ws_size >= (50ull << 20);
    u16* stage = big50 ? (u16*)(W + 18ull * 1024 * 1024) : nullptr;
    if (!big50)
      hipMemsetAsync(d_out, 0, (size_t)out_size * sizeof(float), stream);
    k_up_rs<<<512, 256, 0, stream>>>(x, keys, selval, cnt, bucket, scores);
    k_down_rs<<<512, 256, 0, stream>>>(scores, values, cnt, bucket, stage, out);
    if (big50)
      k_final<<<TOKENS / 2, 256, 0, stream>>>(stage, out);
  }
}